// Round 1
// baseline (2715.135 us; speedup 1.0000x reference)
//
#include <hip/hip_runtime.h>
#include <math.h>

// MoEProcessor: B=8, N=4096, D=256, H=W=64, WS=8, NH=8, M=16, E=4, TD=768, HID=1024, TK=2
// Full f32 implementation. Expert 0 (FNO) writes out = cw0*e0 for every element,
// experts 1..3 accumulate out += cw_e*e_e.  Weights [8,2] written at out+8388608.

#define NB 8
#define NN 4096
#define DD 256
#define HID 1024

__device__ __forceinline__ float gelu_f(float v) {
    return 0.5f * v * (1.0f + erff(v * 0.7071067811865475f));
}

// ---------------- gating ----------------
__global__ void k_gate_mean(const float* __restrict__ x, const float* __restrict__ text,
                            float* __restrict__ feat) {
    int b = blockIdx.x;
    int t = threadIdx.x; // 256
    const float* xb = x + (size_t)b * NN * DD;
    float s = 0.f;
    for (int n = 0; n < NN; ++n) s += xb[(size_t)n * DD + t];
    feat[b * 1024 + t] = s * (1.0f / NN);
    for (int j = t; j < 768; j += 256) feat[b * 1024 + 256 + j] = text[b * 768 + j];
}

__global__ void k_gate_mlp1(const float* __restrict__ feat, const float* __restrict__ w1,
                            const float* __restrict__ b1, float* __restrict__ h1) {
    int b = blockIdx.x, j = threadIdx.x;
    float acc = b1[j];
    const float* f = feat + b * 1024;
    for (int k = 0; k < 1024; ++k) acc += f[k] * w1[k * 256 + j];
    h1[b * 256 + j] = fmaxf(acc, 0.f);
}

__global__ void k_gate_top(const float* __restrict__ h1, const float* __restrict__ w2,
                           const float* __restrict__ b2, float* __restrict__ cw,
                           float* __restrict__ wout) {
    __shared__ float lg[8][4];
    int t = threadIdx.x;
    if (t < 32) {
        int b = t >> 2, e = t & 3;
        float acc = b2[e];
        const float* h = h1 + b * 256;
        for (int k = 0; k < 256; ++k) acc += h[k] * w2[k * 4 + e];
        lg[b][e] = acc;
    }
    __syncthreads();
    if (t < 8) {
        int b = t;
        float v[4];
        #pragma unroll
        for (int e = 0; e < 4; ++e) v[e] = lg[b][e];
        // jax.lax.top_k: stable descending -> first-occurrence argmax semantics
        int i0 = 0;
        #pragma unroll
        for (int e = 1; e < 4; ++e) if (v[e] > v[i0]) i0 = e;
        int i1 = -1;
        #pragma unroll
        for (int e = 0; e < 4; ++e) {
            if (e == i0) continue;
            if (i1 < 0 || v[e] > v[i1]) i1 = e;
        }
        float v0 = v[i0], v1 = v[i1];
        float e1v = expf(v1 - v0);
        float inv = 1.0f / (1.0f + e1v);
        float w0 = inv, w1v = e1v * inv;
        wout[b * 2 + 0] = w0;
        wout[b * 2 + 1] = w1v;
        float c[4] = {0.f, 0.f, 0.f, 0.f};
        c[i0] += w0; c[i1] += w1v;
        #pragma unroll
        for (int e = 0; e < 4; ++e) cw[b * 4 + e] = c[e];
    }
}

// ---------------- FNO ----------------
// transpose [B,N,D] -> [B,D,N]
__global__ void k_transpose(const float* __restrict__ x, float* __restrict__ xg) {
    __shared__ float tile[32][33];
    int b = blockIdx.z;
    int nt = blockIdx.x, dt = blockIdx.y;
    int tx = threadIdx.x, ty = threadIdx.y; // 32, 8
    const float* xb = x + (size_t)b * NN * DD;
    float* xgb = xg + (size_t)b * DD * NN;
    #pragma unroll
    for (int i = 0; i < 4; ++i) {
        int n = nt * 32 + ty + i * 8;
        tile[ty + i * 8][tx] = xb[(size_t)n * DD + dt * 32 + tx];
    }
    __syncthreads();
    #pragma unroll
    for (int i = 0; i < 4; ++i) {
        int d = dt * 32 + ty + i * 8;
        xgb[(size_t)d * NN + nt * 32 + tx] = tile[tx][ty + i * 8];
    }
}

// reduced rfft2: per plane (b,d) compute X[kh,kw] for kh in {0..15,48..63}, kw in 0..15
// output layout float2 [p][32][16], krow<16 -> kh=krow ; krow>=16 -> kh=krow+32
__global__ void __launch_bounds__(64) k_rfft2(const float* __restrict__ xg, float* __restrict__ xft) {
    __shared__ float plane[64][65];
    __shared__ float s1[64][16][2];
    __shared__ float twc[64], tws[64];
    int p = blockIdx.x;
    int t = threadIdx.x;
    const float* src = xg + (size_t)p * 4096;
    for (int i = 0; i < 64; ++i) plane[i][t] = src[i * 64 + t];
    twc[t] = cosf((float)t * (6.283185307179586f / 64.0f));
    tws[t] = sinf((float)t * (6.283185307179586f / 64.0f));
    __syncthreads();
    // stage 1: rows, e^{-i theta}
    int r = t;
    for (int kw = 0; kw < 16; ++kw) {
        float re = 0.f, im = 0.f;
        for (int w = 0; w < 64; ++w) {
            int j = (w * kw) & 63;
            float xv = plane[r][w];
            re += xv * twc[j];
            im -= xv * tws[j];
        }
        s1[r][kw][0] = re; s1[r][kw][1] = im;
    }
    __syncthreads();
    // stage 2: columns
    float2* dst = (float2*)xft + (size_t)p * 512;
    #pragma unroll
    for (int q = 0; q < 8; ++q) {
        int oi = t + q * 64;
        int krow = oi >> 4, kw = oi & 15;
        int kh = krow < 16 ? krow : krow + 32;
        float re = 0.f, im = 0.f;
        for (int h = 0; h < 64; ++h) {
            int j = (h * kh) & 63;
            float c = twc[j], s = tws[j];
            float ar = s1[h][kw][0], ai = s1[h][kw][1];
            re += ar * c + ai * s;
            im += ai * c - ar * s;
        }
        dst[oi] = make_float2(re, im);
    }
}

// spectral contraction: out[b,o,krow,y] = sum_i xft[b,i,krow,y] * w[i,o,x,y]
__global__ void __launch_bounds__(512) k_spectral(const float* __restrict__ xft,
        const float* __restrict__ w1r, const float* __restrict__ w1i,
        const float* __restrict__ w2r, const float* __restrict__ w2i,
        float* __restrict__ oft) {
    __shared__ float xf[8][32][16][2]; // 32 KB
    int region = blockIdx.z;
    const float* wr = region ? w2r : w1r;
    const float* wi = region ? w2i : w1i;
    int xm = blockIdx.y;              // mode index within region 0..15
    int krow = region * 16 + xm;
    int o0 = blockIdx.x * 32;
    int t = threadIdx.x;
    int y = t & 15, ol = t >> 4;
    int o = o0 + ol;
    float accr[8], acci[8];
    #pragma unroll
    for (int b = 0; b < 8; ++b) { accr[b] = 0.f; acci[b] = 0.f; }
    for (int i0 = 0; i0 < 256; i0 += 32) {
        __syncthreads();
        #pragma unroll
        for (int l = 0; l < 16; ++l) {
            int idx = t + l * 512;
            int c = idx & 1, yy = (idx >> 1) & 15, ic = (idx >> 5) & 31, b = idx >> 10;
            xf[b][ic][yy][c] = xft[(((size_t)b * 256 + i0 + ic) * 32 + krow) * 32 + yy * 2 + c];
        }
        __syncthreads();
        for (int ic = 0; ic < 32; ++ic) {
            int i = i0 + ic;
            size_t widx = (((size_t)i * 256 + o) * 16 + xm) * 16 + y;
            float wrv = wr[widx], wiv = wi[widx];
            #pragma unroll
            for (int b = 0; b < 8; ++b) {
                float ar = xf[b][ic][y][0], ai = xf[b][ic][y][1];
                accr[b] += ar * wrv - ai * wiv;
                acci[b] += ar * wiv + ai * wrv;
            }
        }
    }
    float2* dst = (float2*)oft;
    #pragma unroll
    for (int b = 0; b < 8; ++b)
        dst[(((size_t)b * 256 + o) * 32 + krow) * 16 + y] = make_float2(accr[b], acci[b]);
}

// fused irfft2 + conv-branch + gelu + residual + gating weight: writes all of out
__global__ void __launch_bounds__(64) k_irfft_fuse(const float* __restrict__ oft,
        const float* __restrict__ x2, const float* __restrict__ x,
        const float* __restrict__ cw, float* __restrict__ out) {
    __shared__ float F[32][16][2];
    __shared__ float tarr[64][16][2];
    __shared__ float twc[64], tws[64];
    int p = blockIdx.x; // b*256 + o
    int b = p >> 8, o = p & 255;
    int t = threadIdx.x;
    const float2* src = (const float2*)oft + (size_t)p * 512;
    #pragma unroll
    for (int l = 0; l < 8; ++l) {
        int idx = t + l * 64;
        ((float2*)F)[idx] = src[idx];
    }
    twc[t] = cosf((float)t * (6.283185307179586f / 64.0f));
    tws[t] = sinf((float)t * (6.283185307179586f / 64.0f));
    __syncthreads();
    // stage A: t[h,kw] = (1/64) sum_krow F[krow,kw] e^{+2pi i h kh/64}
    int h = t;
    for (int kw = 0; kw < 16; ++kw) {
        float re = 0.f, im = 0.f;
        #pragma unroll
        for (int krow = 0; krow < 32; ++krow) {
            int kh = krow < 16 ? krow : krow + 32;
            int j = (h * kh) & 63;
            float c = twc[j], s = tws[j];
            float fr = F[krow][kw][0], fi = F[krow][kw][1];
            re += fr * c - fi * s;
            im += fr * s + fi * c;
        }
        tarr[h][kw][0] = re * (1.f / 64.f);
        tarr[h][kw][1] = im * (1.f / 64.f);
    }
    __syncthreads();
    float cw0 = cw[b * 4 + 0];
    const size_t base = ((size_t)b * 4096) * 256 + o;
    for (int q = 0; q < 64; ++q) {
        int idx = q * 64 + t;       // idx = h*64 + w ; hh == q (uniform), w == t
        int hh = idx >> 6, w = idx & 63;
        float acc = tarr[hh][0][0];
        #pragma unroll
        for (int kw = 1; kw < 16; ++kw) {
            int j = (w * kw) & 63;
            acc += 2.f * (tarr[hh][kw][0] * twc[j] - tarr[hh][kw][1] * tws[j]);
        }
        float x1 = acc * (1.f / 64.f);
        size_t g = base + (size_t)idx * 256;
        float v = gelu_f(x1 + x2[g]) + x[g];
        out[g] = cw0 * v;
    }
}

// ---------------- generic matmul (K=256): out[r,j] = A[r,:]@B[:,j] + bias[j] (+res) ----------------
__global__ void __launch_bounds__(256) k_matmul_bias(const float* __restrict__ A,
        const float* __restrict__ Bm, const float* __restrict__ bias,
        const float* __restrict__ res, float* __restrict__ outp, int Ncols, int mode) {
    __shared__ float xs[256][8];
    int row0 = blockIdx.x * 8;
    int j = blockIdx.y * 256 + threadIdx.x;
    int t = threadIdx.x;
    #pragma unroll
    for (int l = 0; l < 8; ++l) {
        int idx = t + l * 256;
        int k = idx & 255, r = idx >> 8;
        xs[k][r] = A[(size_t)(row0 + r) * 256 + k];
    }
    __syncthreads();
    float acc[8];
    #pragma unroll
    for (int r = 0; r < 8; ++r) acc[r] = 0.f;
    for (int k = 0; k < 256; ++k) {
        float bv = Bm[(size_t)k * Ncols + j];
        float4 x0 = *(const float4*)&xs[k][0];
        float4 x1 = *(const float4*)&xs[k][4];
        acc[0] += x0.x * bv; acc[1] += x0.y * bv; acc[2] += x0.z * bv; acc[3] += x0.w * bv;
        acc[4] += x1.x * bv; acc[5] += x1.y * bv; acc[6] += x1.z * bv; acc[7] += x1.w * bv;
    }
    float bj = bias[j];
    #pragma unroll
    for (int r = 0; r < 8; ++r) {
        size_t oidx = (size_t)(row0 + r) * Ncols + j;
        float v = acc[r] + bj;
        if (mode == 1) v += res[(size_t)(row0 + r) * 256 + j];
        outp[oidx] = v;
    }
}

// ---------------- layernorm ----------------
__global__ void __launch_bounds__(256) k_ln(const float* __restrict__ in, const float* __restrict__ g,
        const float* __restrict__ be, float* __restrict__ outp) {
    int row = blockIdx.x * 4 + (threadIdx.x >> 6);
    int lane = threadIdx.x & 63;
    const float4* rp = (const float4*)(in + (size_t)row * 256);
    float4 v = rp[lane];
    float s = v.x + v.y + v.z + v.w;
    float s2 = v.x * v.x + v.y * v.y + v.z * v.z + v.w * v.w;
    #pragma unroll
    for (int off = 32; off > 0; off >>= 1) {
        s += __shfl_down(s, off);
        s2 += __shfl_down(s2, off);
    }
    s = __shfl(s, 0); s2 = __shfl(s2, 0);
    float mu = s * (1.f / 256.f);
    float var = s2 * (1.f / 256.f) - mu * mu;
    float rstd = rsqrtf(var + 1e-5f);
    float4 gv = ((const float4*)g)[lane];
    float4 bv = ((const float4*)be)[lane];
    float4 ov;
    ov.x = (v.x - mu) * rstd * gv.x + bv.x;
    ov.y = (v.y - mu) * rstd * gv.y + bv.y;
    ov.z = (v.z - mu) * rstd * gv.z + bv.z;
    ov.w = (v.w - mu) * rstd * gv.w + bv.w;
    ((float4*)(outp + (size_t)row * 256))[lane] = ov;
}

// ---------------- window attention core ----------------
__global__ void __launch_bounds__(64) k_window_attn(const float* __restrict__ qkv,
        float* __restrict__ attn_o) {
    __shared__ float ks[64][36], vs[64][36];
    __shared__ float ps[64][65];
    int wi = blockIdx.x >> 3;   // window 0..511
    int hd = blockIdx.x & 7;    // head
    int b = wi >> 6;
    int hb = (wi >> 3) & 7, wb = wi & 7;
    int t = threadIdx.x;
    for (int l = 0; l < 32; ++l) {
        int idx = t + l * 64;
        int tok = idx >> 5, d = idx & 31;
        int n = (hb * 8 + (tok >> 3)) * 64 + wb * 8 + (tok & 7);
        size_t base = ((size_t)b * 4096 + n) * 768 + hd * 32 + d;
        ks[tok][d] = qkv[base + 256];
        vs[tok][d] = qkv[base + 512];
    }
    int l = t;
    int nq = (hb * 8 + (l >> 3)) * 64 + wb * 8 + (l & 7);
    const float4* qp = (const float4*)(qkv + ((size_t)b * 4096 + nq) * 768 + hd * 32);
    float4 q[8];
    #pragma unroll
    for (int i = 0; i < 8; ++i) q[i] = qp[i];
    __syncthreads();
    const float scale = 0.17677669529663687f; // 1/sqrt(32)
    float mx = -1e30f;
    for (int m = 0; m < 64; ++m) {
        const float4* kr = (const float4*)&ks[m][0];
        float a = 0.f;
        #pragma unroll
        for (int i = 0; i < 8; ++i) {
            float4 kv = kr[i];
            a += q[i].x * kv.x + q[i].y * kv.y + q[i].z * kv.z + q[i].w * kv.w;
        }
        a *= scale;
        ps[l][m] = a;
        mx = fmaxf(mx, a);
    }
    float ssum = 0.f;
    for (int m = 0; m < 64; ++m) {
        float p = expf(ps[l][m] - mx);
        ps[l][m] = p;
        ssum += p;
    }
    float inv = 1.f / ssum;
    float4 o[8];
    #pragma unroll
    for (int i = 0; i < 8; ++i) o[i] = make_float4(0.f, 0.f, 0.f, 0.f);
    for (int m = 0; m < 64; ++m) {
        float p = ps[l][m];
        const float4* vr = (const float4*)&vs[m][0];
        #pragma unroll
        for (int i = 0; i < 8; ++i) {
            float4 vv = vr[i];
            o[i].x += p * vv.x; o[i].y += p * vv.y; o[i].z += p * vv.z; o[i].w += p * vv.w;
        }
    }
    float4* op = (float4*)(attn_o + ((size_t)b * 4096 + nq) * 256 + hd * 32);
    #pragma unroll
    for (int i = 0; i < 8; ++i) {
        o[i].x *= inv; o[i].y *= inv; o[i].z *= inv; o[i].w *= inv;
        op[i] = o[i];
    }
}

// ---------------- fused MLP: out += cw * (gelu(in@w1+b1)@w2 + b2 + res) ----------------
__global__ void __launch_bounds__(256) k_mlp_fused(const float* __restrict__ inp,
        const float* __restrict__ res, const float* __restrict__ w1,
        const float* __restrict__ b1, const float* __restrict__ w2,
        const float* __restrict__ b2, const float* __restrict__ cw, int eidx,
        float* __restrict__ outp) {
    __shared__ float xs[256][8];   // 8 KB  (transposed x tile)
    __shared__ float hs[1024][8];  // 32 KB (transposed hidden tile)
    int row0 = blockIdx.x * 8;
    int t = threadIdx.x;
    #pragma unroll
    for (int l = 0; l < 8; ++l) {
        int idx = t + l * 256;
        int k = idx & 255, r = idx >> 8;
        xs[k][r] = inp[(size_t)(row0 + r) * 256 + k];
    }
    __syncthreads();
    float acc[4][8];
    #pragma unroll
    for (int jc = 0; jc < 4; ++jc)
        #pragma unroll
        for (int r = 0; r < 8; ++r) acc[jc][r] = 0.f;
    for (int k = 0; k < 256; ++k) {
        float4 x0 = *(const float4*)&xs[k][0];
        float4 x1 = *(const float4*)&xs[k][4];
        #pragma unroll
        for (int jc = 0; jc < 4; ++jc) {
            float wv = w1[(size_t)k * 1024 + jc * 256 + t];
            acc[jc][0] += x0.x * wv; acc[jc][1] += x0.y * wv;
            acc[jc][2] += x0.z * wv; acc[jc][3] += x0.w * wv;
            acc[jc][4] += x1.x * wv; acc[jc][5] += x1.y * wv;
            acc[jc][6] += x1.z * wv; acc[jc][7] += x1.w * wv;
        }
    }
    #pragma unroll
    for (int jc = 0; jc < 4; ++jc) {
        int j = jc * 256 + t;
        float bb = b1[j];
        float4 h0, h1v;
        h0.x = gelu_f(acc[jc][0] + bb); h0.y = gelu_f(acc[jc][1] + bb);
        h0.z = gelu_f(acc[jc][2] + bb); h0.w = gelu_f(acc[jc][3] + bb);
        h1v.x = gelu_f(acc[jc][4] + bb); h1v.y = gelu_f(acc[jc][5] + bb);
        h1v.z = gelu_f(acc[jc][6] + bb); h1v.w = gelu_f(acc[jc][7] + bb);
        *(float4*)&hs[j][0] = h0;
        *(float4*)&hs[j][4] = h1v;
    }
    __syncthreads();
    float acc2[8];
    #pragma unroll
    for (int r = 0; r < 8; ++r) acc2[r] = 0.f;
    for (int kk = 0; kk < 1024; ++kk) {
        float wv = w2[(size_t)kk * 256 + t];
        float4 h0 = *(const float4*)&hs[kk][0];
        float4 h1v = *(const float4*)&hs[kk][4];
        acc2[0] += h0.x * wv; acc2[1] += h0.y * wv; acc2[2] += h0.z * wv; acc2[3] += h0.w * wv;
        acc2[4] += h1v.x * wv; acc2[5] += h1v.y * wv; acc2[6] += h1v.z * wv; acc2[7] += h1v.w * wv;
    }
    float bj = b2[t];
    #pragma unroll
    for (int r = 0; r < 8; ++r) {
        int row = row0 + r;
        int bidx = row >> 12;
        float cwv = cw[bidx * 4 + eidx];
        size_t g = (size_t)row * 256 + t;
        float v = acc2[r] + bj + res[g];
        outp[g] += cwv * v;
    }
}

extern "C" void kernel_launch(void* const* d_in, const int* in_sizes, int n_in,
                              void* d_out, int out_size, void* d_ws, size_t ws_size,
                              hipStream_t stream) {
    (void)in_sizes; (void)n_in; (void)out_size; (void)ws_size;
    const float* x        = (const float*)d_in[0];
    const float* text     = (const float*)d_in[1];
    const float* gate_w1  = (const float*)d_in[2];
    const float* gate_b1  = (const float*)d_in[3];
    const float* gate_w2  = (const float*)d_in[4];
    const float* gate_b2  = (const float*)d_in[5];
    const float* fno_w1r  = (const float*)d_in[6];
    const float* fno_w1i  = (const float*)d_in[7];
    const float* fno_w2r  = (const float*)d_in[8];
    const float* fno_w2i  = (const float*)d_in[9];
    const float* fno_cw   = (const float*)d_in[10];
    const float* fno_cb   = (const float*)d_in[11];
    const float* mlp1_w1  = (const float*)d_in[12];
    const float* mlp1_b1  = (const float*)d_in[13];
    const float* mlp1_w2  = (const float*)d_in[14];
    const float* mlp1_b2  = (const float*)d_in[15];
    const float* mlp2_w1  = (const float*)d_in[16];
    const float* mlp2_b1  = (const float*)d_in[17];
    const float* mlp2_w2  = (const float*)d_in[18];
    const float* mlp2_b2  = (const float*)d_in[19];
    const float* ln1_g    = (const float*)d_in[20];
    const float* ln1_b    = (const float*)d_in[21];
    const float* qkv_w    = (const float*)d_in[22];
    const float* qkv_b    = (const float*)d_in[23];
    const float* out_w    = (const float*)d_in[24];
    const float* out_b    = (const float*)d_in[25];
    const float* ln2_g    = (const float*)d_in[26];
    const float* ln2_b    = (const float*)d_in[27];
    const float* wa_w1    = (const float*)d_in[28];
    const float* wa_b1    = (const float*)d_in[29];
    const float* wa_w2    = (const float*)d_in[30];
    const float* wa_b2    = (const float*)d_in[31];

    float* ws  = (float*)d_ws;
    float* feat = ws;                    // 8192
    float* h1   = ws + 8192;             // 2048
    float* cwp  = ws + 10240;            // 32
    float* regA = ws + 16384;            // 8388608  xg / ln1-out / attn_o
    float* xft  = regA + 8388608;        // 2097152
    float* oft  = xft + 2097152;         // 2097152
    float* regD = oft + 2097152;         // 8388608  x2 / xp
    float* regE = regD + 8388608;        // 25165824 qkv / h2
    // total ws: 46,153,728 floats = 184.6 MB

    float* outp = (float*)d_out;
    float* wout = outp + (size_t)NB * NN * DD;   // weights [8,2]

    // gating
    k_gate_mean<<<8, 256, 0, stream>>>(x, text, feat);
    k_gate_mlp1<<<8, 256, 0, stream>>>(feat, gate_w1, gate_b1, h1);
    k_gate_top<<<1, 64, 0, stream>>>(h1, gate_w2, gate_b2, cwp, wout);

    // expert 0: FNO (writes all of out with weight cw0)
    k_transpose<<<dim3(128, 8, 8), dim3(32, 8), 0, stream>>>(x, regA);
    k_rfft2<<<2048, 64, 0, stream>>>(regA, xft);
    k_matmul_bias<<<dim3(4096, 1), 256, 0, stream>>>(x, fno_cw, fno_cb, nullptr, regD, 256, 0);
    k_spectral<<<dim3(8, 16, 2), 512, 0, stream>>>(xft, fno_w1r, fno_w1i, fno_w2r, fno_w2i, oft);
    k_irfft_fuse<<<2048, 64, 0, stream>>>(oft, regD, x, cwp, outp);

    // expert 1: MLP
    k_mlp_fused<<<4096, 256, 0, stream>>>(x, x, mlp1_w1, mlp1_b1, mlp1_w2, mlp1_b2, cwp, 1, outp);

    // expert 2: window attention
    k_ln<<<8192, 256, 0, stream>>>(x, ln1_g, ln1_b, regA);
    k_matmul_bias<<<dim3(4096, 3), 256, 0, stream>>>(regA, qkv_w, qkv_b, nullptr, regE, 768, 0);
    k_window_attn<<<4096, 64, 0, stream>>>(regE, regA);
    k_matmul_bias<<<dim3(4096, 1), 256, 0, stream>>>(regA, out_w, out_b, x, regD, 256, 1);
    k_ln<<<8192, 256, 0, stream>>>(regD, ln2_g, ln2_b, regE);
    k_mlp_fused<<<4096, 256, 0, stream>>>(regE, regD, wa_w1, wa_b1, wa_w2, wa_b2, cwp, 2, outp);

    // expert 3: MLP
    k_mlp_fused<<<4096, 256, 0, stream>>>(x, x, mlp2_w1, mlp2_b1, mlp2_w2, mlp2_b2, cwp, 3, outp);
}

// Round 2
// 1193.230 us; speedup vs baseline: 2.2754x; 2.2754x over previous
//
#include <hip/hip_runtime.h>
#include <math.h>

// MoEProcessor: B=8, N=4096, D=256, H=W=64, WS=8, NH=8, M=16, E=4, TD=768, HID=1024, TK=2
// Round 2: all GEMMs via bf16 MFMA (16x16x32), m97-style 128x128 tiles.

#define NB 8
#define NN 4096
#define DD 256

typedef __attribute__((ext_vector_type(8))) short bf16x8;
typedef __attribute__((ext_vector_type(4))) float f32x4;

__device__ __forceinline__ float gelu_f(float v) {
    return 0.5f * v * (1.0f + erff(v * 0.7071067811865475f));
}
__device__ __forceinline__ ushort f2bf(float f) {
    uint32_t u = __float_as_uint(f);
    uint32_t r = (u + 0x7fffu + ((u >> 16) & 1u)) >> 16;
    return (ushort)r;
}
__device__ __forceinline__ float b2f(ushort h) {
    return __uint_as_float(((uint32_t)h) << 16);
}

// ---------------- gating ----------------
__global__ void k_gate_mean(const float* __restrict__ x, const float* __restrict__ text,
                            float* __restrict__ feat) {
    int b = blockIdx.x;
    int t = threadIdx.x; // 256
    const float* xb = x + (size_t)b * NN * DD;
    float s = 0.f;
    for (int n = 0; n < NN; ++n) s += xb[(size_t)n * DD + t];
    feat[b * 1024 + t] = s * (1.0f / NN);
    for (int j = t; j < 768; j += 256) feat[b * 1024 + 256 + j] = text[b * 768 + j];
}

__global__ void k_gate_mlp1(const float* __restrict__ feat, const float* __restrict__ w1,
                            const float* __restrict__ b1, float* __restrict__ h1) {
    int b = blockIdx.x, j = threadIdx.x;
    float acc = b1[j];
    const float* f = feat + b * 1024;
    for (int k = 0; k < 1024; ++k) acc += f[k] * w1[k * 256 + j];
    h1[b * 256 + j] = fmaxf(acc, 0.f);
}

__global__ void k_gate_top(const float* __restrict__ h1, const float* __restrict__ w2,
                           const float* __restrict__ b2, float* __restrict__ cw,
                           float* __restrict__ wout) {
    __shared__ float lg[8][4];
    int t = threadIdx.x;
    if (t < 32) {
        int b = t >> 2, e = t & 3;
        float acc = b2[e];
        const float* h = h1 + b * 256;
        for (int k = 0; k < 256; ++k) acc += h[k] * w2[k * 4 + e];
        lg[b][e] = acc;
    }
    __syncthreads();
    if (t < 8) {
        int b = t;
        float v[4];
        #pragma unroll
        for (int e = 0; e < 4; ++e) v[e] = lg[b][e];
        int i0 = 0;
        #pragma unroll
        for (int e = 1; e < 4; ++e) if (v[e] > v[i0]) i0 = e;
        int i1 = -1;
        #pragma unroll
        for (int e = 0; e < 4; ++e) {
            if (e == i0) continue;
            if (i1 < 0 || v[e] > v[i1]) i1 = e;
        }
        float v0 = v[i0], v1 = v[i1];
        float e1v = expf(v1 - v0);
        float inv = 1.0f / (1.0f + e1v);
        float w0 = inv, w1v = e1v * inv;
        wout[b * 2 + 0] = w0;
        wout[b * 2 + 1] = w1v;
        float c[4] = {0.f, 0.f, 0.f, 0.f};
        c[i0] += w0; c[i1] += w1v;
        #pragma unroll
        for (int e = 0; e < 4; ++e) cw[b * 4 + e] = c[e];
    }
}

// ---------------- prep: f32 -> bf16 ----------------
__global__ void k_cvtbf(const float* __restrict__ src, ushort* __restrict__ dst) {
    int i = blockIdx.x * 256 + threadIdx.x;
    float4 v = ((const float4*)src)[i];
    ushort4 o;
    o.x = f2bf(v.x); o.y = f2bf(v.y); o.z = f2bf(v.z); o.w = f2bf(v.w);
    ((ushort4*)dst)[i] = o;
}

// transpose+convert: src f32 [K][N] -> dst bf16 [N][K].  grid (N/32, K/32), block (32,8)
__global__ void k_wt(const float* __restrict__ src, ushort* __restrict__ dst, int K, int N) {
    __shared__ float tile[32][33];
    int n0 = blockIdx.x * 32, k0 = blockIdx.y * 32;
    int tx = threadIdx.x, ty = threadIdx.y;
    #pragma unroll
    for (int i = 0; i < 4; ++i)
        tile[ty + i * 8][tx] = src[(size_t)(k0 + ty + i * 8) * N + n0 + tx];
    __syncthreads();
    #pragma unroll
    for (int i = 0; i < 4; ++i)
        dst[(size_t)(n0 + ty + i * 8) * K + k0 + tx] = f2bf(tile[tx][ty + i * 8]);
}

// ---------------- MFMA GEMM ----------------
// C[M,N] = A[M,K]bf16 @ Bt[N,K]bf16^T, 128x128 tile, BK=32, 4 waves (2x2), 4x4 frags.
// MODE 0: outb = bf16(gelu(acc+bias))           (gemm1, hidden)
// MODE 1: outb = bf16(acc+bias)                 (qkv)
// MODE 2: outf = acc+bias (+res)                (conv / out-proj)
// MODE 3: outf += cw[b,eidx]*(acc+bias+res)     (gemm2, expert accumulate)
template<int MODE>
__global__ void __launch_bounds__(256) k_gemm(const ushort* __restrict__ A,
        const ushort* __restrict__ Bt, const float* __restrict__ bias,
        const float* __restrict__ res, float* __restrict__ outf,
        ushort* __restrict__ outb, const float* __restrict__ cw, int eidx,
        int K, int Ncols) {
    __shared__ alignas(16) char smem[32768];
    ushort* sA = (ushort*)smem;            // [2][4096]
    ushort* sB = (ushort*)(smem + 16384);  // [2][4096]
    int m0 = blockIdx.x * 128;
    int n0 = blockIdx.y * 128;
    int t = threadIdx.x;
    int lane = t & 63, wid = t >> 6;
    int wr = wid >> 1, wc = wid & 1;
    int rlo = lane & 15, khi = (lane >> 4) * 8;

    auto stage = [&](int buf, int k0) {
        const ushort* Ab = A + (size_t)m0 * K + k0;
        const ushort* Bb = Bt + (size_t)n0 * K + k0;
        #pragma unroll
        for (int h = 0; h < 2; ++h) {
            int s = t + h * 256;
            int row = s >> 2, kc = (s & 3) * 8;
            __builtin_amdgcn_global_load_lds(
                (const __attribute__((address_space(1))) void*)(Ab + (size_t)row * K + kc),
                (__attribute__((address_space(3))) void*)(sA + buf * 4096 + s * 8),
                16, 0, 0);
            __builtin_amdgcn_global_load_lds(
                (const __attribute__((address_space(1))) void*)(Bb + (size_t)row * K + kc),
                (__attribute__((address_space(3))) void*)(sB + buf * 4096 + s * 8),
                16, 0, 0);
        }
    };

    f32x4 acc[4][4];
    #pragma unroll
    for (int i = 0; i < 4; ++i)
        #pragma unroll
        for (int j = 0; j < 4; ++j) acc[i][j] = (f32x4){0.f, 0.f, 0.f, 0.f};

    int KT = K >> 5;
    stage(0, 0);
    int cur = 0;
    for (int kt = 0; kt < KT; ++kt) {
        __syncthreads();
        if (kt + 1 < KT) stage(cur ^ 1, (kt + 1) << 5);
        const ushort* Ap = sA + cur * 4096;
        const ushort* Bp = sB + cur * 4096;
        bf16x8 af[4], bfr[4];
        #pragma unroll
        for (int i = 0; i < 4; ++i) {
            af[i]  = *(const bf16x8*)(Ap + (wr * 64 + i * 16 + rlo) * 32 + khi);
            bfr[i] = *(const bf16x8*)(Bp + (wc * 64 + i * 16 + rlo) * 32 + khi);
        }
        #pragma unroll
        for (int i = 0; i < 4; ++i)
            #pragma unroll
            for (int j = 0; j < 4; ++j)
                acc[i][j] = __builtin_amdgcn_mfma_f32_16x16x32_bf16(af[i], bfr[j], acc[i][j], 0, 0, 0);
        cur ^= 1;
    }

    // bias per thread's 4 column slots
    float bj4[4];
    #pragma unroll
    for (int nt = 0; nt < 4; ++nt) bj4[nt] = bias[n0 + wc * 64 + nt * 16 + rlo];

    if constexpr (MODE == 0 || MODE == 1) {
        ushort* eb = (ushort*)smem;  // [32][136]
        #pragma unroll
        for (int mt = 0; mt < 4; ++mt) {
            __syncthreads();
            #pragma unroll
            for (int nt = 0; nt < 4; ++nt) {
                int col = wc * 64 + nt * 16 + rlo;
                #pragma unroll
                for (int j = 0; j < 4; ++j) {
                    float v = acc[mt][nt][j] + bj4[nt];
                    if (MODE == 0) v = gelu_f(v);
                    eb[(wr * 16 + (lane >> 4) * 4 + j) * 136 + col] = f2bf(v);
                }
            }
            __syncthreads();
            #pragma unroll
            for (int h = 0; h < 2; ++h) {
                int s = t + h * 256;
                int r = s >> 4, c = (s & 15) * 8;
                int grow = m0 + (r >> 4) * 64 + mt * 16 + (r & 15);
                *(uint4*)(outb + (size_t)grow * Ncols + n0 + c) = *(uint4*)&eb[r * 136 + c];
            }
        }
    } else {
        float* ep = (float*)smem;  // [32][132]
        #pragma unroll
        for (int mt = 0; mt < 4; ++mt) {
            __syncthreads();
            #pragma unroll
            for (int nt = 0; nt < 4; ++nt) {
                int col = wc * 64 + nt * 16 + rlo;
                #pragma unroll
                for (int j = 0; j < 4; ++j)
                    ep[(wr * 16 + (lane >> 4) * 4 + j) * 132 + col] = acc[mt][nt][j] + bj4[nt];
            }
            __syncthreads();
            #pragma unroll
            for (int h = 0; h < 4; ++h) {
                int s = t + h * 256;
                int r = s >> 5, c4 = (s & 31) * 4;
                int grow = m0 + (r >> 4) * 64 + mt * 16 + (r & 15);
                size_t g = (size_t)grow * Ncols + n0 + c4;
                float4 v = *(float4*)&ep[r * 132 + c4];
                if constexpr (MODE == 2) {
                    if (res) {
                        float4 rv = *(const float4*)&res[g];
                        v.x += rv.x; v.y += rv.y; v.z += rv.z; v.w += rv.w;
                    }
                    *(float4*)&outf[g] = v;
                } else {
                    float cwv = cw[(grow >> 12) * 4 + eidx];
                    float4 rv = *(const float4*)&res[g];
                    float4 ov = *(float4*)&outf[g];
                    ov.x += cwv * (v.x + rv.x);
                    ov.y += cwv * (v.y + rv.y);
                    ov.z += cwv * (v.z + rv.z);
                    ov.w += cwv * (v.w + rv.w);
                    *(float4*)&outf[g] = ov;
                }
            }
        }
    }
}

// ---------------- FNO ----------------
__global__ void k_transpose(const float* __restrict__ x, float* __restrict__ xg) {
    __shared__ float tile[32][33];
    int b = blockIdx.z;
    int nt = blockIdx.x, dt = blockIdx.y;
    int tx = threadIdx.x, ty = threadIdx.y;
    const float* xb = x + (size_t)b * NN * DD;
    float* xgb = xg + (size_t)b * DD * NN;
    #pragma unroll
    for (int i = 0; i < 4; ++i) {
        int n = nt * 32 + ty + i * 8;
        tile[ty + i * 8][tx] = xb[(size_t)n * DD + dt * 32 + tx];
    }
    __syncthreads();
    #pragma unroll
    for (int i = 0; i < 4; ++i) {
        int d = dt * 32 + ty + i * 8;
        xgb[(size_t)d * NN + nt * 32 + tx] = tile[tx][ty + i * 8];
    }
}

__global__ void __launch_bounds__(64) k_rfft2(const float* __restrict__ xg, float* __restrict__ xft) {
    __shared__ float plane[64][65];
    __shared__ float s1[64][16][2];
    __shared__ float twc[64], tws[64];
    int p = blockIdx.x;
    int t = threadIdx.x;
    const float* src = xg + (size_t)p * 4096;
    for (int i = 0; i < 64; ++i) plane[i][t] = src[i * 64 + t];
    twc[t] = cosf((float)t * (6.283185307179586f / 64.0f));
    tws[t] = sinf((float)t * (6.283185307179586f / 64.0f));
    __syncthreads();
    int r = t;
    for (int kw = 0; kw < 16; ++kw) {
        float re = 0.f, im = 0.f;
        for (int w = 0; w < 64; ++w) {
            int j = (w * kw) & 63;
            float xv = plane[r][w];
            re += xv * twc[j];
            im -= xv * tws[j];
        }
        s1[r][kw][0] = re; s1[r][kw][1] = im;
    }
    __syncthreads();
    float2* dst = (float2*)xft + (size_t)p * 512;
    #pragma unroll
    for (int q = 0; q < 8; ++q) {
        int oi = t + q * 64;
        int krow = oi >> 4, kw = oi & 15;
        int kh = krow < 16 ? krow : krow + 32;
        float re = 0.f, im = 0.f;
        for (int h = 0; h < 64; ++h) {
            int j = (h * kh) & 63;
            float c = twc[j], s = tws[j];
            float ar = s1[h][kw][0], ai = s1[h][kw][1];
            re += ar * c + ai * s;
            im += ai * c - ar * s;
        }
        dst[oi] = make_float2(re, im);
    }
}

__global__ void __launch_bounds__(512) k_spectral(const float* __restrict__ xft,
        const float* __restrict__ w1r, const float* __restrict__ w1i,
        const float* __restrict__ w2r, const float* __restrict__ w2i,
        float* __restrict__ oft) {
    __shared__ float xf[8][32][16][2];
    int region = blockIdx.z;
    const float* wr = region ? w2r : w1r;
    const float* wi = region ? w2i : w1i;
    int xm = blockIdx.y;
    int krow = region * 16 + xm;
    int o0 = blockIdx.x * 32;
    int t = threadIdx.x;
    int y = t & 15, ol = t >> 4;
    int o = o0 + ol;
    float accr[8], acci[8];
    #pragma unroll
    for (int b = 0; b < 8; ++b) { accr[b] = 0.f; acci[b] = 0.f; }
    for (int i0 = 0; i0 < 256; i0 += 32) {
        __syncthreads();
        #pragma unroll
        for (int l = 0; l < 16; ++l) {
            int idx = t + l * 512;
            int c = idx & 1, yy = (idx >> 1) & 15, ic = (idx >> 5) & 31, b = idx >> 10;
            xf[b][ic][yy][c] = xft[(((size_t)b * 256 + i0 + ic) * 32 + krow) * 32 + yy * 2 + c];
        }
        __syncthreads();
        for (int ic = 0; ic < 32; ++ic) {
            int i = i0 + ic;
            size_t widx = (((size_t)i * 256 + o) * 16 + xm) * 16 + y;
            float wrv = wr[widx], wiv = wi[widx];
            #pragma unroll
            for (int b = 0; b < 8; ++b) {
                float ar = xf[b][ic][y][0], ai = xf[b][ic][y][1];
                accr[b] += ar * wrv - ai * wiv;
                acci[b] += ar * wiv + ai * wrv;
            }
        }
    }
    float2* dst = (float2*)oft;
    #pragma unroll
    for (int b = 0; b < 8; ++b)
        dst[(((size_t)b * 256 + o) * 32 + krow) * 16 + y] = make_float2(accr[b], acci[b]);
}

__global__ void __launch_bounds__(64) k_irfft_fuse(const float* __restrict__ oft,
        const float* __restrict__ x2, const float* __restrict__ x,
        const float* __restrict__ cw, float* __restrict__ out) {
    __shared__ float F[32][16][2];
    __shared__ float tarr[64][16][2];
    __shared__ float twc[64], tws[64];
    int p = blockIdx.x;
    int b = p >> 8, o = p & 255;
    int t = threadIdx.x;
    const float2* src = (const float2*)oft + (size_t)p * 512;
    #pragma unroll
    for (int l = 0; l < 8; ++l) {
        int idx = t + l * 64;
        ((float2*)F)[idx] = src[idx];
    }
    twc[t] = cosf((float)t * (6.283185307179586f / 64.0f));
    tws[t] = sinf((float)t * (6.283185307179586f / 64.0f));
    __syncthreads();
    int h = t;
    for (int kw = 0; kw < 16; ++kw) {
        float re = 0.f, im = 0.f;
        #pragma unroll
        for (int krow = 0; krow < 32; ++krow) {
            int kh = krow < 16 ? krow : krow + 32;
            int j = (h * kh) & 63;
            float c = twc[j], s = tws[j];
            float fr = F[krow][kw][0], fi = F[krow][kw][1];
            re += fr * c - fi * s;
            im += fr * s + fi * c;
        }
        tarr[h][kw][0] = re * (1.f / 64.f);
        tarr[h][kw][1] = im * (1.f / 64.f);
    }
    __syncthreads();
    float cw0 = cw[b * 4 + 0];
    const size_t base = ((size_t)b * 4096) * 256 + o;
    for (int q = 0; q < 64; ++q) {
        int idx = q * 64 + t;
        int hh = idx >> 6, w = idx & 63;
        float acc = tarr[hh][0][0];
        #pragma unroll
        for (int kw = 1; kw < 16; ++kw) {
            int j = (w * kw) & 63;
            acc += 2.f * (tarr[hh][kw][0] * twc[j] - tarr[hh][kw][1] * tws[j]);
        }
        float x1 = acc * (1.f / 64.f);
        size_t g = base + (size_t)idx * 256;
        float v = gelu_f(x1 + x2[g]) + x[g];
        out[g] = cw0 * v;
    }
}

// ---------------- layernorm (f32 in, bf16 out) ----------------
__global__ void __launch_bounds__(256) k_ln(const float* __restrict__ in, const float* __restrict__ g,
        const float* __restrict__ be, ushort* __restrict__ outb) {
    int row = blockIdx.x * 4 + (threadIdx.x >> 6);
    int lane = threadIdx.x & 63;
    const float4* rp = (const float4*)(in + (size_t)row * 256);
    float4 v = rp[lane];
    float s = v.x + v.y + v.z + v.w;
    float s2 = v.x * v.x + v.y * v.y + v.z * v.z + v.w * v.w;
    #pragma unroll
    for (int off = 32; off > 0; off >>= 1) {
        s += __shfl_down(s, off);
        s2 += __shfl_down(s2, off);
    }
    s = __shfl(s, 0); s2 = __shfl(s2, 0);
    float mu = s * (1.f / 256.f);
    float var = s2 * (1.f / 256.f) - mu * mu;
    float rstd = rsqrtf(var + 1e-5f);
    float4 gv = ((const float4*)g)[lane];
    float4 bv = ((const float4*)be)[lane];
    ushort4 ov;
    ov.x = f2bf((v.x - mu) * rstd * gv.x + bv.x);
    ov.y = f2bf((v.y - mu) * rstd * gv.y + bv.y);
    ov.z = f2bf((v.z - mu) * rstd * gv.z + bv.z);
    ov.w = f2bf((v.w - mu) * rstd * gv.w + bv.w);
    ((ushort4*)(outb + (size_t)row * 256))[lane] = ov;
}

// ---------------- window attention core (bf16 in, bf16 out) ----------------
__global__ void __launch_bounds__(64) k_window_attn(const ushort* __restrict__ qkvb,
        ushort* __restrict__ aob) {
    __shared__ float ks[64][36], vs[64][36];
    __shared__ float ps[64][65];
    int wi = blockIdx.x >> 3;
    int hd = blockIdx.x & 7;
    int b = wi >> 6;
    int hb = (wi >> 3) & 7, wb = wi & 7;
    int t = threadIdx.x;
    for (int l2 = 0; l2 < 32; ++l2) {
        int idx = t + l2 * 64;
        int tok = idx >> 5, d = idx & 31;
        int n = (hb * 8 + (tok >> 3)) * 64 + wb * 8 + (tok & 7);
        size_t base = ((size_t)b * 4096 + n) * 768 + hd * 32 + d;
        ks[tok][d] = b2f(qkvb[base + 256]);
        vs[tok][d] = b2f(qkvb[base + 512]);
    }
    int l = t;
    int nq = (hb * 8 + (l >> 3)) * 64 + wb * 8 + (l & 7);
    const ushort4* qp = (const ushort4*)(qkvb + ((size_t)b * 4096 + nq) * 768 + hd * 32);
    float4 q[8];
    #pragma unroll
    for (int i = 0; i < 8; ++i) {
        ushort4 u = qp[i];
        q[i] = make_float4(b2f(u.x), b2f(u.y), b2f(u.z), b2f(u.w));
    }
    __syncthreads();
    const float scale = 0.17677669529663687f;
    float mx = -1e30f;
    for (int m = 0; m < 64; ++m) {
        const float4* kr = (const float4*)&ks[m][0];
        float a = 0.f;
        #pragma unroll
        for (int i = 0; i < 8; ++i) {
            float4 kv = kr[i];
            a += q[i].x * kv.x + q[i].y * kv.y + q[i].z * kv.z + q[i].w * kv.w;
        }
        a *= scale;
        ps[l][m] = a;
        mx = fmaxf(mx, a);
    }
    float ssum = 0.f;
    for (int m = 0; m < 64; ++m) {
        float p = expf(ps[l][m] - mx);
        ps[l][m] = p;
        ssum += p;
    }
    float inv = 1.f / ssum;
    float4 o[8];
    #pragma unroll
    for (int i = 0; i < 8; ++i) o[i] = make_float4(0.f, 0.f, 0.f, 0.f);
    for (int m = 0; m < 64; ++m) {
        float p = ps[l][m];
        const float4* vr = (const float4*)&vs[m][0];
        #pragma unroll
        for (int i = 0; i < 8; ++i) {
            float4 vv = vr[i];
            o[i].x += p * vv.x; o[i].y += p * vv.y; o[i].z += p * vv.z; o[i].w += p * vv.w;
        }
    }
    ushort* op = aob + ((size_t)b * 4096 + nq) * 256 + hd * 32;
    #pragma unroll
    for (int i = 0; i < 8; ++i) {
        ushort4 u;
        u.x = f2bf(o[i].x * inv); u.y = f2bf(o[i].y * inv);
        u.z = f2bf(o[i].z * inv); u.w = f2bf(o[i].w * inv);
        ((ushort4*)op)[i] = u;
    }
}

extern "C" void kernel_launch(void* const* d_in, const int* in_sizes, int n_in,
                              void* d_out, int out_size, void* d_ws, size_t ws_size,
                              hipStream_t stream) {
    (void)in_sizes; (void)n_in; (void)out_size; (void)ws_size;
    const float* x        = (const float*)d_in[0];
    const float* text     = (const float*)d_in[1];
    const float* gate_w1  = (const float*)d_in[2];
    const float* gate_b1  = (const float*)d_in[3];
    const float* gate_w2  = (const float*)d_in[4];
    const float* gate_b2  = (const float*)d_in[5];
    const float* fno_w1r  = (const float*)d_in[6];
    const float* fno_w1i  = (const float*)d_in[7];
    const float* fno_w2r  = (const float*)d_in[8];
    const float* fno_w2i  = (const float*)d_in[9];
    const float* fno_cw   = (const float*)d_in[10];
    const float* fno_cb   = (const float*)d_in[11];
    const float* mlp1_w1  = (const float*)d_in[12];
    const float* mlp1_b1  = (const float*)d_in[13];
    const float* mlp1_w2  = (const float*)d_in[14];
    const float* mlp1_b2  = (const float*)d_in[15];
    const float* mlp2_w1  = (const float*)d_in[16];
    const float* mlp2_b1  = (const float*)d_in[17];
    const float* mlp2_w2  = (const float*)d_in[18];
    const float* mlp2_b2  = (const float*)d_in[19];
    const float* ln1_g    = (const float*)d_in[20];
    const float* ln1_b    = (const float*)d_in[21];
    const float* qkv_w    = (const float*)d_in[22];
    const float* qkv_b    = (const float*)d_in[23];
    const float* out_w    = (const float*)d_in[24];
    const float* out_b    = (const float*)d_in[25];
    const float* ln2_g    = (const float*)d_in[26];
    const float* ln2_b    = (const float*)d_in[27];
    const float* wa_w1    = (const float*)d_in[28];
    const float* wa_b1    = (const float*)d_in[29];
    const float* wa_w2    = (const float*)d_in[30];
    const float* wa_b2    = (const float*)d_in[31];

    float* ws   = (float*)d_ws;
    float* feat = ws;                // 8192
    float* h1   = ws + 8192;         // 2048
    float* cwp  = ws + 10240;        // 32
    ushort* wbf = (ushort*)(ws + 16384);     // weight bf16 pool (<= 1M floats)
    ushort* w1aT = wbf;
    ushort* w2aT = w1aT + 262144;
    ushort* w1bT = w2aT + 262144;
    ushort* w2bT = w1bT + 262144;
    ushort* w1cT = w2bT + 262144;
    ushort* w2cT = w1cT + 262144;
    ushort* qkvT = w2cT + 262144;
    ushort* outwT = qkvT + 196608;
    ushort* convT = outwT + 65536;
    ushort* Xbf  = (ushort*)(ws + 16384 + 1048576);          // 8.39M ushorts
    float* slotA = ws + 16384 + 1048576 + 4194304;           // 8.39M floats (xg / abf)
    ushort* abf  = (ushort*)slotA;
    float* xft   = slotA + 8388608;                          // 2.1M
    float* oft   = xft + 2097152;                            // 2.1M
    float* regD  = oft + 2097152;                            // 8.39M (x2 / xattn)
    ushort* bigb = (ushort*)(regD + 8388608);                // qkv-bf16 / hidden-bf16
    // total: 43,008,000 floats = 172 MB

    float* outp = (float*)d_out;
    float* wout = outp + (size_t)NB * NN * DD;

    // gating
    k_gate_mean<<<8, 256, 0, stream>>>(x, text, feat);
    k_gate_mlp1<<<8, 256, 0, stream>>>(feat, gate_w1, gate_b1, h1);
    k_gate_top<<<1, 64, 0, stream>>>(h1, gate_w2, gate_b2, cwp, wout);

    // prep: bf16 conversions
    k_cvtbf<<<8192, 256, 0, stream>>>(x, Xbf);
    dim3 wtb(32, 8);
    k_wt<<<dim3(32, 8), wtb, 0, stream>>>(mlp1_w1, w1aT, 256, 1024);
    k_wt<<<dim3(8, 32), wtb, 0, stream>>>(mlp1_w2, w2aT, 1024, 256);
    k_wt<<<dim3(32, 8), wtb, 0, stream>>>(mlp2_w1, w1bT, 256, 1024);
    k_wt<<<dim3(8, 32), wtb, 0, stream>>>(mlp2_w2, w2bT, 1024, 256);
    k_wt<<<dim3(32, 8), wtb, 0, stream>>>(wa_w1, w1cT, 256, 1024);
    k_wt<<<dim3(8, 32), wtb, 0, stream>>>(wa_w2, w2cT, 1024, 256);
    k_wt<<<dim3(24, 8), wtb, 0, stream>>>(qkv_w, qkvT, 256, 768);
    k_wt<<<dim3(8, 8), wtb, 0, stream>>>(out_w, outwT, 256, 256);
    k_wt<<<dim3(8, 8), wtb, 0, stream>>>(fno_cw, convT, 256, 256);

    // expert 0: FNO (writes all of out with weight cw0)
    k_transpose<<<dim3(128, 8, 8), dim3(32, 8), 0, stream>>>(x, slotA);
    k_rfft2<<<2048, 64, 0, stream>>>(slotA, xft);
    k_gemm<2><<<dim3(256, 2), 256, 0, stream>>>(Xbf, convT, fno_cb, nullptr, regD, nullptr, nullptr, 0, 256, 256);
    k_spectral<<<dim3(8, 16, 2), 512, 0, stream>>>(xft, fno_w1r, fno_w1i, fno_w2r, fno_w2i, oft);
    k_irfft_fuse<<<2048, 64, 0, stream>>>(oft, regD, x, cwp, outp);

    // expert 1: MLP
    k_gemm<0><<<dim3(256, 8), 256, 0, stream>>>(Xbf, w1aT, mlp1_b1, nullptr, nullptr, bigb, nullptr, 0, 256, 1024);
    k_gemm<3><<<dim3(256, 2), 256, 0, stream>>>(bigb, w2aT, mlp1_b2, x, outp, nullptr, cwp, 1, 1024, 256);

    // expert 2: window attention
    k_ln<<<8192, 256, 0, stream>>>(x, ln1_g, ln1_b, abf);
    k_gemm<1><<<dim3(256, 6), 256, 0, stream>>>(abf, qkvT, qkv_b, nullptr, nullptr, bigb, nullptr, 0, 256, 768);
    k_window_attn<<<4096, 64, 0, stream>>>(bigb, abf);
    k_gemm<2><<<dim3(256, 2), 256, 0, stream>>>(abf, outwT, out_b, x, regD, nullptr, nullptr, 0, 256, 256);
    k_ln<<<8192, 256, 0, stream>>>(regD, ln2_g, ln2_b, abf);
    k_gemm<0><<<dim3(256, 8), 256, 0, stream>>>(abf, w1cT, wa_b1, nullptr, nullptr, bigb, nullptr, 0, 256, 1024);
    k_gemm<3><<<dim3(256, 2), 256, 0, stream>>>(bigb, w2cT, wa_b2, regD, outp, nullptr, cwp, 2, 1024, 256);

    // expert 3: MLP
    k_gemm<0><<<dim3(256, 8), 256, 0, stream>>>(Xbf, w1bT, mlp2_b1, nullptr, nullptr, bigb, nullptr, 0, 256, 1024);
    k_gemm<3><<<dim3(256, 2), 256, 0, stream>>>(bigb, w2bT, mlp2_b2, x, outp, nullptr, cwp, 3, 1024, 256);
}

// Round 4
// 897.137 us; speedup vs baseline: 3.0264x; 1.3300x over previous
//
#include <hip/hip_runtime.h>
#include <math.h>

// MoEProcessor: B=8, N=4096, D=256, H=W=64, WS=8, NH=8, M=16, E=4, TD=768, HID=1024, TK=2
// Round 4: R3 structure with hardened buffer aliasing (gating scratch moved out of the
// FNO x2t/tmp dataflow; gate_mlp1 reverted to proven R2 version).

#define NB 8
#define NN 4096
#define DD 256

typedef __attribute__((ext_vector_type(8))) short bf16x8;
typedef __attribute__((ext_vector_type(4))) float f32x4;

__device__ __forceinline__ float gelu_f(float v) {
    return 0.5f * v * (1.0f + erff(v * 0.7071067811865475f));
}
__device__ __forceinline__ ushort f2bf(float f) {
    uint32_t u = __float_as_uint(f);
    uint32_t r = (u + 0x7fffu + ((u >> 16) & 1u)) >> 16;
    return (ushort)r;
}
__device__ __forceinline__ float b2f(ushort h) {
    return __uint_as_float(((uint32_t)h) << 16);
}

// ---------------- gating ----------------
// stage 1: partial sums over 128-row chunks
__global__ void k_gate_mean1(const float* __restrict__ x, float* __restrict__ partial) {
    int c = blockIdx.x, b = blockIdx.y;
    int t = threadIdx.x;
    const float* xb = x + ((size_t)b * NN + c * 128) * DD;
    float s = 0.f;
    for (int n = 0; n < 128; ++n) s += xb[(size_t)n * DD + t];
    partial[((size_t)b * 32 + c) * 256 + t] = s;
}
__global__ void k_gate_mean2(const float* __restrict__ partial, const float* __restrict__ text,
                             float* __restrict__ feat) {
    int b = blockIdx.x, t = threadIdx.x;
    float s = 0.f;
    for (int c = 0; c < 32; ++c) s += partial[((size_t)b * 32 + c) * 256 + t];
    feat[b * 1024 + t] = s * (1.0f / NN);
    for (int j = t; j < 768; j += 256) feat[b * 1024 + 256 + j] = text[b * 768 + j];
}

// proven R1/R2 version: one block per batch, w1 column reads are L2-resident
__global__ void k_gate_mlp1(const float* __restrict__ feat, const float* __restrict__ w1,
                            const float* __restrict__ b1, float* __restrict__ h1) {
    int b = blockIdx.x, j = threadIdx.x;
    float acc = b1[j];
    const float* f = feat + b * 1024;
    for (int k = 0; k < 1024; ++k) acc += f[k] * w1[k * 256 + j];
    h1[b * 256 + j] = fmaxf(acc, 0.f);
}

__global__ void k_gate_top(const float* __restrict__ h1, const float* __restrict__ w2,
                           const float* __restrict__ b2, float* __restrict__ cw,
                           float* __restrict__ wout) {
    __shared__ float lg[8][4];
    int t = threadIdx.x;
    if (t < 32) {
        int b = t >> 2, e = t & 3;
        float acc = b2[e];
        const float* h = h1 + b * 256;
        for (int k = 0; k < 256; ++k) acc += h[k] * w2[k * 4 + e];
        lg[b][e] = acc;
    }
    __syncthreads();
    if (t < 8) {
        int b = t;
        float v[4];
        #pragma unroll
        for (int e = 0; e < 4; ++e) v[e] = lg[b][e];
        int i0 = 0;
        #pragma unroll
        for (int e = 1; e < 4; ++e) if (v[e] > v[i0]) i0 = e;
        int i1 = -1;
        #pragma unroll
        for (int e = 0; e < 4; ++e) {
            if (e == i0) continue;
            if (i1 < 0 || v[e] > v[i1]) i1 = e;
        }
        float v0 = v[i0], v1 = v[i1];
        float e1v = expf(v1 - v0);
        float inv = 1.0f / (1.0f + e1v);
        float w0 = inv, w1v = e1v * inv;
        wout[b * 2 + 0] = w0;
        wout[b * 2 + 1] = w1v;
        float c[4] = {0.f, 0.f, 0.f, 0.f};
        c[i0] += w0; c[i1] += w1v;
        #pragma unroll
        for (int e = 0; e < 4; ++e) cw[b * 4 + e] = c[e];
    }
}

// ---------------- prep: f32 -> bf16 ----------------
__global__ void k_cvtbf(const float* __restrict__ src, ushort* __restrict__ dst) {
    int i = blockIdx.x * 256 + threadIdx.x;
    float4 v = ((const float4*)src)[i];
    ushort4 o;
    o.x = f2bf(v.x); o.y = f2bf(v.y); o.z = f2bf(v.z); o.w = f2bf(v.w);
    ((ushort4*)dst)[i] = o;
}

// transpose+convert: src f32 [K][N] -> dst bf16 [N][K]
__global__ void k_wt(const float* __restrict__ src, ushort* __restrict__ dst, int K, int N) {
    __shared__ float tile[32][33];
    int n0 = blockIdx.x * 32, k0 = blockIdx.y * 32;
    int tx = threadIdx.x, ty = threadIdx.y;
    #pragma unroll
    for (int i = 0; i < 4; ++i)
        tile[ty + i * 8][tx] = src[(size_t)(k0 + ty + i * 8) * N + n0 + tx];
    __syncthreads();
    #pragma unroll
    for (int i = 0; i < 4; ++i)
        dst[(size_t)(n0 + ty + i * 8) * K + k0 + tx] = f2bf(tile[tx][ty + i * 8]);
}

// ---------------- MFMA GEMM ----------------
// C[M,N] = A[M,K]bf16 @ Bt[N,K]bf16^T, 128x128 tile, BK=32, 4 waves (2x2), 4x4 frags.
// MODE 0: outb = bf16(gelu(acc+colbias))
// MODE 1: outb = bf16(acc+colbias)
// MODE 2: outf = acc+colbias (+res)
// MODE 3: outf += cw[b,eidx]*(acc+colbias+res)
// MODE 4: outf = acc+rowbias               (batched via blockIdx.z strides)
template<int MODE>
__global__ void __launch_bounds__(256) k_gemm(const ushort* __restrict__ A,
        const ushort* __restrict__ Bt, const float* __restrict__ bias,
        const float* __restrict__ res, float* __restrict__ outf,
        ushort* __restrict__ outb, const float* __restrict__ cw, int eidx,
        int K, int Ncols, size_t bsA, size_t bsB, size_t bsC) {
    __shared__ alignas(16) char smem[32768];
    ushort* sA = (ushort*)smem;            // [2][4096]
    ushort* sB = (ushort*)(smem + 16384);  // [2][4096]
    int z = blockIdx.z;
    A += z * bsA; Bt += z * bsB;
    if (outf) outf += z * bsC;
    int m0 = blockIdx.x * 128;
    int n0 = blockIdx.y * 128;
    int t = threadIdx.x;
    int lane = t & 63, wid = t >> 6;
    int wr = wid >> 1, wc = wid & 1;
    int rlo = lane & 15, khi = (lane >> 4) * 8;

    auto stage = [&](int buf, int k0) {
        const ushort* Ab = A + (size_t)m0 * K + k0;
        const ushort* Bb = Bt + (size_t)n0 * K + k0;
        #pragma unroll
        for (int h = 0; h < 2; ++h) {
            int s = t + h * 256;
            int row = s >> 2, kc = (s & 3) * 8;
            __builtin_amdgcn_global_load_lds(
                (const __attribute__((address_space(1))) void*)(Ab + (size_t)row * K + kc),
                (__attribute__((address_space(3))) void*)(sA + buf * 4096 + s * 8),
                16, 0, 0);
            __builtin_amdgcn_global_load_lds(
                (const __attribute__((address_space(1))) void*)(Bb + (size_t)row * K + kc),
                (__attribute__((address_space(3))) void*)(sB + buf * 4096 + s * 8),
                16, 0, 0);
        }
    };

    f32x4 acc[4][4];
    #pragma unroll
    for (int i = 0; i < 4; ++i)
        #pragma unroll
        for (int j = 0; j < 4; ++j) acc[i][j] = (f32x4){0.f, 0.f, 0.f, 0.f};

    int KT = K >> 5;
    stage(0, 0);
    int cur = 0;
    for (int kt = 0; kt < KT; ++kt) {
        __syncthreads();
        if (kt + 1 < KT) stage(cur ^ 1, (kt + 1) << 5);
        const ushort* Ap = sA + cur * 4096;
        const ushort* Bp = sB + cur * 4096;
        bf16x8 af[4], bfr[4];
        #pragma unroll
        for (int i = 0; i < 4; ++i) {
            af[i]  = *(const bf16x8*)(Ap + (wr * 64 + i * 16 + rlo) * 32 + khi);
            bfr[i] = *(const bf16x8*)(Bp + (wc * 64 + i * 16 + rlo) * 32 + khi);
        }
        #pragma unroll
        for (int i = 0; i < 4; ++i)
            #pragma unroll
            for (int j = 0; j < 4; ++j)
                acc[i][j] = __builtin_amdgcn_mfma_f32_16x16x32_bf16(af[i], bfr[j], acc[i][j], 0, 0, 0);
        cur ^= 1;
    }

    float bj4[4];
    if constexpr (MODE != 4) {
        #pragma unroll
        for (int nt = 0; nt < 4; ++nt) bj4[nt] = bias[n0 + wc * 64 + nt * 16 + rlo];
    }

    if constexpr (MODE == 0 || MODE == 1) {
        ushort* eb = (ushort*)smem;  // [32][136]
        #pragma unroll
        for (int mt = 0; mt < 4; ++mt) {
            __syncthreads();
            #pragma unroll
            for (int nt = 0; nt < 4; ++nt) {
                int col = wc * 64 + nt * 16 + rlo;
                #pragma unroll
                for (int j = 0; j < 4; ++j) {
                    float v = acc[mt][nt][j] + bj4[nt];
                    if (MODE == 0) v = gelu_f(v);
                    eb[(wr * 16 + (lane >> 4) * 4 + j) * 136 + col] = f2bf(v);
                }
            }
            __syncthreads();
            #pragma unroll
            for (int h = 0; h < 2; ++h) {
                int s = t + h * 256;
                int r = s >> 4, c = (s & 15) * 8;
                int grow = m0 + (r >> 4) * 64 + mt * 16 + (r & 15);
                *(uint4*)(outb + (size_t)grow * Ncols + n0 + c) = *(uint4*)&eb[r * 136 + c];
            }
        }
    } else {
        float* ep = (float*)smem;  // [32][132]
        #pragma unroll
        for (int mt = 0; mt < 4; ++mt) {
            __syncthreads();
            #pragma unroll
            for (int nt = 0; nt < 4; ++nt) {
                int col = wc * 64 + nt * 16 + rlo;
                #pragma unroll
                for (int j = 0; j < 4; ++j) {
                    float v = acc[mt][nt][j];
                    if constexpr (MODE == 4)
                        v += bias[m0 + wr * 64 + mt * 16 + (lane >> 4) * 4 + j];
                    else
                        v += bj4[nt];
                    ep[(wr * 16 + (lane >> 4) * 4 + j) * 132 + col] = v;
                }
            }
            __syncthreads();
            #pragma unroll
            for (int h = 0; h < 4; ++h) {
                int s = t + h * 256;
                int r = s >> 5, c4 = (s & 31) * 4;
                int grow = m0 + (r >> 4) * 64 + mt * 16 + (r & 15);
                size_t g = (size_t)grow * Ncols + n0 + c4;
                float4 v = *(float4*)&ep[r * 132 + c4];
                if constexpr (MODE == 2) {
                    if (res) {
                        float4 rv = *(const float4*)&res[g];
                        v.x += rv.x; v.y += rv.y; v.z += rv.z; v.w += rv.w;
                    }
                    *(float4*)&outf[g] = v;
                } else if constexpr (MODE == 4) {
                    *(float4*)&outf[g] = v;
                } else {
                    float cwv = cw[(grow >> 12) * 4 + eidx];
                    float4 rv = *(const float4*)&res[g];
                    float4 ov = *(float4*)&outf[g];
                    ov.x += cwv * (v.x + rv.x);
                    ov.y += cwv * (v.y + rv.y);
                    ov.z += cwv * (v.z + rv.z);
                    ov.w += cwv * (v.w + rv.w);
                    *(float4*)&outf[g] = ov;
                }
            }
        }
    }
}

// ---------------- FNO ----------------
__global__ void k_transpose(const float* __restrict__ x, float* __restrict__ xg) {
    __shared__ float tile[32][33];
    int b = blockIdx.z;
    int nt = blockIdx.x, dt = blockIdx.y;
    int tx = threadIdx.x, ty = threadIdx.y;
    const float* xb = x + (size_t)b * NN * DD;
    float* xgb = xg + (size_t)b * DD * NN;
    #pragma unroll
    for (int i = 0; i < 4; ++i) {
        int n = nt * 32 + ty + i * 8;
        tile[ty + i * 8][tx] = xb[(size_t)n * DD + dt * 32 + tx];
    }
    __syncthreads();
    #pragma unroll
    for (int i = 0; i < 4; ++i) {
        int d = dt * 32 + ty + i * 8;
        xgb[(size_t)d * NN + nt * 32 + tx] = tile[tx][ty + i * 8];
    }
}

__global__ void __launch_bounds__(64) k_rfft2(const float* __restrict__ xg, float* __restrict__ xft) {
    __shared__ float plane[64][65];
    __shared__ float s1[64][16][2];
    __shared__ float twc[64], tws[64];
    int p = blockIdx.x;
    int t = threadIdx.x;
    const float* src = xg + (size_t)p * 4096;
    for (int i = 0; i < 64; ++i) plane[i][t] = src[i * 64 + t];
    twc[t] = cosf((float)t * (6.283185307179586f / 64.0f));
    tws[t] = sinf((float)t * (6.283185307179586f / 64.0f));
    __syncthreads();
    int r = t;
    for (int kw = 0; kw < 16; ++kw) {
        float re = 0.f, im = 0.f;
        for (int w = 0; w < 64; ++w) {
            int j = (w * kw) & 63;
            float xv = plane[r][w];
            re += xv * twc[j];
            im -= xv * tws[j];
        }
        s1[r][kw][0] = re; s1[r][kw][1] = im;
    }
    __syncthreads();
    float2* dst = (float2*)xft + (size_t)p * 512;
    #pragma unroll
    for (int q = 0; q < 8; ++q) {
        int oi = t + q * 64;
        int krow = oi >> 4, kw = oi & 15;
        int kh = krow < 16 ? krow : krow + 32;
        float re = 0.f, im = 0.f;
        for (int h = 0; h < 64; ++h) {
            int j = (h * kh) & 63;
            float c = twc[j], s = tws[j];
            float ar = s1[h][kw][0], ai = s1[h][kw][1];
            re += ar * c + ai * s;
            im += ai * c - ar * s;
        }
        dst[oi] = make_float2(re, im);
    }
}

__global__ void __launch_bounds__(512) k_spectral(const float* __restrict__ xft,
        const float* __restrict__ w1r, const float* __restrict__ w1i,
        const float* __restrict__ w2r, const float* __restrict__ w2i,
        float* __restrict__ oft) {
    __shared__ float xf[8][32][16][2];
    int region = blockIdx.z;
    const float* wr = region ? w2r : w1r;
    const float* wi = region ? w2i : w1i;
    int xm = blockIdx.y;
    int krow = region * 16 + xm;
    int o0 = blockIdx.x * 32;
    int t = threadIdx.x;
    int y = t & 15, ol = t >> 4;
    int o = o0 + ol;
    float accr[8], acci[8];
    #pragma unroll
    for (int b = 0; b < 8; ++b) { accr[b] = 0.f; acci[b] = 0.f; }
    for (int i0 = 0; i0 < 256; i0 += 32) {
        __syncthreads();
        #pragma unroll
        for (int l = 0; l < 16; ++l) {
            int idx = t + l * 512;
            int c = idx & 1, yy = (idx >> 1) & 15, ic = (idx >> 5) & 31, b = idx >> 10;
            xf[b][ic][yy][c] = xft[(((size_t)b * 256 + i0 + ic) * 32 + krow) * 32 + yy * 2 + c];
        }
        __syncthreads();
        for (int ic = 0; ic < 32; ++ic) {
            int i = i0 + ic;
            size_t widx = (((size_t)i * 256 + o) * 16 + xm) * 16 + y;
            float wrv = wr[widx], wiv = wi[widx];
            #pragma unroll
            for (int b = 0; b < 8; ++b) {
                float ar = xf[b][ic][y][0], ai = xf[b][ic][y][1];
                accr[b] += ar * wrv - ai * wiv;
                acci[b] += ar * wiv + ai * wrv;
            }
        }
    }
    float2* dst = (float2*)oft;
    #pragma unroll
    for (int b = 0; b < 8; ++b)
        dst[(((size_t)b * 256 + o) * 32 + krow) * 16 + y] = make_float2(accr[b], acci[b]);
}

// irfft2 + gelu(x1 + conv-branch), all channel-major coalesced. tmp[p][hw]
__global__ void __launch_bounds__(64) k_irfft_fuse(const float* __restrict__ oft,
        const float* __restrict__ x2t, float* __restrict__ tmp) {
    __shared__ float F[32][16][2];
    __shared__ float tarr[64][16][2];
    __shared__ float twc[64], tws[64];
    int p = blockIdx.x;
    int t = threadIdx.x;
    const float2* src = (const float2*)oft + (size_t)p * 512;
    #pragma unroll
    for (int l = 0; l < 8; ++l) {
        int idx = t + l * 64;
        ((float2*)F)[idx] = src[idx];
    }
    twc[t] = cosf((float)t * (6.283185307179586f / 64.0f));
    tws[t] = sinf((float)t * (6.283185307179586f / 64.0f));
    __syncthreads();
    int h = t;
    for (int kw = 0; kw < 16; ++kw) {
        float re = 0.f, im = 0.f;
        #pragma unroll
        for (int krow = 0; krow < 32; ++krow) {
            int kh = krow < 16 ? krow : krow + 32;
            int j = (h * kh) & 63;
            float c = twc[j], s = tws[j];
            float fr = F[krow][kw][0], fi = F[krow][kw][1];
            re += fr * c - fi * s;
            im += fr * s + fi * c;
        }
        tarr[h][kw][0] = re * (1.f / 64.f);
        tarr[h][kw][1] = im * (1.f / 64.f);
    }
    __syncthreads();
    const float* x2p = x2t + (size_t)p * 4096;
    float* tp = tmp + (size_t)p * 4096;
    for (int q = 0; q < 64; ++q) {
        int w = t;
        float acc = tarr[q][0][0];
        #pragma unroll
        for (int kw = 1; kw < 16; ++kw) {
            int j = (w * kw) & 63;
            acc += 2.f * (tarr[q][kw][0] * twc[j] - tarr[q][kw][1] * tws[j]);
        }
        float x1 = acc * (1.f / 64.f);
        int idx = q * 64 + w;
        tp[idx] = gelu_f(x1 + x2p[idx]);
    }
}

// transpose tmp [b][d][n] -> out[b][n][d] = cw0*(tmp + x)
__global__ void k_fno_final(const float* __restrict__ tmp, const float* __restrict__ x,
        const float* __restrict__ cw, float* __restrict__ out) {
    __shared__ float tile[32][33];
    int b = blockIdx.z;
    int n0 = blockIdx.x * 32, d0 = blockIdx.y * 32;
    int tx = threadIdx.x, ty = threadIdx.y;
    const float* tb = tmp + (size_t)b * DD * NN;
    #pragma unroll
    for (int i = 0; i < 4; ++i)
        tile[ty + i * 8][tx] = tb[(size_t)(d0 + ty + i * 8) * NN + n0 + tx];
    __syncthreads();
    float cw0 = cw[b * 4];
    #pragma unroll
    for (int i = 0; i < 4; ++i) {
        int n = n0 + ty + i * 8, d = d0 + tx;
        size_t g = ((size_t)b * NN + n) * DD + d;
        out[g] = cw0 * (tile[tx][ty + i * 8] + x[g]);
    }
}

// ---------------- layernorm (f32 in, bf16 out) ----------------
__global__ void __launch_bounds__(256) k_ln(const float* __restrict__ in, const float* __restrict__ g,
        const float* __restrict__ be, ushort* __restrict__ outb) {
    int row = blockIdx.x * 4 + (threadIdx.x >> 6);
    int lane = threadIdx.x & 63;
    const float4* rp = (const float4*)(in + (size_t)row * 256);
    float4 v = rp[lane];
    float s = v.x + v.y + v.z + v.w;
    float s2 = v.x * v.x + v.y * v.y + v.z * v.z + v.w * v.w;
    #pragma unroll
    for (int off = 32; off > 0; off >>= 1) {
        s += __shfl_down(s, off);
        s2 += __shfl_down(s2, off);
    }
    s = __shfl(s, 0); s2 = __shfl(s2, 0);
    float mu = s * (1.f / 256.f);
    float var = s2 * (1.f / 256.f) - mu * mu;
    float rstd = rsqrtf(var + 1e-5f);
    float4 gv = ((const float4*)g)[lane];
    float4 bv = ((const float4*)be)[lane];
    ushort4 ov;
    ov.x = f2bf((v.x - mu) * rstd * gv.x + bv.x);
    ov.y = f2bf((v.y - mu) * rstd * gv.y + bv.y);
    ov.z = f2bf((v.z - mu) * rstd * gv.z + bv.z);
    ov.w = f2bf((v.w - mu) * rstd * gv.w + bv.w);
    ((ushort4*)(outb + (size_t)row * 256))[lane] = ov;
}

// ---------------- window attention core (bf16 in, bf16 out) ----------------
__global__ void __launch_bounds__(64) k_window_attn(const ushort* __restrict__ qkvb,
        ushort* __restrict__ aob) {
    __shared__ float ks[64][36], vs[64][36];
    __shared__ float ps[64][65];
    int wi = blockIdx.x >> 3;
    int hd = blockIdx.x & 7;
    int b = wi >> 6;
    int hb = (wi >> 3) & 7, wb = wi & 7;
    int t = threadIdx.x;
    for (int l2 = 0; l2 < 32; ++l2) {
        int idx = t + l2 * 64;
        int tok = idx >> 5, d = idx & 31;
        int n = (hb * 8 + (tok >> 3)) * 64 + wb * 8 + (tok & 7);
        size_t base = ((size_t)b * 4096 + n) * 768 + hd * 32 + d;
        ks[tok][d] = b2f(qkvb[base + 256]);
        vs[tok][d] = b2f(qkvb[base + 512]);
    }
    int l = t;
    int nq = (hb * 8 + (l >> 3)) * 64 + wb * 8 + (l & 7);
    const ushort4* qp = (const ushort4*)(qkvb + ((size_t)b * 4096 + nq) * 768 + hd * 32);
    float4 q[8];
    #pragma unroll
    for (int i = 0; i < 8; ++i) {
        ushort4 u = qp[i];
        q[i] = make_float4(b2f(u.x), b2f(u.y), b2f(u.z), b2f(u.w));
    }
    __syncthreads();
    const float scale = 0.17677669529663687f;
    float mx = -1e30f;
    for (int m = 0; m < 64; ++m) {
        const float4* kr = (const float4*)&ks[m][0];
        float a = 0.f;
        #pragma unroll
        for (int i = 0; i < 8; ++i) {
            float4 kv = kr[i];
            a += q[i].x * kv.x + q[i].y * kv.y + q[i].z * kv.z + q[i].w * kv.w;
        }
        a *= scale;
        ps[l][m] = a;
        mx = fmaxf(mx, a);
    }
    float ssum = 0.f;
    for (int m = 0; m < 64; ++m) {
        float p = expf(ps[l][m] - mx);
        ps[l][m] = p;
        ssum += p;
    }
    float inv = 1.f / ssum;
    float4 o[8];
    #pragma unroll
    for (int i = 0; i < 8; ++i) o[i] = make_float4(0.f, 0.f, 0.f, 0.f);
    for (int m = 0; m < 64; ++m) {
        float p = ps[l][m];
        const float4* vr = (const float4*)&vs[m][0];
        #pragma unroll
        for (int i = 0; i < 8; ++i) {
            float4 vv = vr[i];
            o[i].x += p * vv.x; o[i].y += p * vv.y; o[i].z += p * vv.z; o[i].w += p * vv.w;
        }
    }
    ushort* op = aob + ((size_t)b * 4096 + nq) * 256 + hd * 32;
    #pragma unroll
    for (int i = 0; i < 8; ++i) {
        ushort4 u;
        u.x = f2bf(o[i].x * inv); u.y = f2bf(o[i].y * inv);
        u.z = f2bf(o[i].z * inv); u.w = f2bf(o[i].w * inv);
        ((ushort4*)op)[i] = u;
    }
}

extern "C" void kernel_launch(void* const* d_in, const int* in_sizes, int n_in,
                              void* d_out, int out_size, void* d_ws, size_t ws_size,
                              hipStream_t stream) {
    (void)in_sizes; (void)n_in; (void)out_size; (void)ws_size;
    const float* x        = (const float*)d_in[0];
    const float* text     = (const float*)d_in[1];
    const float* gate_w1  = (const float*)d_in[2];
    const float* gate_b1  = (const float*)d_in[3];
    const float* gate_w2  = (const float*)d_in[4];
    const float* gate_b2  = (const float*)d_in[5];
    const float* fno_w1r  = (const float*)d_in[6];
    const float* fno_w1i  = (const float*)d_in[7];
    const float* fno_w2r  = (const float*)d_in[8];
    const float* fno_w2i  = (const float*)d_in[9];
    const float* fno_cw   = (const float*)d_in[10];
    const float* fno_cb   = (const float*)d_in[11];
    const float* mlp1_w1  = (const float*)d_in[12];
    const float* mlp1_b1  = (const float*)d_in[13];
    const float* mlp1_w2  = (const float*)d_in[14];
    const float* mlp1_b2  = (const float*)d_in[15];
    const float* mlp2_w1  = (const float*)d_in[16];
    const float* mlp2_b1  = (const float*)d_in[17];
    const float* mlp2_w2  = (const float*)d_in[18];
    const float* mlp2_b2  = (const float*)d_in[19];
    const float* ln1_g    = (const float*)d_in[20];
    const float* ln1_b    = (const float*)d_in[21];
    const float* qkv_w    = (const float*)d_in[22];
    const float* qkv_b    = (const float*)d_in[23];
    const float* out_w    = (const float*)d_in[24];
    const float* out_b    = (const float*)d_in[25];
    const float* ln2_g    = (const float*)d_in[26];
    const float* ln2_b    = (const float*)d_in[27];
    const float* wa_w1    = (const float*)d_in[28];
    const float* wa_b1    = (const float*)d_in[29];
    const float* wa_w2    = (const float*)d_in[30];
    const float* wa_b2    = (const float*)d_in[31];

    float* ws   = (float*)d_ws;
    float* feat = ws;                // 8192
    float* h1   = ws + 8192;         // 2048
    float* cwp  = ws + 10240;        // 32
    ushort* wbf = (ushort*)(ws + 16384);     // weight bf16 pool
    ushort* w1aT = wbf;
    ushort* w2aT = w1aT + 262144;
    ushort* w1bT = w2aT + 262144;
    ushort* w2bT = w1bT + 262144;
    ushort* w1cT = w2bT + 262144;
    ushort* w2cT = w1cT + 262144;
    ushort* qkvT = w2cT + 262144;
    ushort* outwT = qkvT + 196608;
    ushort* convT = outwT + 65536;
    ushort* Xbf  = (ushort*)(ws + 16384 + 1048576);          // bf16 x
    float* slotA = ws + 16384 + 1048576 + 4194304;           // 8.39M floats (xg / tmp / abf)
    ushort* abf  = (ushort*)slotA;
    float* xft   = slotA + 8388608;                          // 2.1M
    float* oft   = xft + 2097152;                            // 2.1M (also gate partials, pre-FNO)
    float* regD  = oft + 2097152;                            // 8.39M (x2t / xattn)
    ushort* bigb = (ushort*)(regD + 8388608);                // qkv-bf16 / hidden-bf16
    float* gpart = oft;   // gating partial sums live in oft region (written later by spectral)

    float* outp = (float*)d_out;
    float* wout = outp + (size_t)NB * NN * DD;

    // gating
    k_gate_mean1<<<dim3(32, 8), 256, 0, stream>>>(x, gpart);
    k_gate_mean2<<<8, 256, 0, stream>>>(gpart, text, feat);
    k_gate_mlp1<<<8, 256, 0, stream>>>(feat, gate_w1, gate_b1, h1);
    k_gate_top<<<1, 64, 0, stream>>>(h1, gate_w2, gate_b2, cwp, wout);

    // prep: bf16 conversions
    k_cvtbf<<<8192, 256, 0, stream>>>(x, Xbf);
    dim3 wtb(32, 8);
    k_wt<<<dim3(32, 8), wtb, 0, stream>>>(mlp1_w1, w1aT, 256, 1024);
    k_wt<<<dim3(8, 32), wtb, 0, stream>>>(mlp1_w2, w2aT, 1024, 256);
    k_wt<<<dim3(32, 8), wtb, 0, stream>>>(mlp2_w1, w1bT, 256, 1024);
    k_wt<<<dim3(8, 32), wtb, 0, stream>>>(mlp2_w2, w2bT, 1024, 256);
    k_wt<<<dim3(32, 8), wtb, 0, stream>>>(wa_w1, w1cT, 256, 1024);
    k_wt<<<dim3(8, 32), wtb, 0, stream>>>(wa_w2, w2cT, 1024, 256);
    k_wt<<<dim3(24, 8), wtb, 0, stream>>>(qkv_w, qkvT, 256, 768);
    k_wt<<<dim3(8, 8), wtb, 0, stream>>>(out_w, outwT, 256, 256);
    k_wt<<<dim3(8, 8), wtb, 0, stream>>>(fno_cw, convT, 256, 256);

    // expert 0: FNO (channel-major pipeline; final kernel writes all of out)
    k_transpose<<<dim3(128, 8, 8), dim3(32, 8), 0, stream>>>(x, slotA);
    k_rfft2<<<2048, 64, 0, stream>>>(slotA, xft);
    // conv branch, transposed output x2t[b][o][n]: A=convT [o][d], Bt=Xbf[b] [n][d]
    k_gemm<4><<<dim3(2, 32, 8), 256, 0, stream>>>(convT, Xbf, fno_cb, nullptr, regD, nullptr,
        nullptr, 0, 256, 4096, 0, (size_t)NN * DD, (size_t)DD * NN);
    k_spectral<<<dim3(8, 16, 2), 512, 0, stream>>>(xft, fno_w1r, fno_w1i, fno_w2r, fno_w2i, oft);
    k_irfft_fuse<<<2048, 64, 0, stream>>>(oft, regD, slotA);
    k_fno_final<<<dim3(128, 8, 8), dim3(32, 8), 0, stream>>>(slotA, x, cwp, outp);

    // expert 1: MLP
    k_gemm<0><<<dim3(256, 8), 256, 0, stream>>>(Xbf, w1aT, mlp1_b1, nullptr, nullptr, bigb, nullptr, 0, 256, 1024, 0, 0, 0);
    k_gemm<3><<<dim3(256, 2), 256, 0, stream>>>(bigb, w2aT, mlp1_b2, x, outp, nullptr, cwp, 1, 1024, 256, 0, 0, 0);

    // expert 2: window attention
    k_ln<<<8192, 256, 0, stream>>>(x, ln1_g, ln1_b, abf);
    k_gemm<1><<<dim3(256, 6), 256, 0, stream>>>(abf, qkvT, qkv_b, nullptr, nullptr, bigb, nullptr, 0, 256, 768, 0, 0, 0);
    k_window_attn<<<4096, 64, 0, stream>>>(bigb, abf);
    k_gemm<2><<<dim3(256, 2), 256, 0, stream>>>(abf, outwT, out_b, x, regD, nullptr, nullptr, 0, 256, 256, 0, 0, 0);
    k_ln<<<8192, 256, 0, stream>>>(regD, ln2_g, ln2_b, abf);
    k_gemm<0><<<dim3(256, 8), 256, 0, stream>>>(abf, w1cT, wa_b1, nullptr, nullptr, bigb, nullptr, 0, 256, 1024, 0, 0, 0);
    k_gemm<3><<<dim3(256, 2), 256, 0, stream>>>(bigb, w2cT, wa_b2, regD, outp, nullptr, cwp, 2, 1024, 256, 0, 0, 0);

    // expert 3: MLP
    k_gemm<0><<<dim3(256, 8), 256, 0, stream>>>(Xbf, w1bT, mlp2_b1, nullptr, nullptr, bigb, nullptr, 0, 256, 1024, 0, 0, 0);
    k_gemm<3><<<dim3(256, 2), 256, 0, stream>>>(bigb, w2bT, mlp2_b2, x, outp, nullptr, cwp, 3, 1024, 256, 0, 0, 0);
}

// Round 5
// 787.975 us; speedup vs baseline: 3.4457x; 1.1385x over previous
//
#include <hip/hip_runtime.h>
#include <math.h>

// MoEProcessor: B=8, N=4096, D=256, H=W=64, WS=8, NH=8, M=16, E=4, TD=768, HID=1024, TK=2
// Round 5: k_spectral rewritten for bandwidth: i-split x4 (1024 blocks, 32 waves/CU)
// + 4-deep hoisted weight loads; partials reduced by k_red4. Rest identical to R4.

#define NB 8
#define NN 4096
#define DD 256

typedef __attribute__((ext_vector_type(8))) short bf16x8;
typedef __attribute__((ext_vector_type(4))) float f32x4;

__device__ __forceinline__ float gelu_f(float v) {
    return 0.5f * v * (1.0f + erff(v * 0.7071067811865475f));
}
__device__ __forceinline__ ushort f2bf(float f) {
    uint32_t u = __float_as_uint(f);
    uint32_t r = (u + 0x7fffu + ((u >> 16) & 1u)) >> 16;
    return (ushort)r;
}
__device__ __forceinline__ float b2f(ushort h) {
    return __uint_as_float(((uint32_t)h) << 16);
}

// ---------------- gating ----------------
__global__ void k_gate_mean1(const float* __restrict__ x, float* __restrict__ partial) {
    int c = blockIdx.x, b = blockIdx.y;
    int t = threadIdx.x;
    const float* xb = x + ((size_t)b * NN + c * 128) * DD;
    float s = 0.f;
    for (int n = 0; n < 128; ++n) s += xb[(size_t)n * DD + t];
    partial[((size_t)b * 32 + c) * 256 + t] = s;
}
__global__ void k_gate_mean2(const float* __restrict__ partial, const float* __restrict__ text,
                             float* __restrict__ feat) {
    int b = blockIdx.x, t = threadIdx.x;
    float s = 0.f;
    for (int c = 0; c < 32; ++c) s += partial[((size_t)b * 32 + c) * 256 + t];
    feat[b * 1024 + t] = s * (1.0f / NN);
    for (int j = t; j < 768; j += 256) feat[b * 1024 + 256 + j] = text[b * 768 + j];
}

__global__ void k_gate_mlp1(const float* __restrict__ feat, const float* __restrict__ w1,
                            const float* __restrict__ b1, float* __restrict__ h1) {
    int b = blockIdx.x, j = threadIdx.x;
    float acc = b1[j];
    const float* f = feat + b * 1024;
    for (int k = 0; k < 1024; ++k) acc += f[k] * w1[k * 256 + j];
    h1[b * 256 + j] = fmaxf(acc, 0.f);
}

__global__ void k_gate_top(const float* __restrict__ h1, const float* __restrict__ w2,
                           const float* __restrict__ b2, float* __restrict__ cw,
                           float* __restrict__ wout) {
    __shared__ float lg[8][4];
    int t = threadIdx.x;
    if (t < 32) {
        int b = t >> 2, e = t & 3;
        float acc = b2[e];
        const float* h = h1 + b * 256;
        for (int k = 0; k < 256; ++k) acc += h[k] * w2[k * 4 + e];
        lg[b][e] = acc;
    }
    __syncthreads();
    if (t < 8) {
        int b = t;
        float v[4];
        #pragma unroll
        for (int e = 0; e < 4; ++e) v[e] = lg[b][e];
        int i0 = 0;
        #pragma unroll
        for (int e = 1; e < 4; ++e) if (v[e] > v[i0]) i0 = e;
        int i1 = -1;
        #pragma unroll
        for (int e = 0; e < 4; ++e) {
            if (e == i0) continue;
            if (i1 < 0 || v[e] > v[i1]) i1 = e;
        }
        float v0 = v[i0], v1 = v[i1];
        float e1v = expf(v1 - v0);
        float inv = 1.0f / (1.0f + e1v);
        float w0 = inv, w1v = e1v * inv;
        wout[b * 2 + 0] = w0;
        wout[b * 2 + 1] = w1v;
        float c[4] = {0.f, 0.f, 0.f, 0.f};
        c[i0] += w0; c[i1] += w1v;
        #pragma unroll
        for (int e = 0; e < 4; ++e) cw[b * 4 + e] = c[e];
    }
}

// ---------------- prep: f32 -> bf16 ----------------
__global__ void k_cvtbf(const float* __restrict__ src, ushort* __restrict__ dst) {
    int i = blockIdx.x * 256 + threadIdx.x;
    float4 v = ((const float4*)src)[i];
    ushort4 o;
    o.x = f2bf(v.x); o.y = f2bf(v.y); o.z = f2bf(v.z); o.w = f2bf(v.w);
    ((ushort4*)dst)[i] = o;
}

// transpose+convert: src f32 [K][N] -> dst bf16 [N][K]
__global__ void k_wt(const float* __restrict__ src, ushort* __restrict__ dst, int K, int N) {
    __shared__ float tile[32][33];
    int n0 = blockIdx.x * 32, k0 = blockIdx.y * 32;
    int tx = threadIdx.x, ty = threadIdx.y;
    #pragma unroll
    for (int i = 0; i < 4; ++i)
        tile[ty + i * 8][tx] = src[(size_t)(k0 + ty + i * 8) * N + n0 + tx];
    __syncthreads();
    #pragma unroll
    for (int i = 0; i < 4; ++i)
        dst[(size_t)(n0 + ty + i * 8) * K + k0 + tx] = f2bf(tile[tx][ty + i * 8]);
}

// ---------------- MFMA GEMM ----------------
template<int MODE>
__global__ void __launch_bounds__(256) k_gemm(const ushort* __restrict__ A,
        const ushort* __restrict__ Bt, const float* __restrict__ bias,
        const float* __restrict__ res, float* __restrict__ outf,
        ushort* __restrict__ outb, const float* __restrict__ cw, int eidx,
        int K, int Ncols, size_t bsA, size_t bsB, size_t bsC) {
    __shared__ alignas(16) char smem[32768];
    ushort* sA = (ushort*)smem;            // [2][4096]
    ushort* sB = (ushort*)(smem + 16384);  // [2][4096]
    int z = blockIdx.z;
    A += z * bsA; Bt += z * bsB;
    if (outf) outf += z * bsC;
    int m0 = blockIdx.x * 128;
    int n0 = blockIdx.y * 128;
    int t = threadIdx.x;
    int lane = t & 63, wid = t >> 6;
    int wr = wid >> 1, wc = wid & 1;
    int rlo = lane & 15, khi = (lane >> 4) * 8;

    auto stage = [&](int buf, int k0) {
        const ushort* Ab = A + (size_t)m0 * K + k0;
        const ushort* Bb = Bt + (size_t)n0 * K + k0;
        #pragma unroll
        for (int h = 0; h < 2; ++h) {
            int s = t + h * 256;
            int row = s >> 2, kc = (s & 3) * 8;
            __builtin_amdgcn_global_load_lds(
                (const __attribute__((address_space(1))) void*)(Ab + (size_t)row * K + kc),
                (__attribute__((address_space(3))) void*)(sA + buf * 4096 + s * 8),
                16, 0, 0);
            __builtin_amdgcn_global_load_lds(
                (const __attribute__((address_space(1))) void*)(Bb + (size_t)row * K + kc),
                (__attribute__((address_space(3))) void*)(sB + buf * 4096 + s * 8),
                16, 0, 0);
        }
    };

    f32x4 acc[4][4];
    #pragma unroll
    for (int i = 0; i < 4; ++i)
        #pragma unroll
        for (int j = 0; j < 4; ++j) acc[i][j] = (f32x4){0.f, 0.f, 0.f, 0.f};

    int KT = K >> 5;
    stage(0, 0);
    int cur = 0;
    for (int kt = 0; kt < KT; ++kt) {
        __syncthreads();
        if (kt + 1 < KT) stage(cur ^ 1, (kt + 1) << 5);
        const ushort* Ap = sA + cur * 4096;
        const ushort* Bp = sB + cur * 4096;
        bf16x8 af[4], bfr[4];
        #pragma unroll
        for (int i = 0; i < 4; ++i) {
            af[i]  = *(const bf16x8*)(Ap + (wr * 64 + i * 16 + rlo) * 32 + khi);
            bfr[i] = *(const bf16x8*)(Bp + (wc * 64 + i * 16 + rlo) * 32 + khi);
        }
        #pragma unroll
        for (int i = 0; i < 4; ++i)
            #pragma unroll
            for (int j = 0; j < 4; ++j)
                acc[i][j] = __builtin_amdgcn_mfma_f32_16x16x32_bf16(af[i], bfr[j], acc[i][j], 0, 0, 0);
        cur ^= 1;
    }

    float bj4[4];
    if constexpr (MODE != 4) {
        #pragma unroll
        for (int nt = 0; nt < 4; ++nt) bj4[nt] = bias[n0 + wc * 64 + nt * 16 + rlo];
    }

    if constexpr (MODE == 0 || MODE == 1) {
        ushort* eb = (ushort*)smem;  // [32][136]
        #pragma unroll
        for (int mt = 0; mt < 4; ++mt) {
            __syncthreads();
            #pragma unroll
            for (int nt = 0; nt < 4; ++nt) {
                int col = wc * 64 + nt * 16 + rlo;
                #pragma unroll
                for (int j = 0; j < 4; ++j) {
                    float v = acc[mt][nt][j] + bj4[nt];
                    if (MODE == 0) v = gelu_f(v);
                    eb[(wr * 16 + (lane >> 4) * 4 + j) * 136 + col] = f2bf(v);
                }
            }
            __syncthreads();
            #pragma unroll
            for (int h = 0; h < 2; ++h) {
                int s = t + h * 256;
                int r = s >> 4, c = (s & 15) * 8;
                int grow = m0 + (r >> 4) * 64 + mt * 16 + (r & 15);
                *(uint4*)(outb + (size_t)grow * Ncols + n0 + c) = *(uint4*)&eb[r * 136 + c];
            }
        }
    } else {
        float* ep = (float*)smem;  // [32][132]
        #pragma unroll
        for (int mt = 0; mt < 4; ++mt) {
            __syncthreads();
            #pragma unroll
            for (int nt = 0; nt < 4; ++nt) {
                int col = wc * 64 + nt * 16 + rlo;
                #pragma unroll
                for (int j = 0; j < 4; ++j) {
                    float v = acc[mt][nt][j];
                    if constexpr (MODE == 4)
                        v += bias[m0 + wr * 64 + mt * 16 + (lane >> 4) * 4 + j];
                    else
                        v += bj4[nt];
                    ep[(wr * 16 + (lane >> 4) * 4 + j) * 132 + col] = v;
                }
            }
            __syncthreads();
            #pragma unroll
            for (int h = 0; h < 4; ++h) {
                int s = t + h * 256;
                int r = s >> 5, c4 = (s & 31) * 4;
                int grow = m0 + (r >> 4) * 64 + mt * 16 + (r & 15);
                size_t g = (size_t)grow * Ncols + n0 + c4;
                float4 v = *(float4*)&ep[r * 132 + c4];
                if constexpr (MODE == 2) {
                    if (res) {
                        float4 rv = *(const float4*)&res[g];
                        v.x += rv.x; v.y += rv.y; v.z += rv.z; v.w += rv.w;
                    }
                    *(float4*)&outf[g] = v;
                } else if constexpr (MODE == 4) {
                    *(float4*)&outf[g] = v;
                } else {
                    float cwv = cw[(grow >> 12) * 4 + eidx];
                    float4 rv = *(const float4*)&res[g];
                    float4 ov = *(float4*)&outf[g];
                    ov.x += cwv * (v.x + rv.x);
                    ov.y += cwv * (v.y + rv.y);
                    ov.z += cwv * (v.z + rv.z);
                    ov.w += cwv * (v.w + rv.w);
                    *(float4*)&outf[g] = ov;
                }
            }
        }
    }
}

// ---------------- FNO ----------------
__global__ void k_transpose(const float* __restrict__ x, float* __restrict__ xg) {
    __shared__ float tile[32][33];
    int b = blockIdx.z;
    int nt = blockIdx.x, dt = blockIdx.y;
    int tx = threadIdx.x, ty = threadIdx.y;
    const float* xb = x + (size_t)b * NN * DD;
    float* xgb = xg + (size_t)b * DD * NN;
    #pragma unroll
    for (int i = 0; i < 4; ++i) {
        int n = nt * 32 + ty + i * 8;
        tile[ty + i * 8][tx] = xb[(size_t)n * DD + dt * 32 + tx];
    }
    __syncthreads();
    #pragma unroll
    for (int i = 0; i < 4; ++i) {
        int d = dt * 32 + ty + i * 8;
        xgb[(size_t)d * NN + nt * 32 + tx] = tile[tx][ty + i * 8];
    }
}

__global__ void __launch_bounds__(64) k_rfft2(const float* __restrict__ xg, float* __restrict__ xft) {
    __shared__ float plane[64][65];
    __shared__ float s1[64][16][2];
    __shared__ float twc[64], tws[64];
    int p = blockIdx.x;
    int t = threadIdx.x;
    const float* src = xg + (size_t)p * 4096;
    for (int i = 0; i < 64; ++i) plane[i][t] = src[i * 64 + t];
    twc[t] = cosf((float)t * (6.283185307179586f / 64.0f));
    tws[t] = sinf((float)t * (6.283185307179586f / 64.0f));
    __syncthreads();
    int r = t;
    for (int kw = 0; kw < 16; ++kw) {
        float re = 0.f, im = 0.f;
        for (int w = 0; w < 64; ++w) {
            int j = (w * kw) & 63;
            float xv = plane[r][w];
            re += xv * twc[j];
            im -= xv * tws[j];
        }
        s1[r][kw][0] = re; s1[r][kw][1] = im;
    }
    __syncthreads();
    float2* dst = (float2*)xft + (size_t)p * 512;
    #pragma unroll
    for (int q = 0; q < 8; ++q) {
        int oi = t + q * 64;
        int krow = oi >> 4, kw = oi & 15;
        int kh = krow < 16 ? krow : krow + 32;
        float re = 0.f, im = 0.f;
        for (int h = 0; h < 64; ++h) {
            int j = (h * kh) & 63;
            float c = twc[j], s = tws[j];
            float ar = s1[h][kw][0], ai = s1[h][kw][1];
            re += ar * c + ai * s;
            im += ai * c - ar * s;
        }
        dst[oi] = make_float2(re, im);
    }
}

// spectral contraction, i-split x4: part[is][b][o][krow][y] = sum_{i in chunk} xft*w
__global__ void __launch_bounds__(512) k_spectral(const float* __restrict__ xft,
        const float* __restrict__ w1r, const float* __restrict__ w1i,
        const float* __restrict__ w2r, const float* __restrict__ w2i,
        float* __restrict__ part) {
    __shared__ float xf[8][32][16][2];  // 32 KB
    int z = blockIdx.z;                 // 0..7
    int region = z >> 2, is = z & 3;
    const float* wr = region ? w2r : w1r;
    const float* wi = region ? w2i : w1i;
    int xm = blockIdx.y;
    int krow = region * 16 + xm;
    int o0 = blockIdx.x * 32;
    int t = threadIdx.x;
    int y = t & 15, ol = t >> 4;
    int o = o0 + ol;
    float accr[8], acci[8];
    #pragma unroll
    for (int b = 0; b < 8; ++b) { accr[b] = 0.f; acci[b] = 0.f; }
    int ibase = is * 64;
    for (int i0 = ibase; i0 < ibase + 64; i0 += 32) {
        __syncthreads();
        #pragma unroll
        for (int l = 0; l < 16; ++l) {
            int idx = t + l * 512;
            int c = idx & 1, yy = (idx >> 1) & 15, ic = (idx >> 5) & 31, b = idx >> 10;
            xf[b][ic][yy][c] = xft[(((size_t)b * 256 + i0 + ic) * 32 + krow) * 32 + yy * 2 + c];
        }
        __syncthreads();
        size_t wbase = (((size_t)i0 * 256 + o) * 16 + xm) * 16 + y;
        for (int ic4 = 0; ic4 < 32; ic4 += 4) {
            float wrv[4], wiv[4];
            #pragma unroll
            for (int u = 0; u < 4; ++u) {
                size_t widx = wbase + (size_t)(ic4 + u) * 65536;
                wrv[u] = wr[widx];
                wiv[u] = wi[widx];
            }
            #pragma unroll
            for (int u = 0; u < 4; ++u) {
                int ic = ic4 + u;
                #pragma unroll
                for (int b = 0; b < 8; ++b) {
                    float ar = xf[b][ic][y][0], ai = xf[b][ic][y][1];
                    accr[b] += ar * wrv[u] - ai * wiv[u];
                    acci[b] += ar * wiv[u] + ai * wrv[u];
                }
            }
        }
    }
    float2* dst = (float2*)part + (size_t)is * 1048576;
    #pragma unroll
    for (int b = 0; b < 8; ++b)
        dst[(((size_t)b * 256 + o) * 32 + krow) * 16 + y] = make_float2(accr[b], acci[b]);
}

// reduce 4 partials -> oft
__global__ void k_red4(const float* __restrict__ part, float* __restrict__ oft) {
    int i = blockIdx.x * 256 + threadIdx.x;
    const float4* p = (const float4*)part;
    float4 a = p[i];
    float4 b = p[i + 524288];
    float4 c = p[i + 1048576];
    float4 d = p[i + 1572864];
    float4 s;
    s.x = a.x + b.x + c.x + d.x;
    s.y = a.y + b.y + c.y + d.y;
    s.z = a.z + b.z + c.z + d.z;
    s.w = a.w + b.w + c.w + d.w;
    ((float4*)oft)[i] = s;
}

// irfft2 + gelu(x1 + conv-branch), all channel-major coalesced. tmp[p][hw]
__global__ void __launch_bounds__(64) k_irfft_fuse(const float* __restrict__ oft,
        const float* __restrict__ x2t, float* __restrict__ tmp) {
    __shared__ float F[32][16][2];
    __shared__ float tarr[64][16][2];
    __shared__ float twc[64], tws[64];
    int p = blockIdx.x;
    int t = threadIdx.x;
    const float2* src = (const float2*)oft + (size_t)p * 512;
    #pragma unroll
    for (int l = 0; l < 8; ++l) {
        int idx = t + l * 64;
        ((float2*)F)[idx] = src[idx];
    }
    twc[t] = cosf((float)t * (6.283185307179586f / 64.0f));
    tws[t] = sinf((float)t * (6.283185307179586f / 64.0f));
    __syncthreads();
    int h = t;
    for (int kw = 0; kw < 16; ++kw) {
        float re = 0.f, im = 0.f;
        #pragma unroll
        for (int krow = 0; krow < 32; ++krow) {
            int kh = krow < 16 ? krow : krow + 32;
            int j = (h * kh) & 63;
            float c = twc[j], s = tws[j];
            float fr = F[krow][kw][0], fi = F[krow][kw][1];
            re += fr * c - fi * s;
            im += fr * s + fi * c;
        }
        tarr[h][kw][0] = re * (1.f / 64.f);
        tarr[h][kw][1] = im * (1.f / 64.f);
    }
    __syncthreads();
    const float* x2p = x2t + (size_t)p * 4096;
    float* tp = tmp + (size_t)p * 4096;
    for (int q = 0; q < 64; ++q) {
        int w = t;
        float acc = tarr[q][0][0];
        #pragma unroll
        for (int kw = 1; kw < 16; ++kw) {
            int j = (w * kw) & 63;
            acc += 2.f * (tarr[q][kw][0] * twc[j] - tarr[q][kw][1] * tws[j]);
        }
        float x1 = acc * (1.f / 64.f);
        int idx = q * 64 + w;
        tp[idx] = gelu_f(x1 + x2p[idx]);
    }
}

// transpose tmp [b][d][n] -> out[b][n][d] = cw0*(tmp + x)
__global__ void k_fno_final(const float* __restrict__ tmp, const float* __restrict__ x,
        const float* __restrict__ cw, float* __restrict__ out) {
    __shared__ float tile[32][33];
    int b = blockIdx.z;
    int n0 = blockIdx.x * 32, d0 = blockIdx.y * 32;
    int tx = threadIdx.x, ty = threadIdx.y;
    const float* tb = tmp + (size_t)b * DD * NN;
    #pragma unroll
    for (int i = 0; i < 4; ++i)
        tile[ty + i * 8][tx] = tb[(size_t)(d0 + ty + i * 8) * NN + n0 + tx];
    __syncthreads();
    float cw0 = cw[b * 4];
    #pragma unroll
    for (int i = 0; i < 4; ++i) {
        int n = n0 + ty + i * 8, d = d0 + tx;
        size_t g = ((size_t)b * NN + n) * DD + d;
        out[g] = cw0 * (tile[tx][ty + i * 8] + x[g]);
    }
}

// ---------------- layernorm (f32 in, bf16 out) ----------------
__global__ void __launch_bounds__(256) k_ln(const float* __restrict__ in, const float* __restrict__ g,
        const float* __restrict__ be, ushort* __restrict__ outb) {
    int row = blockIdx.x * 4 + (threadIdx.x >> 6);
    int lane = threadIdx.x & 63;
    const float4* rp = (const float4*)(in + (size_t)row * 256);
    float4 v = rp[lane];
    float s = v.x + v.y + v.z + v.w;
    float s2 = v.x * v.x + v.y * v.y + v.z * v.z + v.w * v.w;
    #pragma unroll
    for (int off = 32; off > 0; off >>= 1) {
        s += __shfl_down(s, off);
        s2 += __shfl_down(s2, off);
    }
    s = __shfl(s, 0); s2 = __shfl(s2, 0);
    float mu = s * (1.f / 256.f);
    float var = s2 * (1.f / 256.f) - mu * mu;
    float rstd = rsqrtf(var + 1e-5f);
    float4 gv = ((const float4*)g)[lane];
    float4 bv = ((const float4*)be)[lane];
    ushort4 ov;
    ov.x = f2bf((v.x - mu) * rstd * gv.x + bv.x);
    ov.y = f2bf((v.y - mu) * rstd * gv.y + bv.y);
    ov.z = f2bf((v.z - mu) * rstd * gv.z + bv.z);
    ov.w = f2bf((v.w - mu) * rstd * gv.w + bv.w);
    ((ushort4*)(outb + (size_t)row * 256))[lane] = ov;
}

// ---------------- window attention core (bf16 in, bf16 out) ----------------
__global__ void __launch_bounds__(64) k_window_attn(const ushort* __restrict__ qkvb,
        ushort* __restrict__ aob) {
    __shared__ float ks[64][36], vs[64][36];
    __shared__ float ps[64][65];
    int wi = blockIdx.x >> 3;
    int hd = blockIdx.x & 7;
    int b = wi >> 6;
    int hb = (wi >> 3) & 7, wb = wi & 7;
    int t = threadIdx.x;
    for (int l2 = 0; l2 < 32; ++l2) {
        int idx = t + l2 * 64;
        int tok = idx >> 5, d = idx & 31;
        int n = (hb * 8 + (tok >> 3)) * 64 + wb * 8 + (tok & 7);
        size_t base = ((size_t)b * 4096 + n) * 768 + hd * 32 + d;
        ks[tok][d] = b2f(qkvb[base + 256]);
        vs[tok][d] = b2f(qkvb[base + 512]);
    }
    int l = t;
    int nq = (hb * 8 + (l >> 3)) * 64 + wb * 8 + (l & 7);
    const ushort4* qp = (const ushort4*)(qkvb + ((size_t)b * 4096 + nq) * 768 + hd * 32);
    float4 q[8];
    #pragma unroll
    for (int i = 0; i < 8; ++i) {
        ushort4 u = qp[i];
        q[i] = make_float4(b2f(u.x), b2f(u.y), b2f(u.z), b2f(u.w));
    }
    __syncthreads();
    const float scale = 0.17677669529663687f;
    float mx = -1e30f;
    for (int m = 0; m < 64; ++m) {
        const float4* kr = (const float4*)&ks[m][0];
        float a = 0.f;
        #pragma unroll
        for (int i = 0; i < 8; ++i) {
            float4 kv = kr[i];
            a += q[i].x * kv.x + q[i].y * kv.y + q[i].z * kv.z + q[i].w * kv.w;
        }
        a *= scale;
        ps[l][m] = a;
        mx = fmaxf(mx, a);
    }
    float ssum = 0.f;
    for (int m = 0; m < 64; ++m) {
        float p = expf(ps[l][m] - mx);
        ps[l][m] = p;
        ssum += p;
    }
    float inv = 1.f / ssum;
    float4 o[8];
    #pragma unroll
    for (int i = 0; i < 8; ++i) o[i] = make_float4(0.f, 0.f, 0.f, 0.f);
    for (int m = 0; m < 64; ++m) {
        float p = ps[l][m];
        const float4* vr = (const float4*)&vs[m][0];
        #pragma unroll
        for (int i = 0; i < 8; ++i) {
            float4 vv = vr[i];
            o[i].x += p * vv.x; o[i].y += p * vv.y; o[i].z += p * vv.z; o[i].w += p * vv.w;
        }
    }
    ushort* op = aob + ((size_t)b * 4096 + nq) * 256 + hd * 32;
    #pragma unroll
    for (int i = 0; i < 8; ++i) {
        ushort4 u;
        u.x = f2bf(o[i].x * inv); u.y = f2bf(o[i].y * inv);
        u.z = f2bf(o[i].z * inv); u.w = f2bf(o[i].w * inv);
        ((ushort4*)op)[i] = u;
    }
}

extern "C" void kernel_launch(void* const* d_in, const int* in_sizes, int n_in,
                              void* d_out, int out_size, void* d_ws, size_t ws_size,
                              hipStream_t stream) {
    (void)in_sizes; (void)n_in; (void)out_size; (void)ws_size;
    const float* x        = (const float*)d_in[0];
    const float* text     = (const float*)d_in[1];
    const float* gate_w1  = (const float*)d_in[2];
    const float* gate_b1  = (const float*)d_in[3];
    const float* gate_w2  = (const float*)d_in[4];
    const float* gate_b2  = (const float*)d_in[5];
    const float* fno_w1r  = (const float*)d_in[6];
    const float* fno_w1i  = (const float*)d_in[7];
    const float* fno_w2r  = (const float*)d_in[8];
    const float* fno_w2i  = (const float*)d_in[9];
    const float* fno_cw   = (const float*)d_in[10];
    const float* fno_cb   = (const float*)d_in[11];
    const float* mlp1_w1  = (const float*)d_in[12];
    const float* mlp1_b1  = (const float*)d_in[13];
    const float* mlp1_w2  = (const float*)d_in[14];
    const float* mlp1_b2  = (const float*)d_in[15];
    const float* mlp2_w1  = (const float*)d_in[16];
    const float* mlp2_b1  = (const float*)d_in[17];
    const float* mlp2_w2  = (const float*)d_in[18];
    const float* mlp2_b2  = (const float*)d_in[19];
    const float* ln1_g    = (const float*)d_in[20];
    const float* ln1_b    = (const float*)d_in[21];
    const float* qkv_w    = (const float*)d_in[22];
    const float* qkv_b    = (const float*)d_in[23];
    const float* out_w    = (const float*)d_in[24];
    const float* out_b    = (const float*)d_in[25];
    const float* ln2_g    = (const float*)d_in[26];
    const float* ln2_b    = (const float*)d_in[27];
    const float* wa_w1    = (const float*)d_in[28];
    const float* wa_b1    = (const float*)d_in[29];
    const float* wa_w2    = (const float*)d_in[30];
    const float* wa_b2    = (const float*)d_in[31];

    float* ws   = (float*)d_ws;
    float* feat = ws;                // 8192
    float* h1   = ws + 8192;         // 2048
    float* cwp  = ws + 10240;        // 32
    ushort* wbf = (ushort*)(ws + 16384);     // weight bf16 pool
    ushort* w1aT = wbf;
    ushort* w2aT = w1aT + 262144;
    ushort* w1bT = w2aT + 262144;
    ushort* w2bT = w1bT + 262144;
    ushort* w1cT = w2bT + 262144;
    ushort* w2cT = w1cT + 262144;
    ushort* qkvT = w2cT + 262144;
    ushort* outwT = qkvT + 196608;
    ushort* convT = outwT + 65536;
    ushort* Xbf  = (ushort*)(ws + 16384 + 1048576);          // bf16 x
    float* slotA = ws + 16384 + 1048576 + 4194304;           // 8.39M floats (xg / spectral-partials / tmp / abf)
    ushort* abf  = (ushort*)slotA;
    float* xft   = slotA + 8388608;                          // 2.1M
    float* oft   = xft + 2097152;                            // 2.1M (also gate partials, pre-FNO)
    float* regD  = oft + 2097152;                            // 8.39M (x2t / xattn)
    ushort* bigb = (ushort*)(regD + 8388608);                // qkv-bf16 / hidden-bf16
    float* gpart = oft;   // gating partial sums live in oft region (written later by reduce)

    float* outp = (float*)d_out;
    float* wout = outp + (size_t)NB * NN * DD;

    // gating
    k_gate_mean1<<<dim3(32, 8), 256, 0, stream>>>(x, gpart);
    k_gate_mean2<<<8, 256, 0, stream>>>(gpart, text, feat);
    k_gate_mlp1<<<8, 256, 0, stream>>>(feat, gate_w1, gate_b1, h1);
    k_gate_top<<<1, 64, 0, stream>>>(h1, gate_w2, gate_b2, cwp, wout);

    // prep: bf16 conversions
    k_cvtbf<<<8192, 256, 0, stream>>>(x, Xbf);
    dim3 wtb(32, 8);
    k_wt<<<dim3(32, 8), wtb, 0, stream>>>(mlp1_w1, w1aT, 256, 1024);
    k_wt<<<dim3(8, 32), wtb, 0, stream>>>(mlp1_w2, w2aT, 1024, 256);
    k_wt<<<dim3(32, 8), wtb, 0, stream>>>(mlp2_w1, w1bT, 256, 1024);
    k_wt<<<dim3(8, 32), wtb, 0, stream>>>(mlp2_w2, w2bT, 1024, 256);
    k_wt<<<dim3(32, 8), wtb, 0, stream>>>(wa_w1, w1cT, 256, 1024);
    k_wt<<<dim3(8, 32), wtb, 0, stream>>>(wa_w2, w2cT, 1024, 256);
    k_wt<<<dim3(24, 8), wtb, 0, stream>>>(qkv_w, qkvT, 256, 768);
    k_wt<<<dim3(8, 8), wtb, 0, stream>>>(out_w, outwT, 256, 256);
    k_wt<<<dim3(8, 8), wtb, 0, stream>>>(fno_cw, convT, 256, 256);

    // expert 0: FNO (channel-major pipeline; final kernel writes all of out)
    k_transpose<<<dim3(128, 8, 8), dim3(32, 8), 0, stream>>>(x, slotA);
    k_rfft2<<<2048, 64, 0, stream>>>(slotA, xft);
    // conv branch, transposed output x2t[b][o][n]: A=convT [o][d], Bt=Xbf[b] [n][d]
    k_gemm<4><<<dim3(2, 32, 8), 256, 0, stream>>>(convT, Xbf, fno_cb, nullptr, regD, nullptr,
        nullptr, 0, 256, 4096, 0, (size_t)NN * DD, (size_t)DD * NN);
    // spectral: partials into slotA (xg dead after rfft2), then reduce to oft
    k_spectral<<<dim3(8, 16, 8), 512, 0, stream>>>(xft, fno_w1r, fno_w1i, fno_w2r, fno_w2i, slotA);
    k_red4<<<2048, 256, 0, stream>>>(slotA, oft);
    k_irfft_fuse<<<2048, 64, 0, stream>>>(oft, regD, slotA);
    k_fno_final<<<dim3(128, 8, 8), dim3(32, 8), 0, stream>>>(slotA, x, cwp, outp);

    // expert 1: MLP
    k_gemm<0><<<dim3(256, 8), 256, 0, stream>>>(Xbf, w1aT, mlp1_b1, nullptr, nullptr, bigb, nullptr, 0, 256, 1024, 0, 0, 0);
    k_gemm<3><<<dim3(256, 2), 256, 0, stream>>>(bigb, w2aT, mlp1_b2, x, outp, nullptr, cwp, 1, 1024, 256, 0, 0, 0);

    // expert 2: window attention
    k_ln<<<8192, 256, 0, stream>>>(x, ln1_g, ln1_b, abf);
    k_gemm<1><<<dim3(256, 6), 256, 0, stream>>>(abf, qkvT, qkv_b, nullptr, nullptr, bigb, nullptr, 0, 256, 768, 0, 0, 0);
    k_window_attn<<<4096, 64, 0, stream>>>(bigb, abf);
    k_gemm<2><<<dim3(256, 2), 256, 0, stream>>>(abf, outwT, out_b, x, regD, nullptr, nullptr, 0, 256, 256, 0, 0, 0);
    k_ln<<<8192, 256, 0, stream>>>(regD, ln2_g, ln2_b, abf);
    k_gemm<0><<<dim3(256, 8), 256, 0, stream>>>(abf, w1cT, wa_b1, nullptr, nullptr, bigb, nullptr, 0, 256, 1024, 0, 0, 0);
    k_gemm<3><<<dim3(256, 2), 256, 0, stream>>>(bigb, w2cT, wa_b2, regD, outp, nullptr, cwp, 2, 1024, 256, 0, 0, 0);

    // expert 3: MLP
    k_gemm<0><<<dim3(256, 8), 256, 0, stream>>>(Xbf, w1bT, mlp2_b1, nullptr, nullptr, bigb, nullptr, 0, 256, 1024, 0, 0, 0);
    k_gemm<3><<<dim3(256, 2), 256, 0, stream>>>(bigb, w2bT, mlp2_b2, x, outp, nullptr, cwp, 3, 1024, 256, 0, 0, 0);
}

// Round 6
// 775.433 us; speedup vs baseline: 3.5014x; 1.0162x over previous
//
#include <hip/hip_runtime.h>
#include <math.h>

// MoEProcessor: B=8, N=4096, D=256, H=W=64, WS=8, NH=8, M=16, E=4, TD=768, HID=1024, TK=2
// Round 6: k_spectral LDS reads vectorized (xf repacked [ic][y][b*2+c], pad 20 -> 4x ds_read_b128
// per ic instead of 16x ds_read_b32). Rest identical to R5.

#define NB 8
#define NN 4096
#define DD 256

typedef __attribute__((ext_vector_type(8))) short bf16x8;
typedef __attribute__((ext_vector_type(4))) float f32x4;

__device__ __forceinline__ float gelu_f(float v) {
    return 0.5f * v * (1.0f + erff(v * 0.7071067811865475f));
}
__device__ __forceinline__ ushort f2bf(float f) {
    uint32_t u = __float_as_uint(f);
    uint32_t r = (u + 0x7fffu + ((u >> 16) & 1u)) >> 16;
    return (ushort)r;
}
__device__ __forceinline__ float b2f(ushort h) {
    return __uint_as_float(((uint32_t)h) << 16);
}

// ---------------- gating ----------------
__global__ void k_gate_mean1(const float* __restrict__ x, float* __restrict__ partial) {
    int c = blockIdx.x, b = blockIdx.y;
    int t = threadIdx.x;
    const float* xb = x + ((size_t)b * NN + c * 128) * DD;
    float s = 0.f;
    for (int n = 0; n < 128; ++n) s += xb[(size_t)n * DD + t];
    partial[((size_t)b * 32 + c) * 256 + t] = s;
}
__global__ void k_gate_mean2(const float* __restrict__ partial, const float* __restrict__ text,
                             float* __restrict__ feat) {
    int b = blockIdx.x, t = threadIdx.x;
    float s = 0.f;
    for (int c = 0; c < 32; ++c) s += partial[((size_t)b * 32 + c) * 256 + t];
    feat[b * 1024 + t] = s * (1.0f / NN);
    for (int j = t; j < 768; j += 256) feat[b * 1024 + 256 + j] = text[b * 768 + j];
}

__global__ void k_gate_mlp1(const float* __restrict__ feat, const float* __restrict__ w1,
                            const float* __restrict__ b1, float* __restrict__ h1) {
    int b = blockIdx.x, j = threadIdx.x;
    float acc = b1[j];
    const float* f = feat + b * 1024;
    for (int k = 0; k < 1024; ++k) acc += f[k] * w1[k * 256 + j];
    h1[b * 256 + j] = fmaxf(acc, 0.f);
}

__global__ void k_gate_top(const float* __restrict__ h1, const float* __restrict__ w2,
                           const float* __restrict__ b2, float* __restrict__ cw,
                           float* __restrict__ wout) {
    __shared__ float lg[8][4];
    int t = threadIdx.x;
    if (t < 32) {
        int b = t >> 2, e = t & 3;
        float acc = b2[e];
        const float* h = h1 + b * 256;
        for (int k = 0; k < 256; ++k) acc += h[k] * w2[k * 4 + e];
        lg[b][e] = acc;
    }
    __syncthreads();
    if (t < 8) {
        int b = t;
        float v[4];
        #pragma unroll
        for (int e = 0; e < 4; ++e) v[e] = lg[b][e];
        int i0 = 0;
        #pragma unroll
        for (int e = 1; e < 4; ++e) if (v[e] > v[i0]) i0 = e;
        int i1 = -1;
        #pragma unroll
        for (int e = 0; e < 4; ++e) {
            if (e == i0) continue;
            if (i1 < 0 || v[e] > v[i1]) i1 = e;
        }
        float v0 = v[i0], v1 = v[i1];
        float e1v = expf(v1 - v0);
        float inv = 1.0f / (1.0f + e1v);
        float w0 = inv, w1v = e1v * inv;
        wout[b * 2 + 0] = w0;
        wout[b * 2 + 1] = w1v;
        float c[4] = {0.f, 0.f, 0.f, 0.f};
        c[i0] += w0; c[i1] += w1v;
        #pragma unroll
        for (int e = 0; e < 4; ++e) cw[b * 4 + e] = c[e];
    }
}

// ---------------- prep: f32 -> bf16 ----------------
__global__ void k_cvtbf(const float* __restrict__ src, ushort* __restrict__ dst) {
    int i = blockIdx.x * 256 + threadIdx.x;
    float4 v = ((const float4*)src)[i];
    ushort4 o;
    o.x = f2bf(v.x); o.y = f2bf(v.y); o.z = f2bf(v.z); o.w = f2bf(v.w);
    ((ushort4*)dst)[i] = o;
}

// transpose+convert: src f32 [K][N] -> dst bf16 [N][K]
__global__ void k_wt(const float* __restrict__ src, ushort* __restrict__ dst, int K, int N) {
    __shared__ float tile[32][33];
    int n0 = blockIdx.x * 32, k0 = blockIdx.y * 32;
    int tx = threadIdx.x, ty = threadIdx.y;
    #pragma unroll
    for (int i = 0; i < 4; ++i)
        tile[ty + i * 8][tx] = src[(size_t)(k0 + ty + i * 8) * N + n0 + tx];
    __syncthreads();
    #pragma unroll
    for (int i = 0; i < 4; ++i)
        dst[(size_t)(n0 + ty + i * 8) * K + k0 + tx] = f2bf(tile[tx][ty + i * 8]);
}

// ---------------- MFMA GEMM ----------------
template<int MODE>
__global__ void __launch_bounds__(256) k_gemm(const ushort* __restrict__ A,
        const ushort* __restrict__ Bt, const float* __restrict__ bias,
        const float* __restrict__ res, float* __restrict__ outf,
        ushort* __restrict__ outb, const float* __restrict__ cw, int eidx,
        int K, int Ncols, size_t bsA, size_t bsB, size_t bsC) {
    __shared__ alignas(16) char smem[32768];
    ushort* sA = (ushort*)smem;            // [2][4096]
    ushort* sB = (ushort*)(smem + 16384);  // [2][4096]
    int z = blockIdx.z;
    A += z * bsA; Bt += z * bsB;
    if (outf) outf += z * bsC;
    int m0 = blockIdx.x * 128;
    int n0 = blockIdx.y * 128;
    int t = threadIdx.x;
    int lane = t & 63, wid = t >> 6;
    int wr = wid >> 1, wc = wid & 1;
    int rlo = lane & 15, khi = (lane >> 4) * 8;

    auto stage = [&](int buf, int k0) {
        const ushort* Ab = A + (size_t)m0 * K + k0;
        const ushort* Bb = Bt + (size_t)n0 * K + k0;
        #pragma unroll
        for (int h = 0; h < 2; ++h) {
            int s = t + h * 256;
            int row = s >> 2, kc = (s & 3) * 8;
            __builtin_amdgcn_global_load_lds(
                (const __attribute__((address_space(1))) void*)(Ab + (size_t)row * K + kc),
                (__attribute__((address_space(3))) void*)(sA + buf * 4096 + s * 8),
                16, 0, 0);
            __builtin_amdgcn_global_load_lds(
                (const __attribute__((address_space(1))) void*)(Bb + (size_t)row * K + kc),
                (__attribute__((address_space(3))) void*)(sB + buf * 4096 + s * 8),
                16, 0, 0);
        }
    };

    f32x4 acc[4][4];
    #pragma unroll
    for (int i = 0; i < 4; ++i)
        #pragma unroll
        for (int j = 0; j < 4; ++j) acc[i][j] = (f32x4){0.f, 0.f, 0.f, 0.f};

    int KT = K >> 5;
    stage(0, 0);
    int cur = 0;
    for (int kt = 0; kt < KT; ++kt) {
        __syncthreads();
        if (kt + 1 < KT) stage(cur ^ 1, (kt + 1) << 5);
        const ushort* Ap = sA + cur * 4096;
        const ushort* Bp = sB + cur * 4096;
        bf16x8 af[4], bfr[4];
        #pragma unroll
        for (int i = 0; i < 4; ++i) {
            af[i]  = *(const bf16x8*)(Ap + (wr * 64 + i * 16 + rlo) * 32 + khi);
            bfr[i] = *(const bf16x8*)(Bp + (wc * 64 + i * 16 + rlo) * 32 + khi);
        }
        #pragma unroll
        for (int i = 0; i < 4; ++i)
            #pragma unroll
            for (int j = 0; j < 4; ++j)
                acc[i][j] = __builtin_amdgcn_mfma_f32_16x16x32_bf16(af[i], bfr[j], acc[i][j], 0, 0, 0);
        cur ^= 1;
    }

    float bj4[4];
    if constexpr (MODE != 4) {
        #pragma unroll
        for (int nt = 0; nt < 4; ++nt) bj4[nt] = bias[n0 + wc * 64 + nt * 16 + rlo];
    }

    if constexpr (MODE == 0 || MODE == 1) {
        ushort* eb = (ushort*)smem;  // [32][136]
        #pragma unroll
        for (int mt = 0; mt < 4; ++mt) {
            __syncthreads();
            #pragma unroll
            for (int nt = 0; nt < 4; ++nt) {
                int col = wc * 64 + nt * 16 + rlo;
                #pragma unroll
                for (int j = 0; j < 4; ++j) {
                    float v = acc[mt][nt][j] + bj4[nt];
                    if (MODE == 0) v = gelu_f(v);
                    eb[(wr * 16 + (lane >> 4) * 4 + j) * 136 + col] = f2bf(v);
                }
            }
            __syncthreads();
            #pragma unroll
            for (int h = 0; h < 2; ++h) {
                int s = t + h * 256;
                int r = s >> 4, c = (s & 15) * 8;
                int grow = m0 + (r >> 4) * 64 + mt * 16 + (r & 15);
                *(uint4*)(outb + (size_t)grow * Ncols + n0 + c) = *(uint4*)&eb[r * 136 + c];
            }
        }
    } else {
        float* ep = (float*)smem;  // [32][132]
        #pragma unroll
        for (int mt = 0; mt < 4; ++mt) {
            __syncthreads();
            #pragma unroll
            for (int nt = 0; nt < 4; ++nt) {
                int col = wc * 64 + nt * 16 + rlo;
                #pragma unroll
                for (int j = 0; j < 4; ++j) {
                    float v = acc[mt][nt][j];
                    if constexpr (MODE == 4)
                        v += bias[m0 + wr * 64 + mt * 16 + (lane >> 4) * 4 + j];
                    else
                        v += bj4[nt];
                    ep[(wr * 16 + (lane >> 4) * 4 + j) * 132 + col] = v;
                }
            }
            __syncthreads();
            #pragma unroll
            for (int h = 0; h < 4; ++h) {
                int s = t + h * 256;
                int r = s >> 5, c4 = (s & 31) * 4;
                int grow = m0 + (r >> 4) * 64 + mt * 16 + (r & 15);
                size_t g = (size_t)grow * Ncols + n0 + c4;
                float4 v = *(float4*)&ep[r * 132 + c4];
                if constexpr (MODE == 2) {
                    if (res) {
                        float4 rv = *(const float4*)&res[g];
                        v.x += rv.x; v.y += rv.y; v.z += rv.z; v.w += rv.w;
                    }
                    *(float4*)&outf[g] = v;
                } else if constexpr (MODE == 4) {
                    *(float4*)&outf[g] = v;
                } else {
                    float cwv = cw[(grow >> 12) * 4 + eidx];
                    float4 rv = *(const float4*)&res[g];
                    float4 ov = *(float4*)&outf[g];
                    ov.x += cwv * (v.x + rv.x);
                    ov.y += cwv * (v.y + rv.y);
                    ov.z += cwv * (v.z + rv.z);
                    ov.w += cwv * (v.w + rv.w);
                    *(float4*)&outf[g] = ov;
                }
            }
        }
    }
}

// ---------------- FNO ----------------
__global__ void k_transpose(const float* __restrict__ x, float* __restrict__ xg) {
    __shared__ float tile[32][33];
    int b = blockIdx.z;
    int nt = blockIdx.x, dt = blockIdx.y;
    int tx = threadIdx.x, ty = threadIdx.y;
    const float* xb = x + (size_t)b * NN * DD;
    float* xgb = xg + (size_t)b * DD * NN;
    #pragma unroll
    for (int i = 0; i < 4; ++i) {
        int n = nt * 32 + ty + i * 8;
        tile[ty + i * 8][tx] = xb[(size_t)n * DD + dt * 32 + tx];
    }
    __syncthreads();
    #pragma unroll
    for (int i = 0; i < 4; ++i) {
        int d = dt * 32 + ty + i * 8;
        xgb[(size_t)d * NN + nt * 32 + tx] = tile[tx][ty + i * 8];
    }
}

__global__ void __launch_bounds__(64) k_rfft2(const float* __restrict__ xg, float* __restrict__ xft) {
    __shared__ float plane[64][65];
    __shared__ float s1[64][16][2];
    __shared__ float twc[64], tws[64];
    int p = blockIdx.x;
    int t = threadIdx.x;
    const float* src = xg + (size_t)p * 4096;
    for (int i = 0; i < 64; ++i) plane[i][t] = src[i * 64 + t];
    twc[t] = cosf((float)t * (6.283185307179586f / 64.0f));
    tws[t] = sinf((float)t * (6.283185307179586f / 64.0f));
    __syncthreads();
    int r = t;
    for (int kw = 0; kw < 16; ++kw) {
        float re = 0.f, im = 0.f;
        for (int w = 0; w < 64; ++w) {
            int j = (w * kw) & 63;
            float xv = plane[r][w];
            re += xv * twc[j];
            im -= xv * tws[j];
        }
        s1[r][kw][0] = re; s1[r][kw][1] = im;
    }
    __syncthreads();
    float2* dst = (float2*)xft + (size_t)p * 512;
    #pragma unroll
    for (int q = 0; q < 8; ++q) {
        int oi = t + q * 64;
        int krow = oi >> 4, kw = oi & 15;
        int kh = krow < 16 ? krow : krow + 32;
        float re = 0.f, im = 0.f;
        for (int h = 0; h < 64; ++h) {
            int j = (h * kh) & 63;
            float c = twc[j], s = tws[j];
            float ar = s1[h][kw][0], ai = s1[h][kw][1];
            re += ar * c + ai * s;
            im += ai * c - ar * s;
        }
        dst[oi] = make_float2(re, im);
    }
}

// spectral contraction, i-split x4; LDS x-tile packed [ic][y][b*2+c] (pad 20) for b128 reads
__global__ void __launch_bounds__(512) k_spectral(const float* __restrict__ xft,
        const float* __restrict__ w1r, const float* __restrict__ w1i,
        const float* __restrict__ w2r, const float* __restrict__ w2i,
        float* __restrict__ part) {
    __shared__ float xf[32][16][20];    // 40 KB
    int z = blockIdx.z;                 // 0..7
    int region = z >> 2, is = z & 3;
    const float* wr = region ? w2r : w1r;
    const float* wi = region ? w2i : w1i;
    int xm = blockIdx.y;
    int krow = region * 16 + xm;
    int o0 = blockIdx.x * 32;
    int t = threadIdx.x;
    int y = t & 15, ol = t >> 4;
    int o = o0 + ol;
    float accr[8], acci[8];
    #pragma unroll
    for (int b = 0; b < 8; ++b) { accr[b] = 0.f; acci[b] = 0.f; }
    int ibase = is * 64;
    for (int i0 = ibase; i0 < ibase + 64; i0 += 32) {
        __syncthreads();
        #pragma unroll
        for (int l = 0; l < 16; ++l) {
            int idx = t + l * 512;
            int c = idx & 1, yy = (idx >> 1) & 15, ic = (idx >> 5) & 31, b = idx >> 10;
            xf[ic][yy][b * 2 + c] = xft[(((size_t)b * 256 + i0 + ic) * 32 + krow) * 32 + yy * 2 + c];
        }
        __syncthreads();
        size_t wbase = (((size_t)i0 * 256 + o) * 16 + xm) * 16 + y;
        for (int ic4 = 0; ic4 < 32; ic4 += 4) {
            float wrv[4], wiv[4];
            #pragma unroll
            for (int u = 0; u < 4; ++u) {
                size_t widx = wbase + (size_t)(ic4 + u) * 65536;
                wrv[u] = wr[widx];
                wiv[u] = wi[widx];
            }
            #pragma unroll
            for (int u = 0; u < 4; ++u) {
                int ic = ic4 + u;
                const float* xr = &xf[ic][y][0];
                float4 x0 = *(const float4*)(xr);
                float4 x1 = *(const float4*)(xr + 4);
                accr[0] += x0.x * wrv[u] - x0.y * wiv[u];
                acci[0] += x0.x * wiv[u] + x0.y * wrv[u];
                accr[1] += x0.z * wrv[u] - x0.w * wiv[u];
                acci[1] += x0.z * wiv[u] + x0.w * wrv[u];
                accr[2] += x1.x * wrv[u] - x1.y * wiv[u];
                acci[2] += x1.x * wiv[u] + x1.y * wrv[u];
                accr[3] += x1.z * wrv[u] - x1.w * wiv[u];
                acci[3] += x1.z * wiv[u] + x1.w * wrv[u];
                float4 x2 = *(const float4*)(xr + 8);
                float4 x3 = *(const float4*)(xr + 12);
                accr[4] += x2.x * wrv[u] - x2.y * wiv[u];
                acci[4] += x2.x * wiv[u] + x2.y * wrv[u];
                accr[5] += x2.z * wrv[u] - x2.w * wiv[u];
                acci[5] += x2.z * wiv[u] + x2.w * wrv[u];
                accr[6] += x3.x * wrv[u] - x3.y * wiv[u];
                acci[6] += x3.x * wiv[u] + x3.y * wrv[u];
                accr[7] += x3.z * wrv[u] - x3.w * wiv[u];
                acci[7] += x3.z * wiv[u] + x3.w * wrv[u];
            }
        }
    }
    float2* dst = (float2*)part + (size_t)is * 1048576;
    #pragma unroll
    for (int b = 0; b < 8; ++b)
        dst[(((size_t)b * 256 + o) * 32 + krow) * 16 + y] = make_float2(accr[b], acci[b]);
}

// reduce 4 partials -> oft
__global__ void k_red4(const float* __restrict__ part, float* __restrict__ oft) {
    int i = blockIdx.x * 256 + threadIdx.x;
    const float4* p = (const float4*)part;
    float4 a = p[i];
    float4 b = p[i + 524288];
    float4 c = p[i + 1048576];
    float4 d = p[i + 1572864];
    float4 s;
    s.x = a.x + b.x + c.x + d.x;
    s.y = a.y + b.y + c.y + d.y;
    s.z = a.z + b.z + c.z + d.z;
    s.w = a.w + b.w + c.w + d.w;
    ((float4*)oft)[i] = s;
}

// irfft2 + gelu(x1 + conv-branch), all channel-major coalesced. tmp[p][hw]
__global__ void __launch_bounds__(64) k_irfft_fuse(const float* __restrict__ oft,
        const float* __restrict__ x2t, float* __restrict__ tmp) {
    __shared__ float F[32][16][2];
    __shared__ float tarr[64][16][2];
    __shared__ float twc[64], tws[64];
    int p = blockIdx.x;
    int t = threadIdx.x;
    const float2* src = (const float2*)oft + (size_t)p * 512;
    #pragma unroll
    for (int l = 0; l < 8; ++l) {
        int idx = t + l * 64;
        ((float2*)F)[idx] = src[idx];
    }
    twc[t] = cosf((float)t * (6.283185307179586f / 64.0f));
    tws[t] = sinf((float)t * (6.283185307179586f / 64.0f));
    __syncthreads();
    int h = t;
    for (int kw = 0; kw < 16; ++kw) {
        float re = 0.f, im = 0.f;
        #pragma unroll
        for (int krow = 0; krow < 32; ++krow) {
            int kh = krow < 16 ? krow : krow + 32;
            int j = (h * kh) & 63;
            float c = twc[j], s = tws[j];
            float fr = F[krow][kw][0], fi = F[krow][kw][1];
            re += fr * c - fi * s;
            im += fr * s + fi * c;
        }
        tarr[h][kw][0] = re * (1.f / 64.f);
        tarr[h][kw][1] = im * (1.f / 64.f);
    }
    __syncthreads();
    const float* x2p = x2t + (size_t)p * 4096;
    float* tp = tmp + (size_t)p * 4096;
    for (int q = 0; q < 64; ++q) {
        int w = t;
        float acc = tarr[q][0][0];
        #pragma unroll
        for (int kw = 1; kw < 16; ++kw) {
            int j = (w * kw) & 63;
            acc += 2.f * (tarr[q][kw][0] * twc[j] - tarr[q][kw][1] * tws[j]);
        }
        float x1 = acc * (1.f / 64.f);
        int idx = q * 64 + w;
        tp[idx] = gelu_f(x1 + x2p[idx]);
    }
}

// transpose tmp [b][d][n] -> out[b][n][d] = cw0*(tmp + x)
__global__ void k_fno_final(const float* __restrict__ tmp, const float* __restrict__ x,
        const float* __restrict__ cw, float* __restrict__ out) {
    __shared__ float tile[32][33];
    int b = blockIdx.z;
    int n0 = blockIdx.x * 32, d0 = blockIdx.y * 32;
    int tx = threadIdx.x, ty = threadIdx.y;
    const float* tb = tmp + (size_t)b * DD * NN;
    #pragma unroll
    for (int i = 0; i < 4; ++i)
        tile[ty + i * 8][tx] = tb[(size_t)(d0 + ty + i * 8) * NN + n0 + tx];
    __syncthreads();
    float cw0 = cw[b * 4];
    #pragma unroll
    for (int i = 0; i < 4; ++i) {
        int n = n0 + ty + i * 8, d = d0 + tx;
        size_t g = ((size_t)b * NN + n) * DD + d;
        out[g] = cw0 * (tile[tx][ty + i * 8] + x[g]);
    }
}

// ---------------- layernorm (f32 in, bf16 out) ----------------
__global__ void __launch_bounds__(256) k_ln(const float* __restrict__ in, const float* __restrict__ g,
        const float* __restrict__ be, ushort* __restrict__ outb) {
    int row = blockIdx.x * 4 + (threadIdx.x >> 6);
    int lane = threadIdx.x & 63;
    const float4* rp = (const float4*)(in + (size_t)row * 256);
    float4 v = rp[lane];
    float s = v.x + v.y + v.z + v.w;
    float s2 = v.x * v.x + v.y * v.y + v.z * v.z + v.w * v.w;
    #pragma unroll
    for (int off = 32; off > 0; off >>= 1) {
        s += __shfl_down(s, off);
        s2 += __shfl_down(s2, off);
    }
    s = __shfl(s, 0); s2 = __shfl(s2, 0);
    float mu = s * (1.f / 256.f);
    float var = s2 * (1.f / 256.f) - mu * mu;
    float rstd = rsqrtf(var + 1e-5f);
    float4 gv = ((const float4*)g)[lane];
    float4 bv = ((const float4*)be)[lane];
    ushort4 ov;
    ov.x = f2bf((v.x - mu) * rstd * gv.x + bv.x);
    ov.y = f2bf((v.y - mu) * rstd * gv.y + bv.y);
    ov.z = f2bf((v.z - mu) * rstd * gv.z + bv.z);
    ov.w = f2bf((v.w - mu) * rstd * gv.w + bv.w);
    ((ushort4*)(outb + (size_t)row * 256))[lane] = ov;
}

// ---------------- window attention core (bf16 in, bf16 out) ----------------
__global__ void __launch_bounds__(64) k_window_attn(const ushort* __restrict__ qkvb,
        ushort* __restrict__ aob) {
    __shared__ float ks[64][36], vs[64][36];
    __shared__ float ps[64][65];
    int wi = blockIdx.x >> 3;
    int hd = blockIdx.x & 7;
    int b = wi >> 6;
    int hb = (wi >> 3) & 7, wb = wi & 7;
    int t = threadIdx.x;
    for (int l2 = 0; l2 < 32; ++l2) {
        int idx = t + l2 * 64;
        int tok = idx >> 5, d = idx & 31;
        int n = (hb * 8 + (tok >> 3)) * 64 + wb * 8 + (tok & 7);
        size_t base = ((size_t)b * 4096 + n) * 768 + hd * 32 + d;
        ks[tok][d] = b2f(qkvb[base + 256]);
        vs[tok][d] = b2f(qkvb[base + 512]);
    }
    int l = t;
    int nq = (hb * 8 + (l >> 3)) * 64 + wb * 8 + (l & 7);
    const ushort4* qp = (const ushort4*)(qkvb + ((size_t)b * 4096 + nq) * 768 + hd * 32);
    float4 q[8];
    #pragma unroll
    for (int i = 0; i < 8; ++i) {
        ushort4 u = qp[i];
        q[i] = make_float4(b2f(u.x), b2f(u.y), b2f(u.z), b2f(u.w));
    }
    __syncthreads();
    const float scale = 0.17677669529663687f;
    float mx = -1e30f;
    for (int m = 0; m < 64; ++m) {
        const float4* kr = (const float4*)&ks[m][0];
        float a = 0.f;
        #pragma unroll
        for (int i = 0; i < 8; ++i) {
            float4 kv = kr[i];
            a += q[i].x * kv.x + q[i].y * kv.y + q[i].z * kv.z + q[i].w * kv.w;
        }
        a *= scale;
        ps[l][m] = a;
        mx = fmaxf(mx, a);
    }
    float ssum = 0.f;
    for (int m = 0; m < 64; ++m) {
        float p = expf(ps[l][m] - mx);
        ps[l][m] = p;
        ssum += p;
    }
    float inv = 1.f / ssum;
    float4 o[8];
    #pragma unroll
    for (int i = 0; i < 8; ++i) o[i] = make_float4(0.f, 0.f, 0.f, 0.f);
    for (int m = 0; m < 64; ++m) {
        float p = ps[l][m];
        const float4* vr = (const float4*)&vs[m][0];
        #pragma unroll
        for (int i = 0; i < 8; ++i) {
            float4 vv = vr[i];
            o[i].x += p * vv.x; o[i].y += p * vv.y; o[i].z += p * vv.z; o[i].w += p * vv.w;
        }
    }
    ushort* op = aob + ((size_t)b * 4096 + nq) * 256 + hd * 32;
    #pragma unroll
    for (int i = 0; i < 8; ++i) {
        ushort4 u;
        u.x = f2bf(o[i].x * inv); u.y = f2bf(o[i].y * inv);
        u.z = f2bf(o[i].z * inv); u.w = f2bf(o[i].w * inv);
        ((ushort4*)op)[i] = u;
    }
}

extern "C" void kernel_launch(void* const* d_in, const int* in_sizes, int n_in,
                              void* d_out, int out_size, void* d_ws, size_t ws_size,
                              hipStream_t stream) {
    (void)in_sizes; (void)n_in; (void)out_size; (void)ws_size;
    const float* x        = (const float*)d_in[0];
    const float* text     = (const float*)d_in[1];
    const float* gate_w1  = (const float*)d_in[2];
    const float* gate_b1  = (const float*)d_in[3];
    const float* gate_w2  = (const float*)d_in[4];
    const float* gate_b2  = (const float*)d_in[5];
    const float* fno_w1r  = (const float*)d_in[6];
    const float* fno_w1i  = (const float*)d_in[7];
    const float* fno_w2r  = (const float*)d_in[8];
    const float* fno_w2i  = (const float*)d_in[9];
    const float* fno_cw   = (const float*)d_in[10];
    const float* fno_cb   = (const float*)d_in[11];
    const float* mlp1_w1  = (const float*)d_in[12];
    const float* mlp1_b1  = (const float*)d_in[13];
    const float* mlp1_w2  = (const float*)d_in[14];
    const float* mlp1_b2  = (const float*)d_in[15];
    const float* mlp2_w1  = (const float*)d_in[16];
    const float* mlp2_b1  = (const float*)d_in[17];
    const float* mlp2_w2  = (const float*)d_in[18];
    const float* mlp2_b2  = (const float*)d_in[19];
    const float* ln1_g    = (const float*)d_in[20];
    const float* ln1_b    = (const float*)d_in[21];
    const float* qkv_w    = (const float*)d_in[22];
    const float* qkv_b    = (const float*)d_in[23];
    const float* out_w    = (const float*)d_in[24];
    const float* out_b    = (const float*)d_in[25];
    const float* ln2_g    = (const float*)d_in[26];
    const float* ln2_b    = (const float*)d_in[27];
    const float* wa_w1    = (const float*)d_in[28];
    const float* wa_b1    = (const float*)d_in[29];
    const float* wa_w2    = (const float*)d_in[30];
    const float* wa_b2    = (const float*)d_in[31];

    float* ws   = (float*)d_ws;
    float* feat = ws;                // 8192
    float* h1   = ws + 8192;         // 2048
    float* cwp  = ws + 10240;        // 32
    ushort* wbf = (ushort*)(ws + 16384);     // weight bf16 pool
    ushort* w1aT = wbf;
    ushort* w2aT = w1aT + 262144;
    ushort* w1bT = w2aT + 262144;
    ushort* w2bT = w1bT + 262144;
    ushort* w1cT = w2bT + 262144;
    ushort* w2cT = w1cT + 262144;
    ushort* qkvT = w2cT + 262144;
    ushort* outwT = qkvT + 196608;
    ushort* convT = outwT + 65536;
    ushort* Xbf  = (ushort*)(ws + 16384 + 1048576);          // bf16 x
    float* slotA = ws + 16384 + 1048576 + 4194304;           // 8.39M floats (xg / spectral-partials / tmp / abf)
    ushort* abf  = (ushort*)slotA;
    float* xft   = slotA + 8388608;                          // 2.1M
    float* oft   = xft + 2097152;                            // 2.1M (also gate partials, pre-FNO)
    float* regD  = oft + 2097152;                            // 8.39M (x2t / xattn)
    ushort* bigb = (ushort*)(regD + 8388608);                // qkv-bf16 / hidden-bf16
    float* gpart = oft;   // gating partial sums live in oft region (written later by reduce)

    float* outp = (float*)d_out;
    float* wout = outp + (size_t)NB * NN * DD;

    // gating
    k_gate_mean1<<<dim3(32, 8), 256, 0, stream>>>(x, gpart);
    k_gate_mean2<<<8, 256, 0, stream>>>(gpart, text, feat);
    k_gate_mlp1<<<8, 256, 0, stream>>>(feat, gate_w1, gate_b1, h1);
    k_gate_top<<<1, 64, 0, stream>>>(h1, gate_w2, gate_b2, cwp, wout);

    // prep: bf16 conversions
    k_cvtbf<<<8192, 256, 0, stream>>>(x, Xbf);
    dim3 wtb(32, 8);
    k_wt<<<dim3(32, 8), wtb, 0, stream>>>(mlp1_w1, w1aT, 256, 1024);
    k_wt<<<dim3(8, 32), wtb, 0, stream>>>(mlp1_w2, w2aT, 1024, 256);
    k_wt<<<dim3(32, 8), wtb, 0, stream>>>(mlp2_w1, w1bT, 256, 1024);
    k_wt<<<dim3(8, 32), wtb, 0, stream>>>(mlp2_w2, w2bT, 1024, 256);
    k_wt<<<dim3(32, 8), wtb, 0, stream>>>(wa_w1, w1cT, 256, 1024);
    k_wt<<<dim3(8, 32), wtb, 0, stream>>>(wa_w2, w2cT, 1024, 256);
    k_wt<<<dim3(24, 8), wtb, 0, stream>>>(qkv_w, qkvT, 256, 768);
    k_wt<<<dim3(8, 8), wtb, 0, stream>>>(out_w, outwT, 256, 256);
    k_wt<<<dim3(8, 8), wtb, 0, stream>>>(fno_cw, convT, 256, 256);

    // expert 0: FNO (channel-major pipeline; final kernel writes all of out)
    k_transpose<<<dim3(128, 8, 8), dim3(32, 8), 0, stream>>>(x, slotA);
    k_rfft2<<<2048, 64, 0, stream>>>(slotA, xft);
    // conv branch, transposed output x2t[b][o][n]: A=convT [o][d], Bt=Xbf[b] [n][d]
    k_gemm<4><<<dim3(2, 32, 8), 256, 0, stream>>>(convT, Xbf, fno_cb, nullptr, regD, nullptr,
        nullptr, 0, 256, 4096, 0, (size_t)NN * DD, (size_t)DD * NN);
    // spectral: partials into slotA (xg dead after rfft2), then reduce to oft
    k_spectral<<<dim3(8, 16, 8), 512, 0, stream>>>(xft, fno_w1r, fno_w1i, fno_w2r, fno_w2i, slotA);
    k_red4<<<2048, 256, 0, stream>>>(slotA, oft);
    k_irfft_fuse<<<2048, 64, 0, stream>>>(oft, regD, slotA);
    k_fno_final<<<dim3(128, 8, 8), dim3(32, 8), 0, stream>>>(slotA, x, cwp, outp);

    // expert 1: MLP
    k_gemm<0><<<dim3(256, 8), 256, 0, stream>>>(Xbf, w1aT, mlp1_b1, nullptr, nullptr, bigb, nullptr, 0, 256, 1024, 0, 0, 0);
    k_gemm<3><<<dim3(256, 2), 256, 0, stream>>>(bigb, w2aT, mlp1_b2, x, outp, nullptr, cwp, 1, 1024, 256, 0, 0, 0);

    // expert 2: window attention
    k_ln<<<8192, 256, 0, stream>>>(x, ln1_g, ln1_b, abf);
    k_gemm<1><<<dim3(256, 6), 256, 0, stream>>>(abf, qkvT, qkv_b, nullptr, nullptr, bigb, nullptr, 0, 256, 768, 0, 0, 0);
    k_window_attn<<<4096, 64, 0, stream>>>(bigb, abf);
    k_gemm<2><<<dim3(256, 2), 256, 0, stream>>>(abf, outwT, out_b, x, regD, nullptr, nullptr, 0, 256, 256, 0, 0, 0);
    k_ln<<<8192, 256, 0, stream>>>(regD, ln2_g, ln2_b, abf);
    k_gemm<0><<<dim3(256, 8), 256, 0, stream>>>(abf, w1cT, wa_b1, nullptr, nullptr, bigb, nullptr, 0, 256, 1024, 0, 0, 0);
    k_gemm<3><<<dim3(256, 2), 256, 0, stream>>>(bigb, w2cT, wa_b2, regD, outp, nullptr, cwp, 2, 1024, 256, 0, 0, 0);

    // expert 3: MLP
    k_gemm<0><<<dim3(256, 8), 256, 0, stream>>>(Xbf, w1bT, mlp2_b1, nullptr, nullptr, bigb, nullptr, 0, 256, 1024, 0, 0, 0);
    k_gemm<3><<<dim3(256, 2), 256, 0, stream>>>(bigb, w2bT, mlp2_b2, x, outp, nullptr, cwp, 3, 1024, 256, 0, 0, 0);
}

// Round 7
// 713.163 us; speedup vs baseline: 3.8072x; 1.0873x over previous
//
#include <hip/hip_runtime.h>
#include <math.h>

// MoEProcessor: B=8, N=4096, D=256, H=W=64, WS=8, NH=8, M=16, E=4, TD=768, HID=1024, TK=2
// Round 7: MFMA window attention (1 head/wave, QK^T and PV on matrix cores);
// k_red4 merged into k_irfft_fuse. Rest identical to R6.

#define NB 8
#define NN 4096
#define DD 256

typedef __attribute__((ext_vector_type(8))) short bf16x8;
typedef __attribute__((ext_vector_type(4))) float f32x4;

__device__ __forceinline__ float gelu_f(float v) {
    return 0.5f * v * (1.0f + erff(v * 0.7071067811865475f));
}
__device__ __forceinline__ ushort f2bf(float f) {
    uint32_t u = __float_as_uint(f);
    uint32_t r = (u + 0x7fffu + ((u >> 16) & 1u)) >> 16;
    return (ushort)r;
}
__device__ __forceinline__ float b2f(ushort h) {
    return __uint_as_float(((uint32_t)h) << 16);
}

// ---------------- gating ----------------
__global__ void k_gate_mean1(const float* __restrict__ x, float* __restrict__ partial) {
    int c = blockIdx.x, b = blockIdx.y;
    int t = threadIdx.x;
    const float* xb = x + ((size_t)b * NN + c * 128) * DD;
    float s = 0.f;
    for (int n = 0; n < 128; ++n) s += xb[(size_t)n * DD + t];
    partial[((size_t)b * 32 + c) * 256 + t] = s;
}
__global__ void k_gate_mean2(const float* __restrict__ partial, const float* __restrict__ text,
                             float* __restrict__ feat) {
    int b = blockIdx.x, t = threadIdx.x;
    float s = 0.f;
    for (int c = 0; c < 32; ++c) s += partial[((size_t)b * 32 + c) * 256 + t];
    feat[b * 1024 + t] = s * (1.0f / NN);
    for (int j = t; j < 768; j += 256) feat[b * 1024 + 256 + j] = text[b * 768 + j];
}

__global__ void k_gate_mlp1(const float* __restrict__ feat, const float* __restrict__ w1,
                            const float* __restrict__ b1, float* __restrict__ h1) {
    int b = blockIdx.x, j = threadIdx.x;
    float acc = b1[j];
    const float* f = feat + b * 1024;
    for (int k = 0; k < 1024; ++k) acc += f[k] * w1[k * 256 + j];
    h1[b * 256 + j] = fmaxf(acc, 0.f);
}

__global__ void k_gate_top(const float* __restrict__ h1, const float* __restrict__ w2,
                           const float* __restrict__ b2, float* __restrict__ cw,
                           float* __restrict__ wout) {
    __shared__ float lg[8][4];
    int t = threadIdx.x;
    if (t < 32) {
        int b = t >> 2, e = t & 3;
        float acc = b2[e];
        const float* h = h1 + b * 256;
        for (int k = 0; k < 256; ++k) acc += h[k] * w2[k * 4 + e];
        lg[b][e] = acc;
    }
    __syncthreads();
    if (t < 8) {
        int b = t;
        float v[4];
        #pragma unroll
        for (int e = 0; e < 4; ++e) v[e] = lg[b][e];
        int i0 = 0;
        #pragma unroll
        for (int e = 1; e < 4; ++e) if (v[e] > v[i0]) i0 = e;
        int i1 = -1;
        #pragma unroll
        for (int e = 0; e < 4; ++e) {
            if (e == i0) continue;
            if (i1 < 0 || v[e] > v[i1]) i1 = e;
        }
        float v0 = v[i0], v1 = v[i1];
        float e1v = expf(v1 - v0);
        float inv = 1.0f / (1.0f + e1v);
        float w0 = inv, w1v = e1v * inv;
        wout[b * 2 + 0] = w0;
        wout[b * 2 + 1] = w1v;
        float c[4] = {0.f, 0.f, 0.f, 0.f};
        c[i0] += w0; c[i1] += w1v;
        #pragma unroll
        for (int e = 0; e < 4; ++e) cw[b * 4 + e] = c[e];
    }
}

// ---------------- prep: f32 -> bf16 ----------------
__global__ void k_cvtbf(const float* __restrict__ src, ushort* __restrict__ dst) {
    int i = blockIdx.x * 256 + threadIdx.x;
    float4 v = ((const float4*)src)[i];
    ushort4 o;
    o.x = f2bf(v.x); o.y = f2bf(v.y); o.z = f2bf(v.z); o.w = f2bf(v.w);
    ((ushort4*)dst)[i] = o;
}

// transpose+convert: src f32 [K][N] -> dst bf16 [N][K]
__global__ void k_wt(const float* __restrict__ src, ushort* __restrict__ dst, int K, int N) {
    __shared__ float tile[32][33];
    int n0 = blockIdx.x * 32, k0 = blockIdx.y * 32;
    int tx = threadIdx.x, ty = threadIdx.y;
    #pragma unroll
    for (int i = 0; i < 4; ++i)
        tile[ty + i * 8][tx] = src[(size_t)(k0 + ty + i * 8) * N + n0 + tx];
    __syncthreads();
    #pragma unroll
    for (int i = 0; i < 4; ++i)
        dst[(size_t)(n0 + ty + i * 8) * K + k0 + tx] = f2bf(tile[tx][ty + i * 8]);
}

// ---------------- MFMA GEMM ----------------
template<int MODE>
__global__ void __launch_bounds__(256) k_gemm(const ushort* __restrict__ A,
        const ushort* __restrict__ Bt, const float* __restrict__ bias,
        const float* __restrict__ res, float* __restrict__ outf,
        ushort* __restrict__ outb, const float* __restrict__ cw, int eidx,
        int K, int Ncols, size_t bsA, size_t bsB, size_t bsC) {
    __shared__ alignas(16) char smem[32768];
    ushort* sA = (ushort*)smem;            // [2][4096]
    ushort* sB = (ushort*)(smem + 16384);  // [2][4096]
    int z = blockIdx.z;
    A += z * bsA; Bt += z * bsB;
    if (outf) outf += z * bsC;
    int m0 = blockIdx.x * 128;
    int n0 = blockIdx.y * 128;
    int t = threadIdx.x;
    int lane = t & 63, wid = t >> 6;
    int wr = wid >> 1, wc = wid & 1;
    int rlo = lane & 15, khi = (lane >> 4) * 8;

    auto stage = [&](int buf, int k0) {
        const ushort* Ab = A + (size_t)m0 * K + k0;
        const ushort* Bb = Bt + (size_t)n0 * K + k0;
        #pragma unroll
        for (int h = 0; h < 2; ++h) {
            int s = t + h * 256;
            int row = s >> 2, kc = (s & 3) * 8;
            __builtin_amdgcn_global_load_lds(
                (const __attribute__((address_space(1))) void*)(Ab + (size_t)row * K + kc),
                (__attribute__((address_space(3))) void*)(sA + buf * 4096 + s * 8),
                16, 0, 0);
            __builtin_amdgcn_global_load_lds(
                (const __attribute__((address_space(1))) void*)(Bb + (size_t)row * K + kc),
                (__attribute__((address_space(3))) void*)(sB + buf * 4096 + s * 8),
                16, 0, 0);
        }
    };

    f32x4 acc[4][4];
    #pragma unroll
    for (int i = 0; i < 4; ++i)
        #pragma unroll
        for (int j = 0; j < 4; ++j) acc[i][j] = (f32x4){0.f, 0.f, 0.f, 0.f};

    int KT = K >> 5;
    stage(0, 0);
    int cur = 0;
    for (int kt = 0; kt < KT; ++kt) {
        __syncthreads();
        if (kt + 1 < KT) stage(cur ^ 1, (kt + 1) << 5);
        const ushort* Ap = sA + cur * 4096;
        const ushort* Bp = sB + cur * 4096;
        bf16x8 af[4], bfr[4];
        #pragma unroll
        for (int i = 0; i < 4; ++i) {
            af[i]  = *(const bf16x8*)(Ap + (wr * 64 + i * 16 + rlo) * 32 + khi);
            bfr[i] = *(const bf16x8*)(Bp + (wc * 64 + i * 16 + rlo) * 32 + khi);
        }
        #pragma unroll
        for (int i = 0; i < 4; ++i)
            #pragma unroll
            for (int j = 0; j < 4; ++j)
                acc[i][j] = __builtin_amdgcn_mfma_f32_16x16x32_bf16(af[i], bfr[j], acc[i][j], 0, 0, 0);
        cur ^= 1;
    }

    float bj4[4];
    if constexpr (MODE != 4) {
        #pragma unroll
        for (int nt = 0; nt < 4; ++nt) bj4[nt] = bias[n0 + wc * 64 + nt * 16 + rlo];
    }

    if constexpr (MODE == 0 || MODE == 1) {
        ushort* eb = (ushort*)smem;  // [32][136]
        #pragma unroll
        for (int mt = 0; mt < 4; ++mt) {
            __syncthreads();
            #pragma unroll
            for (int nt = 0; nt < 4; ++nt) {
                int col = wc * 64 + nt * 16 + rlo;
                #pragma unroll
                for (int j = 0; j < 4; ++j) {
                    float v = acc[mt][nt][j] + bj4[nt];
                    if (MODE == 0) v = gelu_f(v);
                    eb[(wr * 16 + (lane >> 4) * 4 + j) * 136 + col] = f2bf(v);
                }
            }
            __syncthreads();
            #pragma unroll
            for (int h = 0; h < 2; ++h) {
                int s = t + h * 256;
                int r = s >> 4, c = (s & 15) * 8;
                int grow = m0 + (r >> 4) * 64 + mt * 16 + (r & 15);
                *(uint4*)(outb + (size_t)grow * Ncols + n0 + c) = *(uint4*)&eb[r * 136 + c];
            }
        }
    } else {
        float* ep = (float*)smem;  // [32][132]
        #pragma unroll
        for (int mt = 0; mt < 4; ++mt) {
            __syncthreads();
            #pragma unroll
            for (int nt = 0; nt < 4; ++nt) {
                int col = wc * 64 + nt * 16 + rlo;
                #pragma unroll
                for (int j = 0; j < 4; ++j) {
                    float v = acc[mt][nt][j];
                    if constexpr (MODE == 4)
                        v += bias[m0 + wr * 64 + mt * 16 + (lane >> 4) * 4 + j];
                    else
                        v += bj4[nt];
                    ep[(wr * 16 + (lane >> 4) * 4 + j) * 132 + col] = v;
                }
            }
            __syncthreads();
            #pragma unroll
            for (int h = 0; h < 4; ++h) {
                int s = t + h * 256;
                int r = s >> 5, c4 = (s & 31) * 4;
                int grow = m0 + (r >> 4) * 64 + mt * 16 + (r & 15);
                size_t g = (size_t)grow * Ncols + n0 + c4;
                float4 v = *(float4*)&ep[r * 132 + c4];
                if constexpr (MODE == 2) {
                    if (res) {
                        float4 rv = *(const float4*)&res[g];
                        v.x += rv.x; v.y += rv.y; v.z += rv.z; v.w += rv.w;
                    }
                    *(float4*)&outf[g] = v;
                } else if constexpr (MODE == 4) {
                    *(float4*)&outf[g] = v;
                } else {
                    float cwv = cw[(grow >> 12) * 4 + eidx];
                    float4 rv = *(const float4*)&res[g];
                    float4 ov = *(float4*)&outf[g];
                    ov.x += cwv * (v.x + rv.x);
                    ov.y += cwv * (v.y + rv.y);
                    ov.z += cwv * (v.z + rv.z);
                    ov.w += cwv * (v.w + rv.w);
                    *(float4*)&outf[g] = ov;
                }
            }
        }
    }
}

// ---------------- FNO ----------------
__global__ void k_transpose(const float* __restrict__ x, float* __restrict__ xg) {
    __shared__ float tile[32][33];
    int b = blockIdx.z;
    int nt = blockIdx.x, dt = blockIdx.y;
    int tx = threadIdx.x, ty = threadIdx.y;
    const float* xb = x + (size_t)b * NN * DD;
    float* xgb = xg + (size_t)b * DD * NN;
    #pragma unroll
    for (int i = 0; i < 4; ++i) {
        int n = nt * 32 + ty + i * 8;
        tile[ty + i * 8][tx] = xb[(size_t)n * DD + dt * 32 + tx];
    }
    __syncthreads();
    #pragma unroll
    for (int i = 0; i < 4; ++i) {
        int d = dt * 32 + ty + i * 8;
        xgb[(size_t)d * NN + nt * 32 + tx] = tile[tx][ty + i * 8];
    }
}

__global__ void __launch_bounds__(64) k_rfft2(const float* __restrict__ xg, float* __restrict__ xft) {
    __shared__ float plane[64][65];
    __shared__ float s1[64][16][2];
    __shared__ float twc[64], tws[64];
    int p = blockIdx.x;
    int t = threadIdx.x;
    const float* src = xg + (size_t)p * 4096;
    for (int i = 0; i < 64; ++i) plane[i][t] = src[i * 64 + t];
    twc[t] = cosf((float)t * (6.283185307179586f / 64.0f));
    tws[t] = sinf((float)t * (6.283185307179586f / 64.0f));
    __syncthreads();
    int r = t;
    for (int kw = 0; kw < 16; ++kw) {
        float re = 0.f, im = 0.f;
        for (int w = 0; w < 64; ++w) {
            int j = (w * kw) & 63;
            float xv = plane[r][w];
            re += xv * twc[j];
            im -= xv * tws[j];
        }
        s1[r][kw][0] = re; s1[r][kw][1] = im;
    }
    __syncthreads();
    float2* dst = (float2*)xft + (size_t)p * 512;
    #pragma unroll
    for (int q = 0; q < 8; ++q) {
        int oi = t + q * 64;
        int krow = oi >> 4, kw = oi & 15;
        int kh = krow < 16 ? krow : krow + 32;
        float re = 0.f, im = 0.f;
        for (int h = 0; h < 64; ++h) {
            int j = (h * kh) & 63;
            float c = twc[j], s = tws[j];
            float ar = s1[h][kw][0], ai = s1[h][kw][1];
            re += ar * c + ai * s;
            im += ai * c - ar * s;
        }
        dst[oi] = make_float2(re, im);
    }
}

// spectral contraction, i-split x4; LDS x-tile packed [ic][y][b*2+c] (pad 20) for b128 reads
__global__ void __launch_bounds__(512) k_spectral(const float* __restrict__ xft,
        const float* __restrict__ w1r, const float* __restrict__ w1i,
        const float* __restrict__ w2r, const float* __restrict__ w2i,
        float* __restrict__ part) {
    __shared__ float xf[32][16][20];    // 40 KB
    int z = blockIdx.z;                 // 0..7
    int region = z >> 2, is = z & 3;
    const float* wr = region ? w2r : w1r;
    const float* wi = region ? w2i : w1i;
    int xm = blockIdx.y;
    int krow = region * 16 + xm;
    int o0 = blockIdx.x * 32;
    int t = threadIdx.x;
    int y = t & 15, ol = t >> 4;
    int o = o0 + ol;
    float accr[8], acci[8];
    #pragma unroll
    for (int b = 0; b < 8; ++b) { accr[b] = 0.f; acci[b] = 0.f; }
    int ibase = is * 64;
    for (int i0 = ibase; i0 < ibase + 64; i0 += 32) {
        __syncthreads();
        #pragma unroll
        for (int l = 0; l < 16; ++l) {
            int idx = t + l * 512;
            int c = idx & 1, yy = (idx >> 1) & 15, ic = (idx >> 5) & 31, b = idx >> 10;
            xf[ic][yy][b * 2 + c] = xft[(((size_t)b * 256 + i0 + ic) * 32 + krow) * 32 + yy * 2 + c];
        }
        __syncthreads();
        size_t wbase = (((size_t)i0 * 256 + o) * 16 + xm) * 16 + y;
        for (int ic4 = 0; ic4 < 32; ic4 += 4) {
            float wrv[4], wiv[4];
            #pragma unroll
            for (int u = 0; u < 4; ++u) {
                size_t widx = wbase + (size_t)(ic4 + u) * 65536;
                wrv[u] = wr[widx];
                wiv[u] = wi[widx];
            }
            #pragma unroll
            for (int u = 0; u < 4; ++u) {
                int ic = ic4 + u;
                const float* xr = &xf[ic][y][0];
                float4 x0 = *(const float4*)(xr);
                float4 x1 = *(const float4*)(xr + 4);
                accr[0] += x0.x * wrv[u] - x0.y * wiv[u];
                acci[0] += x0.x * wiv[u] + x0.y * wrv[u];
                accr[1] += x0.z * wrv[u] - x0.w * wiv[u];
                acci[1] += x0.z * wiv[u] + x0.w * wrv[u];
                accr[2] += x1.x * wrv[u] - x1.y * wiv[u];
                acci[2] += x1.x * wiv[u] + x1.y * wrv[u];
                accr[3] += x1.z * wrv[u] - x1.w * wiv[u];
                acci[3] += x1.z * wiv[u] + x1.w * wrv[u];
                float4 x2 = *(const float4*)(xr + 8);
                float4 x3 = *(const float4*)(xr + 12);
                accr[4] += x2.x * wrv[u] - x2.y * wiv[u];
                acci[4] += x2.x * wiv[u] + x2.y * wrv[u];
                accr[5] += x2.z * wrv[u] - x2.w * wiv[u];
                acci[5] += x2.z * wiv[u] + x2.w * wrv[u];
                accr[6] += x3.x * wrv[u] - x3.y * wiv[u];
                acci[6] += x3.x * wiv[u] + x3.y * wrv[u];
                accr[7] += x3.z * wrv[u] - x3.w * wiv[u];
                acci[7] += x3.z * wiv[u] + x3.w * wrv[u];
            }
        }
    }
    float2* dst = (float2*)part + (size_t)is * 1048576;
    #pragma unroll
    for (int b = 0; b < 8; ++b)
        dst[(((size_t)b * 256 + o) * 32 + krow) * 16 + y] = make_float2(accr[b], acci[b]);
}

// irfft2 + gelu(x1 + conv-branch); sums 4 spectral partials inline. tmp[p][hw]
__global__ void __launch_bounds__(64) k_irfft_fuse(const float* __restrict__ part,
        const float* __restrict__ x2t, float* __restrict__ tmp) {
    __shared__ float F[32][16][2];
    __shared__ float tarr[64][16][2];
    __shared__ float twc[64], tws[64];
    int p = blockIdx.x;
    int t = threadIdx.x;
    const float2* s0 = (const float2*)part + (size_t)p * 512;
    #pragma unroll
    for (int l = 0; l < 8; ++l) {
        int idx = t + l * 64;
        float2 a = s0[idx];
        float2 b2 = s0[idx + 1048576];
        float2 c2 = s0[idx + 2097152];
        float2 d2 = s0[idx + 3145728];
        ((float2*)F)[idx] = make_float2(a.x + b2.x + c2.x + d2.x, a.y + b2.y + c2.y + d2.y);
    }
    twc[t] = cosf((float)t * (6.283185307179586f / 64.0f));
    tws[t] = sinf((float)t * (6.283185307179586f / 64.0f));
    __syncthreads();
    int h = t;
    for (int kw = 0; kw < 16; ++kw) {
        float re = 0.f, im = 0.f;
        #pragma unroll
        for (int krow = 0; krow < 32; ++krow) {
            int kh = krow < 16 ? krow : krow + 32;
            int j = (h * kh) & 63;
            float c = twc[j], s = tws[j];
            float fr = F[krow][kw][0], fi = F[krow][kw][1];
            re += fr * c - fi * s;
            im += fr * s + fi * c;
        }
        tarr[h][kw][0] = re * (1.f / 64.f);
        tarr[h][kw][1] = im * (1.f / 64.f);
    }
    __syncthreads();
    const float* x2p = x2t + (size_t)p * 4096;
    float* tp = tmp + (size_t)p * 4096;
    for (int q = 0; q < 64; ++q) {
        int w = t;
        float acc = tarr[q][0][0];
        #pragma unroll
        for (int kw = 1; kw < 16; ++kw) {
            int j = (w * kw) & 63;
            acc += 2.f * (tarr[q][kw][0] * twc[j] - tarr[q][kw][1] * tws[j]);
        }
        float x1 = acc * (1.f / 64.f);
        int idx = q * 64 + w;
        tp[idx] = gelu_f(x1 + x2p[idx]);
    }
}

// transpose tmp [b][d][n] -> out[b][n][d] = cw0*(tmp + x)
__global__ void k_fno_final(const float* __restrict__ tmp, const float* __restrict__ x,
        const float* __restrict__ cw, float* __restrict__ out) {
    __shared__ float tile[32][33];
    int b = blockIdx.z;
    int n0 = blockIdx.x * 32, d0 = blockIdx.y * 32;
    int tx = threadIdx.x, ty = threadIdx.y;
    const float* tb = tmp + (size_t)b * DD * NN;
    #pragma unroll
    for (int i = 0; i < 4; ++i)
        tile[ty + i * 8][tx] = tb[(size_t)(d0 + ty + i * 8) * NN + n0 + tx];
    __syncthreads();
    float cw0 = cw[b * 4];
    #pragma unroll
    for (int i = 0; i < 4; ++i) {
        int n = n0 + ty + i * 8, d = d0 + tx;
        size_t g = ((size_t)b * NN + n) * DD + d;
        out[g] = cw0 * (tile[tx][ty + i * 8] + x[g]);
    }
}

// ---------------- layernorm (f32 in, bf16 out) ----------------
__global__ void __launch_bounds__(256) k_ln(const float* __restrict__ in, const float* __restrict__ g,
        const float* __restrict__ be, ushort* __restrict__ outb) {
    int row = blockIdx.x * 4 + (threadIdx.x >> 6);
    int lane = threadIdx.x & 63;
    const float4* rp = (const float4*)(in + (size_t)row * 256);
    float4 v = rp[lane];
    float s = v.x + v.y + v.z + v.w;
    float s2 = v.x * v.x + v.y * v.y + v.z * v.z + v.w * v.w;
    #pragma unroll
    for (int off = 32; off > 0; off >>= 1) {
        s += __shfl_down(s, off);
        s2 += __shfl_down(s2, off);
    }
    s = __shfl(s, 0); s2 = __shfl(s2, 0);
    float mu = s * (1.f / 256.f);
    float var = s2 * (1.f / 256.f) - mu * mu;
    float rstd = rsqrtf(var + 1e-5f);
    float4 gv = ((const float4*)g)[lane];
    float4 bv = ((const float4*)be)[lane];
    ushort4 ov;
    ov.x = f2bf((v.x - mu) * rstd * gv.x + bv.x);
    ov.y = f2bf((v.y - mu) * rstd * gv.y + bv.y);
    ov.z = f2bf((v.z - mu) * rstd * gv.z + bv.z);
    ov.w = f2bf((v.w - mu) * rstd * gv.w + bv.w);
    ((ushort4*)(outb + (size_t)row * 256))[lane] = ov;
}

// ---------------- MFMA window attention ----------------
// grid (512 windows, 2 head-halves), block 256 = 4 waves; wave w -> head hh*4+w.
// Per-wave LDS arena (7424 ushorts): phase1 Q[64][40]@0, K[64][40]@2560, Vt[32][72]@5120;
// phase2 P[64][72]@0 (overlaps Q+K); epilogue Ot[64][40]@0.
__global__ void __launch_bounds__(256) k_window_attn(const ushort* __restrict__ qkvb,
        ushort* __restrict__ aob) {
    __shared__ ushort lds[4 * 7424];
    int t = threadIdx.x;
    int w = t >> 6, lane = t & 63;
    int wi = blockIdx.x, hh = blockIdx.y;
    int hd = hh * 4 + w;
    int b = wi >> 6, hb = (wi >> 3) & 7, wb = wi & 7;
    ushort* A = lds + w * 7424;
    ushort* Kl = A + 2560;
    ushort* Vt = A + 5120;
    int rlo = lane & 15, kq = lane >> 4;

    // stage Q,K (row-major) and V (transposed); lane = token
    int tok = lane;
    int n = hb * 512 + wb * 8 + ((tok >> 3) << 6) + (tok & 7);
    const ushort* gq = qkvb + ((size_t)b * 4096 + n) * 768 + hd * 32;
    const uint4* qp = (const uint4*)gq;
    const uint4* kp = (const uint4*)(gq + 256);
    const uint4* vp = (const uint4*)(gq + 512);
    uint4 q0 = qp[0], q1 = qp[1], q2 = qp[2], q3 = qp[3];
    uint4 k0 = kp[0], k1 = kp[1], k2 = kp[2], k3 = kp[3];
    uint4 v0 = vp[0], v1 = vp[1], v2 = vp[2], v3 = vp[3];
    uint4* qr = (uint4*)(A + tok * 40);
    qr[0] = q0; qr[1] = q1; qr[2] = q2; qr[3] = q3;
    uint4* kr = (uint4*)(Kl + tok * 40);
    kr[0] = k0; kr[1] = k1; kr[2] = k2; kr[3] = k3;
    ushort vbuf[32];
    *(uint4*)&vbuf[0] = v0; *(uint4*)&vbuf[8] = v1;
    *(uint4*)&vbuf[16] = v2; *(uint4*)&vbuf[24] = v3;
    #pragma unroll
    for (int d = 0; d < 32; ++d) Vt[d * 72 + tok] = vbuf[d];
    __syncthreads();

    // fragments
    bf16x8 Qf[4], Kf[4];
    #pragma unroll
    for (int lt = 0; lt < 4; ++lt)
        Qf[lt] = *(const bf16x8*)(A + (lt * 16 + rlo) * 40 + kq * 8);
    #pragma unroll
    for (int mt = 0; mt < 4; ++mt)
        Kf[mt] = *(const bf16x8*)(Kl + (mt * 16 + rlo) * 40 + kq * 8);

    // scores
    f32x4 S[4][4];
    #pragma unroll
    for (int lt = 0; lt < 4; ++lt)
        #pragma unroll
        for (int mt = 0; mt < 4; ++mt)
            S[lt][mt] = __builtin_amdgcn_mfma_f32_16x16x32_bf16(Qf[lt], Kf[mt],
                        (f32x4){0.f, 0.f, 0.f, 0.f}, 0, 0, 0);
    __syncthreads();

    // softmax rows (row l = lt*16 + kq*4 + j, col m = mt*16 + rlo); write P bf16
    const float scale = 0.17677669529663687f;  // 1/sqrt(32)
    float inv_[4][4];
    #pragma unroll
    for (int lt = 0; lt < 4; ++lt) {
        float m4[4], s4[4];
        #pragma unroll
        for (int j = 0; j < 4; ++j) {
            m4[j] = fmaxf(fmaxf(S[lt][0][j], S[lt][1][j]), fmaxf(S[lt][2][j], S[lt][3][j]));
        }
        #pragma unroll
        for (int off = 1; off < 16; off <<= 1)
            #pragma unroll
            for (int j = 0; j < 4; ++j) m4[j] = fmaxf(m4[j], __shfl_xor(m4[j], off));
        #pragma unroll
        for (int j = 0; j < 4; ++j) s4[j] = 0.f;
        #pragma unroll
        for (int mt = 0; mt < 4; ++mt)
            #pragma unroll
            for (int j = 0; j < 4; ++j) {
                float p = expf((S[lt][mt][j] - m4[j]) * scale);
                s4[j] += p;
                A[(lt * 16 + kq * 4 + j) * 72 + mt * 16 + rlo] = f2bf(p);
            }
        #pragma unroll
        for (int off = 1; off < 16; off <<= 1)
            #pragma unroll
            for (int j = 0; j < 4; ++j) s4[j] += __shfl_xor(s4[j], off);
        #pragma unroll
        for (int j = 0; j < 4; ++j) inv_[lt][j] = 1.0f / s4[j];
    }
    __syncthreads();

    // PV: O[lt][dt] += P[lt][mc] @ V[mc][dt]
    f32x4 O[4][2];
    #pragma unroll
    for (int lt = 0; lt < 4; ++lt)
        #pragma unroll
        for (int dt = 0; dt < 2; ++dt) {
            f32x4 o = (f32x4){0.f, 0.f, 0.f, 0.f};
            #pragma unroll
            for (int mc = 0; mc < 2; ++mc) {
                bf16x8 pa = *(const bf16x8*)(A + (lt * 16 + rlo) * 72 + mc * 32 + kq * 8);
                bf16x8 vb = *(const bf16x8*)(Vt + (dt * 16 + rlo) * 72 + mc * 32 + kq * 8);
                o = __builtin_amdgcn_mfma_f32_16x16x32_bf16(pa, vb, o, 0, 0, 0);
            }
            O[lt][dt] = o;
        }
    __syncthreads();

    // repack O through LDS (Ot[64][40] @ A) and write coalesced 64B per token
    #pragma unroll
    for (int lt = 0; lt < 4; ++lt)
        #pragma unroll
        for (int dt = 0; dt < 2; ++dt)
            #pragma unroll
            for (int j = 0; j < 4; ++j)
                A[(lt * 16 + kq * 4 + j) * 40 + dt * 16 + rlo] = f2bf(O[lt][dt][j] * inv_[lt][j]);
    __syncthreads();
    const uint4* orow = (const uint4*)(A + lane * 40);
    uint4 o0 = orow[0], o1 = orow[1], o2 = orow[2], o3 = orow[3];
    uint4* gout = (uint4*)(aob + ((size_t)b * 4096 + n) * 256 + hd * 32);
    gout[0] = o0; gout[1] = o1; gout[2] = o2; gout[3] = o3;
}

extern "C" void kernel_launch(void* const* d_in, const int* in_sizes, int n_in,
                              void* d_out, int out_size, void* d_ws, size_t ws_size,
                              hipStream_t stream) {
    (void)in_sizes; (void)n_in; (void)out_size; (void)ws_size;
    const float* x        = (const float*)d_in[0];
    const float* text     = (const float*)d_in[1];
    const float* gate_w1  = (const float*)d_in[2];
    const float* gate_b1  = (const float*)d_in[3];
    const float* gate_w2  = (const float*)d_in[4];
    const float* gate_b2  = (const float*)d_in[5];
    const float* fno_w1r  = (const float*)d_in[6];
    const float* fno_w1i  = (const float*)d_in[7];
    const float* fno_w2r  = (const float*)d_in[8];
    const float* fno_w2i  = (const float*)d_in[9];
    const float* fno_cw   = (const float*)d_in[10];
    const float* fno_cb   = (const float*)d_in[11];
    const float* mlp1_w1  = (const float*)d_in[12];
    const float* mlp1_b1  = (const float*)d_in[13];
    const float* mlp1_w2  = (const float*)d_in[14];
    const float* mlp1_b2  = (const float*)d_in[15];
    const float* mlp2_w1  = (const float*)d_in[16];
    const float* mlp2_b1  = (const float*)d_in[17];
    const float* mlp2_w2  = (const float*)d_in[18];
    const float* mlp2_b2  = (const float*)d_in[19];
    const float* ln1_g    = (const float*)d_in[20];
    const float* ln1_b    = (const float*)d_in[21];
    const float* qkv_w    = (const float*)d_in[22];
    const float* qkv_b    = (const float*)d_in[23];
    const float* out_w    = (const float*)d_in[24];
    const float* out_b    = (const float*)d_in[25];
    const float* ln2_g    = (const float*)d_in[26];
    const float* ln2_b    = (const float*)d_in[27];
    const float* wa_w1    = (const float*)d_in[28];
    const float* wa_b1    = (const float*)d_in[29];
    const float* wa_w2    = (const float*)d_in[30];
    const float* wa_b2    = (const float*)d_in[31];

    float* ws   = (float*)d_ws;
    float* feat = ws;                // 8192
    float* h1   = ws + 8192;         // 2048
    float* cwp  = ws + 10240;        // 32
    ushort* wbf = (ushort*)(ws + 16384);     // weight bf16 pool
    ushort* w1aT = wbf;
    ushort* w2aT = w1aT + 262144;
    ushort* w1bT = w2aT + 262144;
    ushort* w2bT = w1bT + 262144;
    ushort* w1cT = w2bT + 262144;
    ushort* w2cT = w1cT + 262144;
    ushort* qkvT = w2cT + 262144;
    ushort* outwT = qkvT + 196608;
    ushort* convT = outwT + 65536;
    ushort* Xbf  = (ushort*)(ws + 16384 + 1048576);          // bf16 x
    float* slotA = ws + 16384 + 1048576 + 4194304;           // 8.39M floats (xg / spectral-partials / abf)
    ushort* abf  = (ushort*)slotA;
    float* xft   = slotA + 8388608;                          // 2.1M
    float* oft   = xft + 2097152;                            // 2.1M (gate partials only now)
    float* regD  = oft + 2097152;                            // 8.39M (x2t / xattn)
    ushort* bigb = (ushort*)(regD + 8388608);                // tmp / qkv-bf16 / hidden-bf16
    float* gpart = oft;

    float* outp = (float*)d_out;
    float* wout = outp + (size_t)NB * NN * DD;

    // gating
    k_gate_mean1<<<dim3(32, 8), 256, 0, stream>>>(x, gpart);
    k_gate_mean2<<<8, 256, 0, stream>>>(gpart, text, feat);
    k_gate_mlp1<<<8, 256, 0, stream>>>(feat, gate_w1, gate_b1, h1);
    k_gate_top<<<1, 64, 0, stream>>>(h1, gate_w2, gate_b2, cwp, wout);

    // prep: bf16 conversions
    k_cvtbf<<<8192, 256, 0, stream>>>(x, Xbf);
    dim3 wtb(32, 8);
    k_wt<<<dim3(32, 8), wtb, 0, stream>>>(mlp1_w1, w1aT, 256, 1024);
    k_wt<<<dim3(8, 32), wtb, 0, stream>>>(mlp1_w2, w2aT, 1024, 256);
    k_wt<<<dim3(32, 8), wtb, 0, stream>>>(mlp2_w1, w1bT, 256, 1024);
    k_wt<<<dim3(8, 32), wtb, 0, stream>>>(mlp2_w2, w2bT, 1024, 256);
    k_wt<<<dim3(32, 8), wtb, 0, stream>>>(wa_w1, w1cT, 256, 1024);
    k_wt<<<dim3(8, 32), wtb, 0, stream>>>(wa_w2, w2cT, 1024, 256);
    k_wt<<<dim3(24, 8), wtb, 0, stream>>>(qkv_w, qkvT, 256, 768);
    k_wt<<<dim3(8, 8), wtb, 0, stream>>>(out_w, outwT, 256, 256);
    k_wt<<<dim3(8, 8), wtb, 0, stream>>>(fno_cw, convT, 256, 256);

    // expert 0: FNO (channel-major pipeline; final kernel writes all of out)
    k_transpose<<<dim3(128, 8, 8), dim3(32, 8), 0, stream>>>(x, slotA);
    k_rfft2<<<2048, 64, 0, stream>>>(slotA, xft);
    k_gemm<4><<<dim3(2, 32, 8), 256, 0, stream>>>(convT, Xbf, fno_cb, nullptr, regD, nullptr,
        nullptr, 0, 256, 4096, 0, (size_t)NN * DD, (size_t)DD * NN);
    // spectral partials into slotA (xg dead after rfft2); irfft sums them inline, tmp -> bigb
    k_spectral<<<dim3(8, 16, 8), 512, 0, stream>>>(xft, fno_w1r, fno_w1i, fno_w2r, fno_w2i, slotA);
    k_irfft_fuse<<<2048, 64, 0, stream>>>(slotA, regD, (float*)bigb);
    k_fno_final<<<dim3(128, 8, 8), dim3(32, 8), 0, stream>>>((float*)bigb, x, cwp, outp);

    // expert 1: MLP
    k_gemm<0><<<dim3(256, 8), 256, 0, stream>>>(Xbf, w1aT, mlp1_b1, nullptr, nullptr, bigb, nullptr, 0, 256, 1024, 0, 0, 0);
    k_gemm<3><<<dim3(256, 2), 256, 0, stream>>>(bigb, w2aT, mlp1_b2, x, outp, nullptr, cwp, 1, 1024, 256, 0, 0, 0);

    // expert 2: window attention
    k_ln<<<8192, 256, 0, stream>>>(x, ln1_g, ln1_b, abf);
    k_gemm<1><<<dim3(256, 6), 256, 0, stream>>>(abf, qkvT, qkv_b, nullptr, nullptr, bigb, nullptr, 0, 256, 768, 0, 0, 0);
    k_window_attn<<<dim3(512, 2), 256, 0, stream>>>(bigb, abf);
    k_gemm<2><<<dim3(256, 2), 256, 0, stream>>>(abf, outwT, out_b, x, regD, nullptr, nullptr, 0, 256, 256, 0, 0, 0);
    k_ln<<<8192, 256, 0, stream>>>(regD, ln2_g, ln2_b, abf);
    k_gemm<0><<<dim3(256, 8), 256, 0, stream>>>(abf, w1cT, wa_b1, nullptr, nullptr, bigb, nullptr, 0, 256, 1024, 0, 0, 0);
    k_gemm<3><<<dim3(256, 2), 256, 0, stream>>>(bigb, w2cT, wa_b2, regD, outp, nullptr, cwp, 2, 1024, 256, 0, 0, 0);

    // expert 3: MLP
    k_gemm<0><<<dim3(256, 8), 256, 0, stream>>>(Xbf, w1bT, mlp2_b1, nullptr, nullptr, bigb, nullptr, 0, 256, 1024, 0, 0, 0);
    k_gemm<3><<<dim3(256, 2), 256, 0, stream>>>(bigb, w2bT, mlp2_b2, x, outp, nullptr, cwp, 3, 1024, 256, 0, 0, 0);
}

// Round 8
// 694.887 us; speedup vs baseline: 3.9073x; 1.0263x over previous
//
#include <hip/hip_runtime.h>
#include <math.h>

// MoEProcessor: B=8, N=4096, D=256, H=W=64, WS=8, NH=8, M=16, E=4, TD=768, HID=1024, TK=2
// Round 8: MFMA spectral contraction (LDS-transposed bf16 weights, 2 i-halves),
// bf16 x2t (GEMM MODE 5) and bf16 tmp in the FNO tail. Rest identical to R7.

#define NB 8
#define NN 4096
#define DD 256

typedef __attribute__((ext_vector_type(8))) short bf16x8;
typedef __attribute__((ext_vector_type(4))) float f32x4;

__device__ __forceinline__ float gelu_f(float v) {
    return 0.5f * v * (1.0f + erff(v * 0.7071067811865475f));
}
__device__ __forceinline__ ushort f2bf(float f) {
    uint32_t u = __float_as_uint(f);
    uint32_t r = (u + 0x7fffu + ((u >> 16) & 1u)) >> 16;
    return (ushort)r;
}
__device__ __forceinline__ float b2f(ushort h) {
    return __uint_as_float(((uint32_t)h) << 16);
}

// ---------------- gating ----------------
__global__ void k_gate_mean1(const float* __restrict__ x, float* __restrict__ partial) {
    int c = blockIdx.x, b = blockIdx.y;
    int t = threadIdx.x;
    const float* xb = x + ((size_t)b * NN + c * 128) * DD;
    float s = 0.f;
    for (int n = 0; n < 128; ++n) s += xb[(size_t)n * DD + t];
    partial[((size_t)b * 32 + c) * 256 + t] = s;
}
__global__ void k_gate_mean2(const float* __restrict__ partial, const float* __restrict__ text,
                             float* __restrict__ feat) {
    int b = blockIdx.x, t = threadIdx.x;
    float s = 0.f;
    for (int c = 0; c < 32; ++c) s += partial[((size_t)b * 32 + c) * 256 + t];
    feat[b * 1024 + t] = s * (1.0f / NN);
    for (int j = t; j < 768; j += 256) feat[b * 1024 + 256 + j] = text[b * 768 + j];
}

__global__ void k_gate_mlp1(const float* __restrict__ feat, const float* __restrict__ w1,
                            const float* __restrict__ b1, float* __restrict__ h1) {
    int b = blockIdx.x, j = threadIdx.x;
    float acc = b1[j];
    const float* f = feat + b * 1024;
    for (int k = 0; k < 1024; ++k) acc += f[k] * w1[k * 256 + j];
    h1[b * 256 + j] = fmaxf(acc, 0.f);
}

__global__ void k_gate_top(const float* __restrict__ h1, const float* __restrict__ w2,
                           const float* __restrict__ b2, float* __restrict__ cw,
                           float* __restrict__ wout) {
    __shared__ float lg[8][4];
    int t = threadIdx.x;
    if (t < 32) {
        int b = t >> 2, e = t & 3;
        float acc = b2[e];
        const float* h = h1 + b * 256;
        for (int k = 0; k < 256; ++k) acc += h[k] * w2[k * 4 + e];
        lg[b][e] = acc;
    }
    __syncthreads();
    if (t < 8) {
        int b = t;
        float v[4];
        #pragma unroll
        for (int e = 0; e < 4; ++e) v[e] = lg[b][e];
        int i0 = 0;
        #pragma unroll
        for (int e = 1; e < 4; ++e) if (v[e] > v[i0]) i0 = e;
        int i1 = -1;
        #pragma unroll
        for (int e = 0; e < 4; ++e) {
            if (e == i0) continue;
            if (i1 < 0 || v[e] > v[i1]) i1 = e;
        }
        float v0 = v[i0], v1 = v[i1];
        float e1v = expf(v1 - v0);
        float inv = 1.0f / (1.0f + e1v);
        float w0 = inv, w1v = e1v * inv;
        wout[b * 2 + 0] = w0;
        wout[b * 2 + 1] = w1v;
        float c[4] = {0.f, 0.f, 0.f, 0.f};
        c[i0] += w0; c[i1] += w1v;
        #pragma unroll
        for (int e = 0; e < 4; ++e) cw[b * 4 + e] = c[e];
    }
}

// ---------------- prep: f32 -> bf16 ----------------
__global__ void k_cvtbf(const float* __restrict__ src, ushort* __restrict__ dst) {
    int i = blockIdx.x * 256 + threadIdx.x;
    float4 v = ((const float4*)src)[i];
    ushort4 o;
    o.x = f2bf(v.x); o.y = f2bf(v.y); o.z = f2bf(v.z); o.w = f2bf(v.w);
    ((ushort4*)dst)[i] = o;
}

// transpose+convert: src f32 [K][N] -> dst bf16 [N][K]
__global__ void k_wt(const float* __restrict__ src, ushort* __restrict__ dst, int K, int N) {
    __shared__ float tile[32][33];
    int n0 = blockIdx.x * 32, k0 = blockIdx.y * 32;
    int tx = threadIdx.x, ty = threadIdx.y;
    #pragma unroll
    for (int i = 0; i < 4; ++i)
        tile[ty + i * 8][tx] = src[(size_t)(k0 + ty + i * 8) * N + n0 + tx];
    __syncthreads();
    #pragma unroll
    for (int i = 0; i < 4; ++i)
        dst[(size_t)(n0 + ty + i * 8) * K + k0 + tx] = f2bf(tile[tx][ty + i * 8]);
}

// ---------------- MFMA GEMM ----------------
// MODE 0: outb = bf16(gelu(acc+colbias))
// MODE 1: outb = bf16(acc+colbias)
// MODE 2: outf = acc+colbias (+res)
// MODE 3: outf += cw[b,eidx]*(acc+colbias+res)
// MODE 4: outf = acc+rowbias  (batched)
// MODE 5: outb = bf16(acc+rowbias)  (batched)
template<int MODE>
__global__ void __launch_bounds__(256) k_gemm(const ushort* __restrict__ A,
        const ushort* __restrict__ Bt, const float* __restrict__ bias,
        const float* __restrict__ res, float* __restrict__ outf,
        ushort* __restrict__ outb, const float* __restrict__ cw, int eidx,
        int K, int Ncols, size_t bsA, size_t bsB, size_t bsC) {
    __shared__ alignas(16) char smem[32768];
    ushort* sA = (ushort*)smem;            // [2][4096]
    ushort* sB = (ushort*)(smem + 16384);  // [2][4096]
    int z = blockIdx.z;
    A += z * bsA; Bt += z * bsB;
    if (outf) outf += z * bsC;
    if (outb) outb += z * bsC;
    int m0 = blockIdx.x * 128;
    int n0 = blockIdx.y * 128;
    int t = threadIdx.x;
    int lane = t & 63, wid = t >> 6;
    int wr = wid >> 1, wc = wid & 1;
    int rlo = lane & 15, khi = (lane >> 4) * 8;

    auto stage = [&](int buf, int k0) {
        const ushort* Ab = A + (size_t)m0 * K + k0;
        const ushort* Bb = Bt + (size_t)n0 * K + k0;
        #pragma unroll
        for (int h = 0; h < 2; ++h) {
            int s = t + h * 256;
            int row = s >> 2, kc = (s & 3) * 8;
            __builtin_amdgcn_global_load_lds(
                (const __attribute__((address_space(1))) void*)(Ab + (size_t)row * K + kc),
                (__attribute__((address_space(3))) void*)(sA + buf * 4096 + s * 8),
                16, 0, 0);
            __builtin_amdgcn_global_load_lds(
                (const __attribute__((address_space(1))) void*)(Bb + (size_t)row * K + kc),
                (__attribute__((address_space(3))) void*)(sB + buf * 4096 + s * 8),
                16, 0, 0);
        }
    };

    f32x4 acc[4][4];
    #pragma unroll
    for (int i = 0; i < 4; ++i)
        #pragma unroll
        for (int j = 0; j < 4; ++j) acc[i][j] = (f32x4){0.f, 0.f, 0.f, 0.f};

    int KT = K >> 5;
    stage(0, 0);
    int cur = 0;
    for (int kt = 0; kt < KT; ++kt) {
        __syncthreads();
        if (kt + 1 < KT) stage(cur ^ 1, (kt + 1) << 5);
        const ushort* Ap = sA + cur * 4096;
        const ushort* Bp = sB + cur * 4096;
        bf16x8 af[4], bfr[4];
        #pragma unroll
        for (int i = 0; i < 4; ++i) {
            af[i]  = *(const bf16x8*)(Ap + (wr * 64 + i * 16 + rlo) * 32 + khi);
            bfr[i] = *(const bf16x8*)(Bp + (wc * 64 + i * 16 + rlo) * 32 + khi);
        }
        #pragma unroll
        for (int i = 0; i < 4; ++i)
            #pragma unroll
            for (int j = 0; j < 4; ++j)
                acc[i][j] = __builtin_amdgcn_mfma_f32_16x16x32_bf16(af[i], bfr[j], acc[i][j], 0, 0, 0);
        cur ^= 1;
    }

    float bj4[4];
    if constexpr (MODE != 4 && MODE != 5) {
        #pragma unroll
        for (int nt = 0; nt < 4; ++nt) bj4[nt] = bias[n0 + wc * 64 + nt * 16 + rlo];
    }

    if constexpr (MODE == 0 || MODE == 1 || MODE == 5) {
        ushort* eb = (ushort*)smem;  // [32][136]
        #pragma unroll
        for (int mt = 0; mt < 4; ++mt) {
            __syncthreads();
            #pragma unroll
            for (int nt = 0; nt < 4; ++nt) {
                int col = wc * 64 + nt * 16 + rlo;
                #pragma unroll
                for (int j = 0; j < 4; ++j) {
                    float v = acc[mt][nt][j];
                    if constexpr (MODE == 5)
                        v += bias[m0 + wr * 64 + mt * 16 + (lane >> 4) * 4 + j];
                    else
                        v += bj4[nt];
                    if (MODE == 0) v = gelu_f(v);
                    eb[(wr * 16 + (lane >> 4) * 4 + j) * 136 + col] = f2bf(v);
                }
            }
            __syncthreads();
            #pragma unroll
            for (int h = 0; h < 2; ++h) {
                int s = t + h * 256;
                int r = s >> 4, c = (s & 15) * 8;
                int grow = m0 + (r >> 4) * 64 + mt * 16 + (r & 15);
                *(uint4*)(outb + (size_t)grow * Ncols + n0 + c) = *(uint4*)&eb[r * 136 + c];
            }
        }
    } else {
        float* ep = (float*)smem;  // [32][132]
        #pragma unroll
        for (int mt = 0; mt < 4; ++mt) {
            __syncthreads();
            #pragma unroll
            for (int nt = 0; nt < 4; ++nt) {
                int col = wc * 64 + nt * 16 + rlo;
                #pragma unroll
                for (int j = 0; j < 4; ++j) {
                    float v = acc[mt][nt][j];
                    if constexpr (MODE == 4)
                        v += bias[m0 + wr * 64 + mt * 16 + (lane >> 4) * 4 + j];
                    else
                        v += bj4[nt];
                    ep[(wr * 16 + (lane >> 4) * 4 + j) * 132 + col] = v;
                }
            }
            __syncthreads();
            #pragma unroll
            for (int h = 0; h < 4; ++h) {
                int s = t + h * 256;
                int r = s >> 5, c4 = (s & 31) * 4;
                int grow = m0 + (r >> 4) * 64 + mt * 16 + (r & 15);
                size_t g = (size_t)grow * Ncols + n0 + c4;
                float4 v = *(float4*)&ep[r * 132 + c4];
                if constexpr (MODE == 2) {
                    if (res) {
                        float4 rv = *(const float4*)&res[g];
                        v.x += rv.x; v.y += rv.y; v.z += rv.z; v.w += rv.w;
                    }
                    *(float4*)&outf[g] = v;
                } else if constexpr (MODE == 4) {
                    *(float4*)&outf[g] = v;
                } else {
                    float cwv = cw[(grow >> 12) * 4 + eidx];
                    float4 rv = *(const float4*)&res[g];
                    float4 ov = *(float4*)&outf[g];
                    ov.x += cwv * (v.x + rv.x);
                    ov.y += cwv * (v.y + rv.y);
                    ov.z += cwv * (v.z + rv.z);
                    ov.w += cwv * (v.w + rv.w);
                    *(float4*)&outf[g] = ov;
                }
            }
        }
    }
}

// ---------------- FNO ----------------
__global__ void k_transpose(const float* __restrict__ x, float* __restrict__ xg) {
    __shared__ float tile[32][33];
    int b = blockIdx.z;
    int nt = blockIdx.x, dt = blockIdx.y;
    int tx = threadIdx.x, ty = threadIdx.y;
    const float* xb = x + (size_t)b * NN * DD;
    float* xgb = xg + (size_t)b * DD * NN;
    #pragma unroll
    for (int i = 0; i < 4; ++i) {
        int n = nt * 32 + ty + i * 8;
        tile[ty + i * 8][tx] = xb[(size_t)n * DD + dt * 32 + tx];
    }
    __syncthreads();
    #pragma unroll
    for (int i = 0; i < 4; ++i) {
        int d = dt * 32 + ty + i * 8;
        xgb[(size_t)d * NN + nt * 32 + tx] = tile[tx][ty + i * 8];
    }
}

__global__ void __launch_bounds__(64) k_rfft2(const float* __restrict__ xg, float* __restrict__ xft) {
    __shared__ float plane[64][65];
    __shared__ float s1[64][16][2];
    __shared__ float twc[64], tws[64];
    int p = blockIdx.x;
    int t = threadIdx.x;
    const float* src = xg + (size_t)p * 4096;
    for (int i = 0; i < 64; ++i) plane[i][t] = src[i * 64 + t];
    twc[t] = cosf((float)t * (6.283185307179586f / 64.0f));
    tws[t] = sinf((float)t * (6.283185307179586f / 64.0f));
    __syncthreads();
    int r = t;
    for (int kw = 0; kw < 16; ++kw) {
        float re = 0.f, im = 0.f;
        for (int w = 0; w < 64; ++w) {
            int j = (w * kw) & 63;
            float xv = plane[r][w];
            re += xv * twc[j];
            im -= xv * tws[j];
        }
        s1[r][kw][0] = re; s1[r][kw][1] = im;
    }
    __syncthreads();
    float2* dst = (float2*)xft + (size_t)p * 512;
    #pragma unroll
    for (int q = 0; q < 8; ++q) {
        int oi = t + q * 64;
        int krow = oi >> 4, kw = oi & 15;
        int kh = krow < 16 ? krow : krow + 32;
        float re = 0.f, im = 0.f;
        for (int h = 0; h < 64; ++h) {
            int j = (h * kh) & 63;
            float c = twc[j], s = tws[j];
            float ar = s1[h][kw][0], ai = s1[h][kw][1];
            re += ar * c + ai * s;
            im += ai * c - ar * s;
        }
        dst[oi] = make_float2(re, im);
    }
}

// ---------------- MFMA spectral ----------------
// grid (16 otile, 16 xm, 4 = region*2 + is), block 512 (8 waves).
// Per mode (krow, y): out[16 o][16 pack] += W[16 o][i] * Xpack[16][i], pack = [8 re; 8 im].
// LDS: Wl[(y*2+arr)][16 o][40 i-pad] bf16, Xl[16 p][16 y][40] bf16 (p-stride 648).
__global__ void __launch_bounds__(512) k_spectral(const float* __restrict__ xft,
        const float* __restrict__ w1r, const float* __restrict__ w1i,
        const float* __restrict__ w2r, const float* __restrict__ w2i,
        float* __restrict__ part) {
    __shared__ alignas(16) ushort Wl[32 * 648];   // 41472 B
    __shared__ alignas(16) ushort Xl[16 * 648];   // 20736 B
    int z = blockIdx.z;
    int region = z >> 1, is = z & 1;
    const float* wrp = region ? w2r : w1r;
    const float* wip = region ? w2i : w1i;
    int xm = blockIdx.y;
    int krow = region * 16 + xm;
    int o0 = blockIdx.x * 16;
    int t = threadIdx.x;
    int wv = t >> 6, lane = t & 63;
    int rlo = lane & 15, khi = lane >> 4;
    int ibase = is * 128;

    f32x4 acc[2][2];  // [yy][arr]
    #pragma unroll
    for (int a = 0; a < 2; ++a)
        #pragma unroll
        for (int b = 0; b < 2; ++b) acc[a][b] = (f32x4){0.f, 0.f, 0.f, 0.f};

    for (int ch = 0; ch < 4; ++ch) {
        int i0 = ibase + ch * 32;
        __syncthreads();
        // stage W: 1024 macro-groups (arr, i8, o, y4), 2 per thread
        #pragma unroll
        for (int s = 0; s < 2; ++s) {
            int m = t + s * 512;
            int y4 = m & 3, ol = (m >> 2) & 15, i8 = (m >> 6) & 7, arr = m >> 9;
            const float* wsrc = arr ? wip : wrp;
            int ig = i0 + i8 * 4;
            float4 f[4];
            #pragma unroll
            for (int u = 0; u < 4; ++u)
                f[u] = *(const float4*)&wsrc[((size_t)(ig + u) * 256 + o0 + ol) * 256 + xm * 16 + y4 * 4];
            #pragma unroll
            for (int yy2 = 0; yy2 < 4; ++yy2) {
                int y = y4 * 4 + yy2;
                ushort4 pk;
                pk.x = f2bf(((const float*)&f[0])[yy2]);
                pk.y = f2bf(((const float*)&f[1])[yy2]);
                pk.z = f2bf(((const float*)&f[2])[yy2]);
                pk.w = f2bf(((const float*)&f[3])[yy2]);
                *(ushort4*)&Wl[(y * 2 + arr) * 648 + ol * 40 + i8 * 4] = pk;
            }
        }
        // stage X: 1024 macro-groups (b, i4, y), 2 per thread
        #pragma unroll
        for (int s = 0; s < 2; ++s) {
            int m = t + s * 512;
            int y = m & 15, i4 = (m >> 4) & 7, b = (m >> 7) & 7;
            int ig = i0 + i4 * 4;
            float2 g[4];
            #pragma unroll
            for (int u = 0; u < 4; ++u)
                g[u] = *(const float2*)&xft[(((size_t)(b * 256 + ig + u)) * 32 + krow) * 32 + y * 2];
            ushort4 re, im;
            re.x = f2bf(g[0].x); re.y = f2bf(g[1].x); re.z = f2bf(g[2].x); re.w = f2bf(g[3].x);
            im.x = f2bf(g[0].y); im.y = f2bf(g[1].y); im.z = f2bf(g[2].y); im.w = f2bf(g[3].y);
            *(ushort4*)&Xl[b * 648 + y * 40 + i4 * 4] = re;
            *(ushort4*)&Xl[(b + 8) * 648 + y * 40 + i4 * 4] = im;
        }
        __syncthreads();
        // compute: wave wv handles y = wv*2 + {0,1}
        #pragma unroll
        for (int yy = 0; yy < 2; ++yy) {
            int y = wv * 2 + yy;
            bf16x8 Bf = *(const bf16x8*)&Xl[rlo * 648 + y * 40 + khi * 8];
            #pragma unroll
            for (int arr = 0; arr < 2; ++arr) {
                bf16x8 Af = *(const bf16x8*)&Wl[(y * 2 + arr) * 648 + rlo * 40 + khi * 8];
                acc[yy][arr] = __builtin_amdgcn_mfma_f32_16x16x32_bf16(Af, Bf, acc[yy][arr], 0, 0, 0);
            }
        }
    }

    // epilogue: C1 = W_r*X, C2 = W_i*X; outr = C1[.,b] - C2[.,b+8]; outi = C2[.,b] + C1[.,b+8]
    float* dp = part + (size_t)is * 4194304;
    int c = rlo;
    int b = c & 7, hi = c >> 3;
    #pragma unroll
    for (int yy = 0; yy < 2; ++yy) {
        int y = wv * 2 + yy;
        #pragma unroll
        for (int j = 0; j < 4; ++j) {
            float C1 = acc[yy][0][j];
            float c2x = __shfl_xor(acc[yy][1][j], 8);
            float val = hi ? (c2x + C1) : (C1 - c2x);
            int o = o0 + khi * 4 + j;
            dp[(((size_t)(b * 256 + o) * 32 + krow) * 16 + y) * 2 + hi] = val;
        }
    }
}

// irfft2 + gelu(x1 + conv-branch); sums 2 spectral partials inline. bf16 x2t in, bf16 tmp out.
__global__ void __launch_bounds__(64) k_irfft_fuse(const float* __restrict__ part,
        const ushort* __restrict__ x2t, ushort* __restrict__ tmp) {
    __shared__ float F[32][16][2];
    __shared__ float tarr[64][16][2];
    __shared__ float twc[64], tws[64];
    int p = blockIdx.x;
    int t = threadIdx.x;
    const float2* s0 = (const float2*)part + (size_t)p * 512;
    #pragma unroll
    for (int l = 0; l < 8; ++l) {
        int idx = t + l * 64;
        float2 a = s0[idx];
        float2 b2 = s0[idx + 2097152];
        ((float2*)F)[idx] = make_float2(a.x + b2.x, a.y + b2.y);
    }
    twc[t] = cosf((float)t * (6.283185307179586f / 64.0f));
    tws[t] = sinf((float)t * (6.283185307179586f / 64.0f));
    __syncthreads();
    int h = t;
    for (int kw = 0; kw < 16; ++kw) {
        float re = 0.f, im = 0.f;
        #pragma unroll
        for (int krow = 0; krow < 32; ++krow) {
            int kh = krow < 16 ? krow : krow + 32;
            int j = (h * kh) & 63;
            float c = twc[j], s = tws[j];
            float fr = F[krow][kw][0], fi = F[krow][kw][1];
            re += fr * c - fi * s;
            im += fr * s + fi * c;
        }
        tarr[h][kw][0] = re * (1.f / 64.f);
        tarr[h][kw][1] = im * (1.f / 64.f);
    }
    __syncthreads();
    const ushort* x2p = x2t + (size_t)p * 4096;
    ushort* tp = tmp + (size_t)p * 4096;
    for (int q = 0; q < 64; ++q) {
        int w = t;
        float acc = tarr[q][0][0];
        #pragma unroll
        for (int kw = 1; kw < 16; ++kw) {
            int j = (w * kw) & 63;
            acc += 2.f * (tarr[q][kw][0] * twc[j] - tarr[q][kw][1] * tws[j]);
        }
        float x1 = acc * (1.f / 64.f);
        int idx = q * 64 + w;
        tp[idx] = f2bf(gelu_f(x1 + b2f(x2p[idx])));
    }
}

// transpose tmp(bf16) [b][d][n] -> out[b][n][d] = cw0*(tmp + x)
__global__ void k_fno_final(const ushort* __restrict__ tmp, const float* __restrict__ x,
        const float* __restrict__ cw, float* __restrict__ out) {
    __shared__ float tile[32][33];
    int b = blockIdx.z;
    int n0 = blockIdx.x * 32, d0 = blockIdx.y * 32;
    int tx = threadIdx.x, ty = threadIdx.y;
    const ushort* tb = tmp + (size_t)b * DD * NN;
    #pragma unroll
    for (int i = 0; i < 4; ++i)
        tile[ty + i * 8][tx] = b2f(tb[(size_t)(d0 + ty + i * 8) * NN + n0 + tx]);
    __syncthreads();
    float cw0 = cw[b * 4];
    #pragma unroll
    for (int i = 0; i < 4; ++i) {
        int n = n0 + ty + i * 8, d = d0 + tx;
        size_t g = ((size_t)b * NN + n) * DD + d;
        out[g] = cw0 * (tile[tx][ty + i * 8] + x[g]);
    }
}

// ---------------- layernorm (f32 in, bf16 out) ----------------
__global__ void __launch_bounds__(256) k_ln(const float* __restrict__ in, const float* __restrict__ g,
        const float* __restrict__ be, ushort* __restrict__ outb) {
    int row = blockIdx.x * 4 + (threadIdx.x >> 6);
    int lane = threadIdx.x & 63;
    const float4* rp = (const float4*)(in + (size_t)row * 256);
    float4 v = rp[lane];
    float s = v.x + v.y + v.z + v.w;
    float s2 = v.x * v.x + v.y * v.y + v.z * v.z + v.w * v.w;
    #pragma unroll
    for (int off = 32; off > 0; off >>= 1) {
        s += __shfl_down(s, off);
        s2 += __shfl_down(s2, off);
    }
    s = __shfl(s, 0); s2 = __shfl(s2, 0);
    float mu = s * (1.f / 256.f);
    float var = s2 * (1.f / 256.f) - mu * mu;
    float rstd = rsqrtf(var + 1e-5f);
    float4 gv = ((const float4*)g)[lane];
    float4 bv = ((const float4*)be)[lane];
    ushort4 ov;
    ov.x = f2bf((v.x - mu) * rstd * gv.x + bv.x);
    ov.y = f2bf((v.y - mu) * rstd * gv.y + bv.y);
    ov.z = f2bf((v.z - mu) * rstd * gv.z + bv.z);
    ov.w = f2bf((v.w - mu) * rstd * gv.w + bv.w);
    ((ushort4*)(outb + (size_t)row * 256))[lane] = ov;
}

// ---------------- MFMA window attention ----------------
__global__ void __launch_bounds__(256) k_window_attn(const ushort* __restrict__ qkvb,
        ushort* __restrict__ aob) {
    __shared__ ushort lds[4 * 7424];
    int t = threadIdx.x;
    int w = t >> 6, lane = t & 63;
    int wi = blockIdx.x, hh = blockIdx.y;
    int hd = hh * 4 + w;
    int b = wi >> 6, hb = (wi >> 3) & 7, wb = wi & 7;
    ushort* A = lds + w * 7424;
    ushort* Kl = A + 2560;
    ushort* Vt = A + 5120;
    int rlo = lane & 15, kq = lane >> 4;

    int tok = lane;
    int n = hb * 512 + wb * 8 + ((tok >> 3) << 6) + (tok & 7);
    const ushort* gq = qkvb + ((size_t)b * 4096 + n) * 768 + hd * 32;
    const uint4* qp = (const uint4*)gq;
    const uint4* kp = (const uint4*)(gq + 256);
    const uint4* vp = (const uint4*)(gq + 512);
    uint4 q0 = qp[0], q1 = qp[1], q2 = qp[2], q3 = qp[3];
    uint4 k0 = kp[0], k1 = kp[1], k2 = kp[2], k3 = kp[3];
    uint4 v0 = vp[0], v1 = vp[1], v2 = vp[2], v3 = vp[3];
    uint4* qr = (uint4*)(A + tok * 40);
    qr[0] = q0; qr[1] = q1; qr[2] = q2; qr[3] = q3;
    uint4* kr = (uint4*)(Kl + tok * 40);
    kr[0] = k0; kr[1] = k1; kr[2] = k2; kr[3] = k3;
    ushort vbuf[32];
    *(uint4*)&vbuf[0] = v0; *(uint4*)&vbuf[8] = v1;
    *(uint4*)&vbuf[16] = v2; *(uint4*)&vbuf[24] = v3;
    #pragma unroll
    for (int d = 0; d < 32; ++d) Vt[d * 72 + tok] = vbuf[d];
    __syncthreads();

    bf16x8 Qf[4], Kf[4];
    #pragma unroll
    for (int lt = 0; lt < 4; ++lt)
        Qf[lt] = *(const bf16x8*)(A + (lt * 16 + rlo) * 40 + kq * 8);
    #pragma unroll
    for (int mt = 0; mt < 4; ++mt)
        Kf[mt] = *(const bf16x8*)(Kl + (mt * 16 + rlo) * 40 + kq * 8);

    f32x4 S[4][4];
    #pragma unroll
    for (int lt = 0; lt < 4; ++lt)
        #pragma unroll
        for (int mt = 0; mt < 4; ++mt)
            S[lt][mt] = __builtin_amdgcn_mfma_f32_16x16x32_bf16(Qf[lt], Kf[mt],
                        (f32x4){0.f, 0.f, 0.f, 0.f}, 0, 0, 0);
    __syncthreads();

    const float scale = 0.17677669529663687f;
    float inv_[4][4];
    #pragma unroll
    for (int lt = 0; lt < 4; ++lt) {
        float m4[4], s4[4];
        #pragma unroll
        for (int j = 0; j < 4; ++j) {
            m4[j] = fmaxf(fmaxf(S[lt][0][j], S[lt][1][j]), fmaxf(S[lt][2][j], S[lt][3][j]));
        }
        #pragma unroll
        for (int off = 1; off < 16; off <<= 1)
            #pragma unroll
            for (int j = 0; j < 4; ++j) m4[j] = fmaxf(m4[j], __shfl_xor(m4[j], off));
        #pragma unroll
        for (int j = 0; j < 4; ++j) s4[j] = 0.f;
        #pragma unroll
        for (int mt = 0; mt < 4; ++mt)
            #pragma unroll
            for (int j = 0; j < 4; ++j) {
                float p = expf((S[lt][mt][j] - m4[j]) * scale);
                s4[j] += p;
                A[(lt * 16 + kq * 4 + j) * 72 + mt * 16 + rlo] = f2bf(p);
            }
        #pragma unroll
        for (int off = 1; off < 16; off <<= 1)
            #pragma unroll
            for (int j = 0; j < 4; ++j) s4[j] += __shfl_xor(s4[j], off);
        #pragma unroll
        for (int j = 0; j < 4; ++j) inv_[lt][j] = 1.0f / s4[j];
    }
    __syncthreads();

    f32x4 O[4][2];
    #pragma unroll
    for (int lt = 0; lt < 4; ++lt)
        #pragma unroll
        for (int dt = 0; dt < 2; ++dt) {
            f32x4 o = (f32x4){0.f, 0.f, 0.f, 0.f};
            #pragma unroll
            for (int mc = 0; mc < 2; ++mc) {
                bf16x8 pa = *(const bf16x8*)(A + (lt * 16 + rlo) * 72 + mc * 32 + kq * 8);
                bf16x8 vb = *(const bf16x8*)(Vt + (dt * 16 + rlo) * 72 + mc * 32 + kq * 8);
                o = __builtin_amdgcn_mfma_f32_16x16x32_bf16(pa, vb, o, 0, 0, 0);
            }
            O[lt][dt] = o;
        }
    __syncthreads();

    #pragma unroll
    for (int lt = 0; lt < 4; ++lt)
        #pragma unroll
        for (int dt = 0; dt < 2; ++dt)
            #pragma unroll
            for (int j = 0; j < 4; ++j)
                A[(lt * 16 + kq * 4 + j) * 40 + dt * 16 + rlo] = f2bf(O[lt][dt][j] * inv_[lt][j]);
    __syncthreads();
    const uint4* orow = (const uint4*)(A + lane * 40);
    uint4 o0 = orow[0], o1 = orow[1], o2 = orow[2], o3 = orow[3];
    uint4* gout = (uint4*)(aob + ((size_t)b * 4096 + n) * 256 + hd * 32);
    gout[0] = o0; gout[1] = o1; gout[2] = o2; gout[3] = o3;
}

extern "C" void kernel_launch(void* const* d_in, const int* in_sizes, int n_in,
                              void* d_out, int out_size, void* d_ws, size_t ws_size,
                              hipStream_t stream) {
    (void)in_sizes; (void)n_in; (void)out_size; (void)ws_size;
    const float* x        = (const float*)d_in[0];
    const float* text     = (const float*)d_in[1];
    const float* gate_w1  = (const float*)d_in[2];
    const float* gate_b1  = (const float*)d_in[3];
    const float* gate_w2  = (const float*)d_in[4];
    const float* gate_b2  = (const float*)d_in[5];
    const float* fno_w1r  = (const float*)d_in[6];
    const float* fno_w1i  = (const float*)d_in[7];
    const float* fno_w2r  = (const float*)d_in[8];
    const float* fno_w2i  = (const float*)d_in[9];
    const float* fno_cw   = (const float*)d_in[10];
    const float* fno_cb   = (const float*)d_in[11];
    const float* mlp1_w1  = (const float*)d_in[12];
    const float* mlp1_b1  = (const float*)d_in[13];
    const float* mlp1_w2  = (const float*)d_in[14];
    const float* mlp1_b2  = (const float*)d_in[15];
    const float* mlp2_w1  = (const float*)d_in[16];
    const float* mlp2_b1  = (const float*)d_in[17];
    const float* mlp2_w2  = (const float*)d_in[18];
    const float* mlp2_b2  = (const float*)d_in[19];
    const float* ln1_g    = (const float*)d_in[20];
    const float* ln1_b    = (const float*)d_in[21];
    const float* qkv_w    = (const float*)d_in[22];
    const float* qkv_b    = (const float*)d_in[23];
    const float* out_w    = (const float*)d_in[24];
    const float* out_b    = (const float*)d_in[25];
    const float* ln2_g    = (const float*)d_in[26];
    const float* ln2_b    = (const float*)d_in[27];
    const float* wa_w1    = (const float*)d_in[28];
    const float* wa_b1    = (const float*)d_in[29];
    const float* wa_w2    = (const float*)d_in[30];
    const float* wa_b2    = (const float*)d_in[31];

    float* ws   = (float*)d_ws;
    float* feat = ws;                // 8192
    float* h1   = ws + 8192;         // 2048
    float* cwp  = ws + 10240;        // 32
    ushort* wbf = (ushort*)(ws + 16384);     // weight bf16 pool
    ushort* w1aT = wbf;
    ushort* w2aT = w1aT + 262144;
    ushort* w1bT = w2aT + 262144;
    ushort* w2bT = w1bT + 262144;
    ushort* w1cT = w2bT + 262144;
    ushort* w2cT = w1cT + 262144;
    ushort* qkvT = w2cT + 262144;
    ushort* outwT = qkvT + 196608;
    ushort* convT = outwT + 65536;
    ushort* Xbf  = (ushort*)(ws + 16384 + 1048576);          // bf16 x
    float* slotA = ws + 16384 + 1048576 + 4194304;           // 8.39M floats (xg / spectral-partials / abf)
    ushort* abf  = (ushort*)slotA;
    float* xft   = slotA + 8388608;                          // 2.1M
    float* oft   = xft + 2097152;                            // 2.1M (gate partials only)
    float* regD  = oft + 2097152;                            // 8.39M (x2t-bf16 / xattn)
    ushort* bigb = (ushort*)(regD + 8388608);                // tmp-bf16 / qkv-bf16 / hidden-bf16
    float* gpart = oft;

    float* outp = (float*)d_out;
    float* wout = outp + (size_t)NB * NN * DD;

    // gating
    k_gate_mean1<<<dim3(32, 8), 256, 0, stream>>>(x, gpart);
    k_gate_mean2<<<8, 256, 0, stream>>>(gpart, text, feat);
    k_gate_mlp1<<<8, 256, 0, stream>>>(feat, gate_w1, gate_b1, h1);
    k_gate_top<<<1, 64, 0, stream>>>(h1, gate_w2, gate_b2, cwp, wout);

    // prep: bf16 conversions
    k_cvtbf<<<8192, 256, 0, stream>>>(x, Xbf);
    dim3 wtb(32, 8);
    k_wt<<<dim3(32, 8), wtb, 0, stream>>>(mlp1_w1, w1aT, 256, 1024);
    k_wt<<<dim3(8, 32), wtb, 0, stream>>>(mlp1_w2, w2aT, 1024, 256);
    k_wt<<<dim3(32, 8), wtb, 0, stream>>>(mlp2_w1, w1bT, 256, 1024);
    k_wt<<<dim3(8, 32), wtb, 0, stream>>>(mlp2_w2, w2bT, 1024, 256);
    k_wt<<<dim3(32, 8), wtb, 0, stream>>>(wa_w1, w1cT, 256, 1024);
    k_wt<<<dim3(8, 32), wtb, 0, stream>>>(wa_w2, w2cT, 1024, 256);
    k_wt<<<dim3(24, 8), wtb, 0, stream>>>(qkv_w, qkvT, 256, 768);
    k_wt<<<dim3(8, 8), wtb, 0, stream>>>(out_w, outwT, 256, 256);
    k_wt<<<dim3(8, 8), wtb, 0, stream>>>(fno_cw, convT, 256, 256);

    // expert 0: FNO (channel-major pipeline; final kernel writes all of out)
    k_transpose<<<dim3(128, 8, 8), dim3(32, 8), 0, stream>>>(x, slotA);
    k_rfft2<<<2048, 64, 0, stream>>>(slotA, xft);
    // conv branch x2t[b][o][n] bf16: A=convT [o][d], Bt=Xbf[b] [n][d]
    k_gemm<5><<<dim3(2, 32, 8), 256, 0, stream>>>(convT, Xbf, fno_cb, nullptr, nullptr,
        (ushort*)regD, nullptr, 0, 256, 4096, 0, (size_t)NN * DD, (size_t)DD * NN);
    // spectral partials (2 halves) into slotA; irfft sums them inline, tmp(bf16) -> bigb
    k_spectral<<<dim3(16, 16, 4), 512, 0, stream>>>(xft, fno_w1r, fno_w1i, fno_w2r, fno_w2i, slotA);
    k_irfft_fuse<<<2048, 64, 0, stream>>>(slotA, (const ushort*)regD, bigb);
    k_fno_final<<<dim3(128, 8, 8), dim3(32, 8), 0, stream>>>(bigb, x, cwp, outp);

    // expert 1: MLP
    k_gemm<0><<<dim3(256, 8), 256, 0, stream>>>(Xbf, w1aT, mlp1_b1, nullptr, nullptr, bigb, nullptr, 0, 256, 1024, 0, 0, 0);
    k_gemm<3><<<dim3(256, 2), 256, 0, stream>>>(bigb, w2aT, mlp1_b2, x, outp, nullptr, cwp, 1, 1024, 256, 0, 0, 0);

    // expert 2: window attention
    k_ln<<<8192, 256, 0, stream>>>(x, ln1_g, ln1_b, abf);
    k_gemm<1><<<dim3(256, 6), 256, 0, stream>>>(abf, qkvT, qkv_b, nullptr, nullptr, bigb, nullptr, 0, 256, 768, 0, 0, 0);
    k_window_attn<<<dim3(512, 2), 256, 0, stream>>>(bigb, abf);
    k_gemm<2><<<dim3(256, 2), 256, 0, stream>>>(abf, outwT, out_b, x, regD, nullptr, nullptr, 0, 256, 256, 0, 0, 0);
    k_ln<<<8192, 256, 0, stream>>>(regD, ln2_g, ln2_b, abf);
    k_gemm<0><<<dim3(256, 8), 256, 0, stream>>>(abf, w1cT, wa_b1, nullptr, nullptr, bigb, nullptr, 0, 256, 1024, 0, 0, 0);
    k_gemm<3><<<dim3(256, 2), 256, 0, stream>>>(bigb, w2cT, wa_b2, regD, outp, nullptr, cwp, 2, 1024, 256, 0, 0, 0);

    // expert 3: MLP
    k_gemm<0><<<dim3(256, 8), 256, 0, stream>>>(Xbf, w1bT, mlp2_b1, nullptr, nullptr, bigb, nullptr, 0, 256, 1024, 0, 0, 0);
    k_gemm<3><<<dim3(256, 2), 256, 0, stream>>>(bigb, w2bT, mlp2_b2, x, outp, nullptr, cwp, 3, 1024, 256, 0, 0, 0);
}